// Round 8
// baseline (620.031 us; speedup 1.0000x reference)
//
#include <hip/hip_runtime.h>
#include <hip/hip_fp16.h>
#include <math.h>

#define L 4096
#define DIN 1024
#define DM 512
#define DI 1024
#define DS 16
#define DTR 32
#define NCH 128
#define CHK 32   // NCH*CHK == L

typedef _Float16 v8h __attribute__((ext_vector_type(8)));
typedef float v4f __attribute__((ext_vector_type(4)));

// ---------------- perm table ----------------
__global__ void perm_k(int* __restrict__ perm, const int* __restrict__ ratep) {
    int p = blockIdx.x * blockDim.x + threadIdx.x;
    if (p >= L) return;
    int rate = ratep[0];
    int cum = 0;
    for (int g = 0; g < rate; ++g) {
        int sz = (L - g + rate - 1) / rate;
        if (p < cum + sz) { perm[p] = g + rate * (p - cum); return; }
        cum += sz;
    }
}

// ---------------- fp32 -> fp16 convert, 4 segments in one launch --------------
__global__ __launch_bounds__(256) void f2h_multi_k(
    const float* __restrict__ s0, _Float16* __restrict__ d0, int b0,
    const float* __restrict__ s1, _Float16* __restrict__ d1, int b1,
    const float* __restrict__ s2, _Float16* __restrict__ d2, int b2,
    const float* __restrict__ s3, _Float16* __restrict__ d3, int b3)
{
    int b = blockIdx.x;
    const float* src; _Float16* dst; int lb;
    if (b < b0)                { src = s0; dst = d0; lb = b; }
    else if (b < b0 + b1)      { src = s1; dst = d1; lb = b - b0; }
    else if (b < b0 + b1 + b2) { src = s2; dst = d2; lb = b - b0 - b1; }
    else                       { src = s3; dst = d3; lb = b - b0 - b1 - b2; }
    int i = (lb * 256 + threadIdx.x) * 4;
    float4 v = *(const float4*)(src + i);
    _Float16 h4[4] = {(_Float16)v.x, (_Float16)v.y, (_Float16)v.z, (_Float16)v.w};
    *(uint2*)(dst + i) = *(uint2*)h4;
}

// ---------------- fp16 MFMA GEMM (round-6 structure: reg prefetch, padded LDS)
// C = act(A(MxK)*B(NxK)^T + bias) [+C]. BNT=128: 4 waves 64x64; BNT=64: 4 waves
// 32x64 (2x grid for N=512). HALF=1: store C as fp16 (no accum).
template<int ACT, int BNT, int HALF>   // ACT: 0 none, 1 relu
__global__ __launch_bounds__(256) void hgemm_nt(
    const _Float16* __restrict__ A, int lda,
    const _Float16* __restrict__ B, int ldb,
    void* __restrict__ Cv, int ldc,
    const float* __restrict__ bias, int K, int accum)
{
    constexpr int MI = (BNT == 128) ? 4 : 2;
    __shared__ _Float16 As[128][40];   // pad 32->40: 2-way bank alias only (free)
    __shared__ _Float16 Bs[BNT][40];
    int tid = threadIdx.x;
    int m0 = blockIdx.y * 128, n0 = blockIdx.x * BNT;
    int lane = tid & 63, wave = tid >> 6;
    int wm, wn;
    if constexpr (BNT == 128) { wm = (wave >> 1) * 64; wn = (wave & 1) * 64; }
    else                      { wm = wave * 32;        wn = 0; }
    int quad = lane >> 4, r16 = lane & 15;
    v4f acc[MI][4] = {};

    int srow = tid >> 1;            // 0..127
    int scol = (tid & 1) * 16;      // 0 or 16
    const _Float16* Ag = A + (size_t)(m0 + srow) * lda + scol;
    int srowB = (BNT == 128) ? srow : (tid >> 2);
    int scolB = (BNT == 128) ? scol : (tid & 3) * 8;
    const _Float16* Bg = B + (size_t)(n0 + srowB) * ldb + scolB;

    uint4 a0, a1, b0, b1;
    a0 = *(const uint4*)(Ag);
    a1 = *(const uint4*)(Ag + 8);
    b0 = *(const uint4*)(Bg);
    if constexpr (BNT == 128) b1 = *(const uint4*)(Bg + 8);

    int KS = K / 32;
    for (int ks = 0; ks < KS; ++ks) {
        __syncthreads();
        *(uint4*)&As[srow][scol] = a0;
        *(uint4*)&As[srow][scol + 8] = a1;
        *(uint4*)&Bs[srowB][scolB] = b0;
        if constexpr (BNT == 128) *(uint4*)&Bs[srowB][scolB + 8] = b1;
        __syncthreads();
        if (ks + 1 < KS) {
            int k0 = (ks + 1) * 32;
            a0 = *(const uint4*)(Ag + k0);
            a1 = *(const uint4*)(Ag + k0 + 8);
            b0 = *(const uint4*)(Bg + k0);
            if constexpr (BNT == 128) b1 = *(const uint4*)(Bg + k0 + 8);
        }
        v8h af[MI], bf[4];
#pragma unroll
        for (int i = 0; i < MI; ++i)
            af[i] = *(const v8h*)&As[wm + i * 16 + r16][quad * 8];
#pragma unroll
        for (int j = 0; j < 4; ++j)
            bf[j] = *(const v8h*)&Bs[wn + j * 16 + r16][quad * 8];
#pragma unroll
        for (int i = 0; i < MI; ++i)
#pragma unroll
            for (int j = 0; j < 4; ++j)
                acc[i][j] = __builtin_amdgcn_mfma_f32_16x16x32_f16(
                    af[i], bf[j], acc[i][j], 0, 0, 0);
    }

    // C/D layout: col = lane&15, row = (lane>>4)*4 + reg
#pragma unroll
    for (int i = 0; i < MI; ++i) {
#pragma unroll
        for (int j = 0; j < 4; ++j) {
            int col = n0 + wn + j * 16 + r16;
            int rbase = m0 + wm + i * 16 + quad * 4;
            float bv = bias ? bias[col] : 0.f;
#pragma unroll
            for (int r = 0; r < 4; ++r) {
                float v = acc[i][j][r] + bv;
                if (ACT == 1) v = fmaxf(v, 0.f);
                if constexpr (HALF) {
                    ((_Float16*)Cv)[(size_t)(rbase + r) * ldc + col] = (_Float16)v;
                } else {
                    float* p = (float*)Cv + (size_t)(rbase + r) * ldc + col;
                    if (accum) v += *p;
                    *p = v;
                }
            }
        }
    }
}

// ---------------- generic fp32 GEMM: C = act(A*B^T + bias) --------------------
// ACT: 0 none, 4 tanh+fused-dot (attn: no C store, atomicAdd partials to avec)
// Split-K via blockIdx.z; accum: 0 store, 2 atomicAdd.
#define BM 64
#define BN 64
#define BKK 32
template<int ACT>
__global__ __launch_bounds__(256) void gemm_nt(
    const float* __restrict__ A, int lda,
    const float* __restrict__ B, int ldb,
    float* __restrict__ C, int ldc,
    const float* __restrict__ bias,
    int M, int N, int K, int kchunk, int accum,
    const float* __restrict__ w2, float* __restrict__ avec)
{
    __shared__ float As[BKK][BM + 4];
    __shared__ float Bs[BKK][BN + 4];
    int tid = threadIdx.x;
    int m0 = blockIdx.y * BM;
    int n0 = blockIdx.x * BN;
    int tx = tid & 15, ty = tid >> 4;
    float acc[4][4] = {};
    int arow = tid >> 3;       // 0..31
    int ak = (tid & 7) * 4;    // 0..28
    int kb = blockIdx.z * kchunk;
    int ke = min(K, kb + kchunk);

    for (int k0 = kb; k0 < ke; k0 += BKK) {
#pragma unroll
        for (int r = 0; r < 2; ++r) {
            int row = arow + r * 32;
            float4 va = *(const float4*)(A + (size_t)(m0 + row) * lda + k0 + ak);
            As[ak + 0][row] = va.x; As[ak + 1][row] = va.y;
            As[ak + 2][row] = va.z; As[ak + 3][row] = va.w;
            float4 vb = *(const float4*)(B + (size_t)(n0 + row) * ldb + k0 + ak);
            Bs[ak + 0][row] = vb.x; Bs[ak + 1][row] = vb.y;
            Bs[ak + 2][row] = vb.z; Bs[ak + 3][row] = vb.w;
        }
        __syncthreads();
#pragma unroll
        for (int kk = 0; kk < BKK; ++kk) {
            float4 a4 = *(const float4*)&As[kk][ty * 4];
            float4 b4 = *(const float4*)&Bs[kk][tx * 4];
            float a[4] = {a4.x, a4.y, a4.z, a4.w};
            float b[4] = {b4.x, b4.y, b4.z, b4.w};
#pragma unroll
            for (int i = 0; i < 4; ++i)
#pragma unroll
                for (int j = 0; j < 4; ++j)
                    acc[i][j] = fmaf(a[i], b[j], acc[i][j]);
        }
        __syncthreads();
    }

#pragma unroll
    for (int i = 0; i < 4; ++i) {
        int row = m0 + ty * 4 + i;
        int col = n0 + tx * 4;
        if (ACT == 4) {
            float part = 0.f;
#pragma unroll
            for (int j = 0; j < 4; ++j) {
                float xv = tanhf(acc[i][j] + bias[col + j]);
                part = fmaf(xv, w2[col + j], part);
            }
            atomicAdd(&avec[row], part);
            continue;
        }
        float* cp = C + (size_t)row * ldc + col;
        if (accum == 2) {
#pragma unroll
            for (int j = 0; j < 4; ++j) atomicAdd(cp + j, acc[i][j]);
            continue;
        }
#pragma unroll
        for (int j = 0; j < 4; ++j)
            cp[j] = acc[i][j] + (bias ? bias[col + j] : 0.f);
    }
}

// ---------------- layernorm (D=512); optional fp16 side-out; optional avec init
__global__ __launch_bounds__(256) void layernorm_k(
    const float* __restrict__ x, const float* __restrict__ w,
    const float* __restrict__ b, float* __restrict__ o,
    _Float16* __restrict__ oh, float* __restrict__ avec,
    const float* __restrict__ b2)
{
    int row = blockIdx.x;
    int tid = threadIdx.x;
    const float* xr = x + (size_t)row * DM;
    float v0 = xr[tid], v1 = xr[tid + 256];
    float s = v0 + v1, ss = v0 * v0 + v1 * v1;
    for (int off = 32; off; off >>= 1) {
        s += __shfl_down(s, off, 64);
        ss += __shfl_down(ss, off, 64);
    }
    __shared__ float sm[4], sm2[4];
    int wave = tid >> 6, lane = tid & 63;
    if (lane == 0) { sm[wave] = s; sm2[wave] = ss; }
    __syncthreads();
    float tot = sm[0] + sm[1] + sm[2] + sm[3];
    float tot2 = sm2[0] + sm2[1] + sm2[2] + sm2[3];
    float mu = tot * (1.f / DM);
    float var = tot2 * (1.f / DM) - mu * mu;
    float rs = rsqrtf(var + 1e-5f);
    float y0 = (v0 - mu) * rs * w[tid] + b[tid];
    float y1 = (v1 - mu) * rs * w[tid + 256] + b[tid + 256];
    o[(size_t)row * DM + tid] = y0;
    o[(size_t)row * DM + tid + 256] = y1;
    if (oh) {
        oh[(size_t)row * DM + tid] = (_Float16)y0;
        oh[(size_t)row * DM + tid + 256] = (_Float16)y1;
    }
    if (avec && tid == 0) avec[row] = b2[0];
}

// ---------------- permuted causal conv (K=4) + SiLU; also zeroes dbl ----------
__global__ __launch_bounds__(256) void conv_silu_k(
    const _Float16* __restrict__ xz, const int* __restrict__ perm,
    const float* __restrict__ cw, const float* __restrict__ cb,
    float* __restrict__ xc, float* __restrict__ dbl)
{
    if (blockIdx.x < 256) {   // zero dbl (L*64 floats) for the split-K atomics
        int zi = (blockIdx.x * 256 + threadIdx.x) * 4;
        *(float4*)(dbl + zi) = make_float4(0.f, 0.f, 0.f, 0.f);
    }
    int g = blockIdx.x * 256 + threadIdx.x;   // g < L*DI
    int c = g & (DI - 1), p = g >> 10;
    float acc = cb[c];
#pragma unroll
    for (int k = 0; k < 4; ++k) {
        int q = p + k - 3;
        if (q >= 0)
            acc = fmaf((float)xz[(size_t)perm[q] * (2 * DI) + c], cw[c * 4 + k], acc);
    }
    float sig = 1.f / (1.f + __expf(-acc));
    xc[g] = acc * sig;
}

// ---------------- chunked parallel selective scan (dt fused in) ---------------
// One thread per (channel, chunk); 16 states in registers. dt computed on the
// fly: softplus(dot(dbl[t,:32], dtw[c,:]) + dtb[c]) — dbl row loads are
// wave-uniform (L1 broadcast).
__device__ __forceinline__ float dt_of(
    const float* __restrict__ dblrow, const v4f* __restrict__ dw, float dtbc)
{
    float dot = dtbc;
#pragma unroll
    for (int q = 0; q < 8; ++q) {
        v4f dr = *(const v4f*)(dblrow + q * 4);
#pragma unroll
        for (int r = 0; r < 4; ++r) dot = fmaf(dr[r], dw[q][r], dot);
    }
    return (dot > 20.f) ? dot : log1pf(__expf(dot));
}

__global__ __launch_bounds__(256) void scan_pass1(
    const float* __restrict__ u, const float* __restrict__ dbl,
    const float* __restrict__ dtw, const float* __restrict__ dtb,
    const float* __restrict__ A_log,
    float* __restrict__ Aprod, float* __restrict__ carry)
{
    int c = blockIdx.x * 256 + threadIdx.x;
    int j = blockIdx.y;
    float Ac[16];
#pragma unroll
    for (int s = 0; s < 16; ++s) Ac[s] = -__expf(A_log[c * DS + s]);
    v4f dw[8];
#pragma unroll
    for (int q = 0; q < 8; ++q) dw[q] = *(const v4f*)(dtw + c * DTR + q * 4);
    float dtbc = dtb[c];
    float ap[16], h[16];
#pragma unroll
    for (int s = 0; s < 16; ++s) { ap[s] = 1.f; h[s] = 0.f; }
    int t0 = j * CHK;
    for (int tt = 0; tt < CHK; ++tt) {
        int t = t0 + tt;
        const float* dblrow = dbl + (size_t)t * 64;
        float dtv = dt_of(dblrow, dw, dtbc);
        float uv  = u[(size_t)t * DI + c];
        v4f Bv[4];
#pragma unroll
        for (int q = 0; q < 4; ++q)
            Bv[q] = *(const v4f*)(dblrow + DTR + q * 4);
        float du = dtv * uv;
#pragma unroll
        for (int s = 0; s < 16; ++s) {
            float dA = __expf(dtv * Ac[s]);
            h[s] = fmaf(dA, h[s], du * Bv[s >> 2][s & 3]);
            ap[s] *= dA;
        }
    }
    size_t base = ((size_t)j * DI + c) * DS;
#pragma unroll
    for (int q = 0; q < 4; ++q) {
        *(v4f*)(Aprod + base + q * 4) = *(v4f*)&ap[q * 4];
        *(v4f*)(carry + base + q * 4) = *(v4f*)&h[q * 4];
    }
}

// Pass 2: exclusive prefix across chunks per (c,s).
__global__ __launch_bounds__(256) void scan_pass2(
    const float* __restrict__ Aprod, const float* __restrict__ carry,
    float* __restrict__ Hin)
{
    int idx = blockIdx.x * 256 + threadIdx.x;  // (c,s) flat, 16384 total
    float H = 0.f;
    Hin[idx] = 0.f;
    for (int j = 1; j < NCH; ++j) {
        H = fmaf(Aprod[(size_t)(j - 1) * (DI * DS) + idx], H,
                 carry[(size_t)(j - 1) * (DI * DS) + idx]);
        Hin[(size_t)j * (DI * DS) + idx] = H;
    }
}

// Pass 3: seeded local scan; gated output scattered, fp16 for out_proj.
__global__ __launch_bounds__(256) void scan_pass3(
    const float* __restrict__ u, const float* __restrict__ dbl,
    const float* __restrict__ dtw, const float* __restrict__ dtb,
    const _Float16* __restrict__ xz, const float* __restrict__ A_log,
    const float* __restrict__ Dsk, const int* __restrict__ perm,
    const float* __restrict__ Hin, _Float16* __restrict__ yo)
{
    int c = blockIdx.x * 256 + threadIdx.x;
    int j = blockIdx.y;
    float Ac[16];
#pragma unroll
    for (int s = 0; s < 16; ++s) Ac[s] = -__expf(A_log[c * DS + s]);
    v4f dw[8];
#pragma unroll
    for (int q = 0; q < 8; ++q) dw[q] = *(const v4f*)(dtw + c * DTR + q * 4);
    float dtbc = dtb[c];
    float Dp = Dsk[c];
    float h[16];
    size_t hbase = ((size_t)j * DI + c) * DS;
#pragma unroll
    for (int q = 0; q < 4; ++q)
        *(v4f*)&h[q * 4] = *(const v4f*)(Hin + hbase + q * 4);
    int t0 = j * CHK;
    for (int tt = 0; tt < CHK; ++tt) {
        int t = t0 + tt;
        const float* dblrow = dbl + (size_t)t * 64;
        float dtv = dt_of(dblrow, dw, dtbc);
        float uv  = u[(size_t)t * DI + c];
        v4f Bv[4], Cv[4];
#pragma unroll
        for (int q = 0; q < 4; ++q) {
            Bv[q] = *(const v4f*)(dblrow + DTR + q * 4);
            Cv[q] = *(const v4f*)(dblrow + DTR + DS + q * 4);
        }
        float du = dtv * uv;
        float y = 0.f;
#pragma unroll
        for (int s = 0; s < 16; ++s) {
            float dA = __expf(dtv * Ac[s]);
            h[s] = fmaf(dA, h[s], du * Bv[s >> 2][s & 3]);
            y = fmaf(h[s], Cv[s >> 2][s & 3], y);
        }
        int tp = perm[t];
        float z = (float)xz[(size_t)tp * (2 * DI) + DI + c];
        float sig = 1.f / (1.f + __expf(-z));
        yo[(size_t)tp * DI + c] = (_Float16)((y + uv * Dp) * (z * sig));
    }
}

// ---------------- softmax over 4096 (single block); zeroes pooled -------------
__global__ __launch_bounds__(1024) void softmax_k(
    const float* __restrict__ a, float* __restrict__ out,
    float* __restrict__ pooled)
{
    int tid = threadIdx.x;
    if (tid < DM) pooled[tid] = 0.f;
    float v[4];
    float mx = -1e30f;
#pragma unroll
    for (int i = 0; i < 4; ++i) { v[i] = a[tid + i * 1024]; mx = fmaxf(mx, v[i]); }
    __shared__ float sm[16];
    for (int off = 32; off; off >>= 1) mx = fmaxf(mx, __shfl_xor(mx, off, 64));
    int wave = tid >> 6, lane = tid & 63;
    if (lane == 0) sm[wave] = mx;
    __syncthreads();
    if (tid < 16) {
        float m = sm[tid];
        for (int off = 8; off; off >>= 1) m = fmaxf(m, __shfl_xor(m, off, 64));
        sm[tid] = m;
    }
    __syncthreads();
    mx = sm[0];
    float s = 0.f;
#pragma unroll
    for (int i = 0; i < 4; ++i) { v[i] = __expf(v[i] - mx); s += v[i]; }
    for (int off = 32; off; off >>= 1) s += __shfl_xor(s, off, 64);
    __syncthreads();
    if (lane == 0) sm[wave] = s;
    __syncthreads();
    if (tid < 16) {
        float t2 = sm[tid];
        for (int off = 8; off; off >>= 1) t2 += __shfl_xor(t2, off, 64);
        sm[tid] = t2;
    }
    __syncthreads();
    float inv = 1.f / sm[0];
#pragma unroll
    for (int i = 0; i < 4; ++i) out[tid + i * 1024] = v[i] * inv;
}

__global__ __launch_bounds__(512) void pool_k(
    const float* __restrict__ aatt, const float* __restrict__ h,
    float* __restrict__ pooled)
{
    int m = threadIdx.x;
    int t0 = blockIdx.x * 128;
    float acc = 0.f;
    for (int r = 0; r < 128; ++r) {
        int t = t0 + r;
        acc = fmaf(aatt[t], h[(size_t)t * DM + m], acc);
    }
    atomicAdd(&pooled[m], acc);
}

__global__ __launch_bounds__(64) void out2048_k(
    const float* __restrict__ pooled, const float* __restrict__ w,
    const float* __restrict__ b, float* __restrict__ out)
{
    int n = blockIdx.x;
    int lane = threadIdx.x;
    const float* wr = w + (size_t)n * DM;
    float acc = 0.f;
#pragma unroll
    for (int k = 0; k < 8; ++k)
        acc = fmaf(wr[lane + k * 64], pooled[lane + k * 64], acc);
    for (int off = 32; off; off >>= 1) acc += __shfl_xor(acc, off, 64);
    if (lane == 0) out[n] = acc + b[n];
}

extern "C" void kernel_launch(void* const* d_in, const int* in_sizes, int n_in,
                              void* d_out, int out_size, void* d_ws, size_t ws_size,
                              hipStream_t stream) {
    const float* x     = (const float*)d_in[0];
    const int*   rate  = (const int*)d_in[1];
    const float* fc1_w = (const float*)d_in[2];
    const float* fc1_b = (const float*)d_in[3];
    const float* ln_w  = (const float*)d_in[4];
    const float* ln_b  = (const float*)d_in[5];
    const float* ipw   = (const float*)d_in[6];
    const float* cw    = (const float*)d_in[7];
    const float* cb    = (const float*)d_in[8];
    const float* xpw   = (const float*)d_in[9];
    const float* dtw   = (const float*)d_in[10];
    const float* dtpb  = (const float*)d_in[11];
    const float* A_log = (const float*)d_in[12];
    const float* Dsk   = (const float*)d_in[13];
    const float* opw   = (const float*)d_in[14];
    const float* nw    = (const float*)d_in[15];
    const float* nb    = (const float*)d_in[16];
    const float* aw1   = (const float*)d_in[17];
    const float* ab1   = (const float*)d_in[18];
    const float* aw2   = (const float*)d_in[19];
    const float* ab2   = (const float*)d_in[20];
    const float* ow    = (const float*)d_in[21];
    const float* ob    = (const float*)d_in[22];
    float* out = (float*)d_out;

    int* perm = (int*)d_ws;
    float* f = (float*)d_ws + 4096;
    float* h    = f; f += (size_t)L * DM;
    float* hln  = f; f += (size_t)L * DM;
    float* xc   = f; f += (size_t)L * DI;
    float* dbl  = f; f += (size_t)L * 64;
    float* avec = f; f += L;
    float* pooled = f; f += DM;
    float* Aprod = f; f += (size_t)NCH * DI * DS;
    float* carry = f; f += (size_t)NCH * DI * DS;
    float* Hin   = f; f += (size_t)NCH * DI * DS;
    _Float16* fh = (_Float16*)f;
    _Float16* xh     = fh; fh += (size_t)L * DIN;
    _Float16* hln_h  = fh; fh += (size_t)L * DM;
    _Float16* yo_h   = fh; fh += (size_t)L * DI;
    _Float16* xz_h   = fh; fh += (size_t)L * 2 * DI;
    _Float16* fc1w_h = fh; fh += (size_t)DM * DIN;
    _Float16* ipw_h  = fh; fh += (size_t)2 * 2 * DI * DM;
    _Float16* opw_h  = fh; fh += (size_t)2 * DM * DI;

    perm_k<<<16, 256, 0, stream>>>(perm, rate);

    // all fp32->fp16 conversions in a single launch
    f2h_multi_k<<<(L * DIN + DM * DIN + 2 * 2 * DI * DM + 2 * DM * DI) / 1024,
                  256, 0, stream>>>(
        x, xh, L * DIN / 1024,
        fc1_w, fc1w_h, DM * DIN / 1024,
        ipw, ipw_h, 2 * 2 * DI * DM / 1024,
        opw, opw_h, 2 * DM * DI / 1024);

    // h = relu(x @ fc1_w^T + fc1_b)   [fp16 MFMA, N64 tile -> 256 blocks]
    hgemm_nt<1, 64, 0><<<dim3(DM / 64, L / 128), 256, 0, stream>>>(
        xh, DIN, fc1w_h, DIN, h, DM, fc1_b, DIN, 0);

    for (int l = 0; l < 2; ++l) {
        layernorm_k<<<L, 256, 0, stream>>>(h, ln_w + l * DM, ln_b + l * DM,
                                           hln, hln_h, nullptr, nullptr);
        // xz = hln @ in_proj^T   [fp16 MFMA -> fp16 out, 512 blocks]
        hgemm_nt<0, 128, 1><<<dim3(2 * DI / 128, L / 128), 256, 0, stream>>>(
            hln_h, DM, ipw_h + (size_t)l * 2 * DI * DM, DM, xz_h, 2 * DI,
            nullptr, DM, 0);
        // xc = silu(causal_conv(x_perm)); also zeroes dbl for split-K atomics
        conv_silu_k<<<L * DI / 256, 256, 0, stream>>>(
            xz_h, perm, cw + (size_t)l * DI * 4, cb + (size_t)l * DI, xc, dbl);
        // dbl = xc @ x_proj^T  (N=64; split-K x4 for occupancy, atomic partials)
        gemm_nt<0><<<dim3(1, L / 64, 4), 256, 0, stream>>>(
            xc, DI, xpw + (size_t)l * 64 * DI, DI, dbl, 64, nullptr,
            L, 64, DI, DI / 4, 2, nullptr, nullptr);
        // chunked parallel selective scan (dt fused into passes 1 & 3)
        scan_pass1<<<dim3(DI / 256, NCH), 256, 0, stream>>>(
            xc, dbl, dtw + (size_t)l * DI * DTR, dtpb + (size_t)l * DI,
            A_log + (size_t)l * DI * DS, Aprod, carry);
        scan_pass2<<<DI * DS / 256, 256, 0, stream>>>(Aprod, carry, Hin);
        scan_pass3<<<dim3(DI / 256, NCH), 256, 0, stream>>>(
            xc, dbl, dtw + (size_t)l * DI * DTR, dtpb + (size_t)l * DI,
            xz_h, A_log + (size_t)l * DI * DS, Dsk + (size_t)l * DI,
            perm, Hin, yo_h);
        // h += yo @ out_proj^T   [fp16 MFMA, N64 tile -> 256 blocks, accumulate]
        hgemm_nt<0, 64, 0><<<dim3(DM / 64, L / 128), 256, 0, stream>>>(
            yo_h, DI, opw_h + (size_t)l * DM * DI, DI, h, DM, nullptr, DI, 1);
    }

    // final LN (also seeds avec with attn bias b2)
    layernorm_k<<<L, 256, 0, stream>>>(h, nw, nb, hln, nullptr, avec, ab2);
    // fused: avec += tanh(hln @ aw1^T + ab1) . w2   (t1 never materialized)
    gemm_nt<4><<<dim3(128 / 64, L / 64), 256, 0, stream>>>(
        hln, DM, aw1, DM, nullptr, 0, ab1, L, 128, DM, DM, 0, aw2, avec);
    softmax_k<<<1, 1024, 0, stream>>>(avec, out + 2048, pooled);
    pool_k<<<32, 512, 0, stream>>>(out + 2048, hln, pooled);
    out2048_k<<<2048, 64, 0, stream>>>(pooled, ow, ob, out);
}

// Round 9
// 588.738 us; speedup vs baseline: 1.0532x; 1.0532x over previous
//
#include <hip/hip_runtime.h>
#include <hip/hip_fp16.h>
#include <math.h>

#define L 4096
#define DIN 1024
#define DM 512
#define DI 1024
#define DS 16
#define DTR 32
#define NCH 256
#define CHK 16   // NCH*CHK == L

typedef _Float16 v8h __attribute__((ext_vector_type(8)));
typedef float v4f __attribute__((ext_vector_type(4)));

// ---------------- perm table ----------------
__global__ void perm_k(int* __restrict__ perm, const int* __restrict__ ratep) {
    int p = blockIdx.x * blockDim.x + threadIdx.x;
    if (p >= L) return;
    int rate = ratep[0];
    int cum = 0;
    for (int g = 0; g < rate; ++g) {
        int sz = (L - g + rate - 1) / rate;
        if (p < cum + sz) { perm[p] = g + rate * (p - cum); return; }
        cum += sz;
    }
}

// ---------------- fp32 -> fp16 convert, 4 segments in one launch --------------
__global__ __launch_bounds__(256) void f2h_multi_k(
    const float* __restrict__ s0, _Float16* __restrict__ d0, int b0,
    const float* __restrict__ s1, _Float16* __restrict__ d1, int b1,
    const float* __restrict__ s2, _Float16* __restrict__ d2, int b2,
    const float* __restrict__ s3, _Float16* __restrict__ d3, int b3)
{
    int b = blockIdx.x;
    const float* src; _Float16* dst; int lb;
    if (b < b0)                { src = s0; dst = d0; lb = b; }
    else if (b < b0 + b1)      { src = s1; dst = d1; lb = b - b0; }
    else if (b < b0 + b1 + b2) { src = s2; dst = d2; lb = b - b0 - b1; }
    else                       { src = s3; dst = d3; lb = b - b0 - b1 - b2; }
    int i = (lb * 256 + threadIdx.x) * 4;
    float4 v = *(const float4*)(src + i);
    _Float16 h4[4] = {(_Float16)v.x, (_Float16)v.y, (_Float16)v.z, (_Float16)v.w};
    *(uint2*)(dst + i) = *(uint2*)h4;
}

// ---------------- fp16 MFMA GEMM (reg prefetch, padded LDS) -------------------
// C = act(A(MxK)*B(NxK)^T + bias) [+C]. BNT=128: 4 waves 64x64; BNT=64: 4 waves
// 32x64 (2x grid for N=512). HALF=1: store C as fp16 (no accum).
template<int ACT, int BNT, int HALF>   // ACT: 0 none, 1 relu
__global__ __launch_bounds__(256) void hgemm_nt(
    const _Float16* __restrict__ A, int lda,
    const _Float16* __restrict__ B, int ldb,
    void* __restrict__ Cv, int ldc,
    const float* __restrict__ bias, int K, int accum)
{
    constexpr int MI = (BNT == 128) ? 4 : 2;
    __shared__ _Float16 As[128][40];   // pad 32->40: 2-way bank alias only (free)
    __shared__ _Float16 Bs[BNT][40];
    int tid = threadIdx.x;
    int m0 = blockIdx.y * 128, n0 = blockIdx.x * BNT;
    int lane = tid & 63, wave = tid >> 6;
    int wm, wn;
    if constexpr (BNT == 128) { wm = (wave >> 1) * 64; wn = (wave & 1) * 64; }
    else                      { wm = wave * 32;        wn = 0; }
    int quad = lane >> 4, r16 = lane & 15;
    v4f acc[MI][4] = {};

    int srow = tid >> 1;            // 0..127
    int scol = (tid & 1) * 16;      // 0 or 16
    const _Float16* Ag = A + (size_t)(m0 + srow) * lda + scol;
    int srowB = (BNT == 128) ? srow : (tid >> 2);
    int scolB = (BNT == 128) ? scol : (tid & 3) * 8;
    const _Float16* Bg = B + (size_t)(n0 + srowB) * ldb + scolB;

    uint4 a0, a1, b0, b1;
    a0 = *(const uint4*)(Ag);
    a1 = *(const uint4*)(Ag + 8);
    b0 = *(const uint4*)(Bg);
    if constexpr (BNT == 128) b1 = *(const uint4*)(Bg + 8);

    int KS = K / 32;
    for (int ks = 0; ks < KS; ++ks) {
        __syncthreads();
        *(uint4*)&As[srow][scol] = a0;
        *(uint4*)&As[srow][scol + 8] = a1;
        *(uint4*)&Bs[srowB][scolB] = b0;
        if constexpr (BNT == 128) *(uint4*)&Bs[srowB][scolB + 8] = b1;
        __syncthreads();
        if (ks + 1 < KS) {
            int k0 = (ks + 1) * 32;
            a0 = *(const uint4*)(Ag + k0);
            a1 = *(const uint4*)(Ag + k0 + 8);
            b0 = *(const uint4*)(Bg + k0);
            if constexpr (BNT == 128) b1 = *(const uint4*)(Bg + k0 + 8);
        }
        v8h af[MI], bf[4];
#pragma unroll
        for (int i = 0; i < MI; ++i)
            af[i] = *(const v8h*)&As[wm + i * 16 + r16][quad * 8];
#pragma unroll
        for (int j = 0; j < 4; ++j)
            bf[j] = *(const v8h*)&Bs[wn + j * 16 + r16][quad * 8];
#pragma unroll
        for (int i = 0; i < MI; ++i)
#pragma unroll
            for (int j = 0; j < 4; ++j)
                acc[i][j] = __builtin_amdgcn_mfma_f32_16x16x32_f16(
                    af[i], bf[j], acc[i][j], 0, 0, 0);
    }

    // C/D layout: col = lane&15, row = (lane>>4)*4 + reg
#pragma unroll
    for (int i = 0; i < MI; ++i) {
#pragma unroll
        for (int j = 0; j < 4; ++j) {
            int col = n0 + wn + j * 16 + r16;
            int rbase = m0 + wm + i * 16 + quad * 4;
            float bv = bias ? bias[col] : 0.f;
#pragma unroll
            for (int r = 0; r < 4; ++r) {
                float v = acc[i][j][r] + bv;
                if (ACT == 1) v = fmaxf(v, 0.f);
                if constexpr (HALF) {
                    ((_Float16*)Cv)[(size_t)(rbase + r) * ldc + col] = (_Float16)v;
                } else {
                    float* p = (float*)Cv + (size_t)(rbase + r) * ldc + col;
                    if (accum) v += *p;
                    *p = v;
                }
            }
        }
    }
}

// ---------------- generic fp32 GEMM: C = act(A*B^T + bias) --------------------
// ACT: 0 none, 2 softplus, 4 tanh+fused-dot (atomicAdd partial dots to avec)
// Split-K via blockIdx.z; accum: 0 store, 2 atomicAdd.
#define BM 64
#define BN 64
#define BKK 32
template<int ACT>
__global__ __launch_bounds__(256) void gemm_nt(
    const float* __restrict__ A, int lda,
    const float* __restrict__ B, int ldb,
    float* __restrict__ C, int ldc,
    const float* __restrict__ bias,
    int M, int N, int K, int kchunk, int accum,
    const float* __restrict__ w2, float* __restrict__ avec)
{
    __shared__ float As[BKK][BM + 4];
    __shared__ float Bs[BKK][BN + 4];
    int tid = threadIdx.x;
    int m0 = blockIdx.y * BM;
    int n0 = blockIdx.x * BN;
    int tx = tid & 15, ty = tid >> 4;
    float acc[4][4] = {};
    int arow = tid >> 3;       // 0..31
    int ak = (tid & 7) * 4;    // 0..28
    int kb = blockIdx.z * kchunk;
    int ke = min(K, kb + kchunk);

    for (int k0 = kb; k0 < ke; k0 += BKK) {
#pragma unroll
        for (int r = 0; r < 2; ++r) {
            int row = arow + r * 32;
            float4 va = *(const float4*)(A + (size_t)(m0 + row) * lda + k0 + ak);
            As[ak + 0][row] = va.x; As[ak + 1][row] = va.y;
            As[ak + 2][row] = va.z; As[ak + 3][row] = va.w;
            float4 vb = *(const float4*)(B + (size_t)(n0 + row) * ldb + k0 + ak);
            Bs[ak + 0][row] = vb.x; Bs[ak + 1][row] = vb.y;
            Bs[ak + 2][row] = vb.z; Bs[ak + 3][row] = vb.w;
        }
        __syncthreads();
#pragma unroll
        for (int kk = 0; kk < BKK; ++kk) {
            float4 a4 = *(const float4*)&As[kk][ty * 4];
            float4 b4 = *(const float4*)&Bs[kk][tx * 4];
            float a[4] = {a4.x, a4.y, a4.z, a4.w};
            float b[4] = {b4.x, b4.y, b4.z, b4.w};
#pragma unroll
            for (int i = 0; i < 4; ++i)
#pragma unroll
                for (int j = 0; j < 4; ++j)
                    acc[i][j] = fmaf(a[i], b[j], acc[i][j]);
        }
        __syncthreads();
    }

#pragma unroll
    for (int i = 0; i < 4; ++i) {
        int row = m0 + ty * 4 + i;
        int col = n0 + tx * 4;
        if (ACT == 4) {
            float part = 0.f;
#pragma unroll
            for (int j = 0; j < 4; ++j) {
                float xv = tanhf(acc[i][j] + bias[col + j]);
                part = fmaf(xv, w2[col + j], part);
            }
            atomicAdd(&avec[row], part);
            continue;
        }
        float* cp = C + (size_t)row * ldc + col;
        if (accum == 2) {
#pragma unroll
            for (int j = 0; j < 4; ++j) atomicAdd(cp + j, acc[i][j]);
            continue;
        }
#pragma unroll
        for (int j = 0; j < 4; ++j) {
            float xv = acc[i][j] + (bias ? bias[col + j] : 0.f);
            if (ACT == 2) xv = (xv > 20.f) ? xv : log1pf(__expf(xv));
            cp[j] = xv;
        }
    }
}

// ---------------- layernorm (D=512); optional fp16 side-out; optional avec init
__global__ __launch_bounds__(256) void layernorm_k(
    const float* __restrict__ x, const float* __restrict__ w,
    const float* __restrict__ b, float* __restrict__ o,
    _Float16* __restrict__ oh, float* __restrict__ avec,
    const float* __restrict__ b2)
{
    int row = blockIdx.x;
    int tid = threadIdx.x;
    const float* xr = x + (size_t)row * DM;
    float v0 = xr[tid], v1 = xr[tid + 256];
    float s = v0 + v1, ss = v0 * v0 + v1 * v1;
    for (int off = 32; off; off >>= 1) {
        s += __shfl_down(s, off, 64);
        ss += __shfl_down(ss, off, 64);
    }
    __shared__ float sm[4], sm2[4];
    int wave = tid >> 6, lane = tid & 63;
    if (lane == 0) { sm[wave] = s; sm2[wave] = ss; }
    __syncthreads();
    float tot = sm[0] + sm[1] + sm[2] + sm[3];
    float tot2 = sm2[0] + sm2[1] + sm2[2] + sm2[3];
    float mu = tot * (1.f / DM);
    float var = tot2 * (1.f / DM) - mu * mu;
    float rs = rsqrtf(var + 1e-5f);
    float y0 = (v0 - mu) * rs * w[tid] + b[tid];
    float y1 = (v1 - mu) * rs * w[tid + 256] + b[tid + 256];
    o[(size_t)row * DM + tid] = y0;
    o[(size_t)row * DM + tid + 256] = y1;
    if (oh) {
        oh[(size_t)row * DM + tid] = (_Float16)y0;
        oh[(size_t)row * DM + tid + 256] = (_Float16)y1;
    }
    if (avec && tid == 0) avec[row] = b2[0];
}

// ---------------- permuted causal conv (K=4) + SiLU; also zeroes dbl ----------
__global__ __launch_bounds__(256) void conv_silu_k(
    const _Float16* __restrict__ xz, const int* __restrict__ perm,
    const float* __restrict__ cw, const float* __restrict__ cb,
    float* __restrict__ xc, float* __restrict__ dbl)
{
    if (blockIdx.x < 256) {   // zero dbl (L*64 floats) for the split-K atomics
        int zi = (blockIdx.x * 256 + threadIdx.x) * 4;
        *(float4*)(dbl + zi) = make_float4(0.f, 0.f, 0.f, 0.f);
    }
    int g = blockIdx.x * 256 + threadIdx.x;   // g < L*DI
    int c = g & (DI - 1), p = g >> 10;
    float acc = cb[c];
#pragma unroll
    for (int k = 0; k < 4; ++k) {
        int q = p + k - 3;
        if (q >= 0)
            acc = fmaf((float)xz[(size_t)perm[q] * (2 * DI) + c], cw[c * 4 + k], acc);
    }
    float sig = 1.f / (1.f + __expf(-acc));
    xc[g] = acc * sig;
}

// ---------------- chunked parallel selective scan ----------------
// One thread per (channel, chunk); 16 states in registers. NCH=256 chunks ->
// 1024 blocks = 4 blocks/CU for latency hiding.
__global__ __launch_bounds__(256) void scan_pass1(
    const float* __restrict__ dt, const float* __restrict__ u,
    const float* __restrict__ dbl, const float* __restrict__ A_log,
    float* __restrict__ Aprod, float* __restrict__ carry)
{
    int c = blockIdx.x * 256 + threadIdx.x;
    int j = blockIdx.y;
    float Ac[16];
#pragma unroll
    for (int s = 0; s < 16; ++s) Ac[s] = -__expf(A_log[c * DS + s]);
    float ap[16], h[16];
#pragma unroll
    for (int s = 0; s < 16; ++s) { ap[s] = 1.f; h[s] = 0.f; }
    int t0 = j * CHK;
    for (int tt = 0; tt < CHK; ++tt) {
        int t = t0 + tt;
        float dtv = dt[(size_t)t * DI + c];
        float uv  = u[(size_t)t * DI + c];
        v4f Bv[4];
#pragma unroll
        for (int q = 0; q < 4; ++q)
            Bv[q] = *(const v4f*)(dbl + (size_t)t * 64 + DTR + q * 4);
        float du = dtv * uv;
#pragma unroll
        for (int s = 0; s < 16; ++s) {
            float dA = __expf(dtv * Ac[s]);
            h[s] = fmaf(dA, h[s], du * Bv[s >> 2][s & 3]);
            ap[s] *= dA;
        }
    }
    size_t base = ((size_t)j * DI + c) * DS;
#pragma unroll
    for (int q = 0; q < 4; ++q) {
        *(v4f*)(Aprod + base + q * 4) = *(v4f*)&ap[q * 4];
        *(v4f*)(carry + base + q * 4) = *(v4f*)&h[q * 4];
    }
}

// Pass 2: exclusive prefix across chunks per (c,s).
__global__ __launch_bounds__(256) void scan_pass2(
    const float* __restrict__ Aprod, const float* __restrict__ carry,
    float* __restrict__ Hin)
{
    int idx = blockIdx.x * 256 + threadIdx.x;  // (c,s) flat, 16384 total
    float H = 0.f;
    Hin[idx] = 0.f;
    for (int j = 1; j < NCH; ++j) {
        H = fmaf(Aprod[(size_t)(j - 1) * (DI * DS) + idx], H,
                 carry[(size_t)(j - 1) * (DI * DS) + idx]);
        Hin[(size_t)j * (DI * DS) + idx] = H;
    }
}

// Pass 3: seeded local scan; gated output scattered, fp16 for out_proj.
__global__ __launch_bounds__(256) void scan_pass3(
    const float* __restrict__ dt, const float* __restrict__ u,
    const float* __restrict__ dbl, const _Float16* __restrict__ xz,
    const float* __restrict__ A_log, const float* __restrict__ Dsk,
    const int* __restrict__ perm, const float* __restrict__ Hin,
    _Float16* __restrict__ yo)
{
    int c = blockIdx.x * 256 + threadIdx.x;
    int j = blockIdx.y;
    float Ac[16];
#pragma unroll
    for (int s = 0; s < 16; ++s) Ac[s] = -__expf(A_log[c * DS + s]);
    float Dp = Dsk[c];
    float h[16];
    size_t hbase = ((size_t)j * DI + c) * DS;
#pragma unroll
    for (int q = 0; q < 4; ++q)
        *(v4f*)&h[q * 4] = *(const v4f*)(Hin + hbase + q * 4);
    int t0 = j * CHK;
    for (int tt = 0; tt < CHK; ++tt) {
        int t = t0 + tt;
        float dtv = dt[(size_t)t * DI + c];
        float uv  = u[(size_t)t * DI + c];
        v4f Bv[4], Cv[4];
#pragma unroll
        for (int q = 0; q < 4; ++q) {
            Bv[q] = *(const v4f*)(dbl + (size_t)t * 64 + DTR + q * 4);
            Cv[q] = *(const v4f*)(dbl + (size_t)t * 64 + DTR + DS + q * 4);
        }
        float du = dtv * uv;
        float y = 0.f;
#pragma unroll
        for (int s = 0; s < 16; ++s) {
            float dA = __expf(dtv * Ac[s]);
            h[s] = fmaf(dA, h[s], du * Bv[s >> 2][s & 3]);
            y = fmaf(h[s], Cv[s >> 2][s & 3], y);
        }
        int tp = perm[t];
        float z = (float)xz[(size_t)tp * (2 * DI) + DI + c];
        float sig = 1.f / (1.f + __expf(-z));
        yo[(size_t)tp * DI + c] = (_Float16)((y + uv * Dp) * (z * sig));
    }
}

// ---------------- softmax over 4096 (single block); zeroes pooled -------------
__global__ __launch_bounds__(1024) void softmax_k(
    const float* __restrict__ a, float* __restrict__ out,
    float* __restrict__ pooled)
{
    int tid = threadIdx.x;
    if (tid < DM) pooled[tid] = 0.f;
    float v[4];
    float mx = -1e30f;
#pragma unroll
    for (int i = 0; i < 4; ++i) { v[i] = a[tid + i * 1024]; mx = fmaxf(mx, v[i]); }
    __shared__ float sm[16];
    for (int off = 32; off; off >>= 1) mx = fmaxf(mx, __shfl_xor(mx, off, 64));
    int wave = tid >> 6, lane = tid & 63;
    if (lane == 0) sm[wave] = mx;
    __syncthreads();
    if (tid < 16) {
        float m = sm[tid];
        for (int off = 8; off; off >>= 1) m = fmaxf(m, __shfl_xor(m, off, 64));
        sm[tid] = m;
    }
    __syncthreads();
    mx = sm[0];
    float s = 0.f;
#pragma unroll
    for (int i = 0; i < 4; ++i) { v[i] = __expf(v[i] - mx); s += v[i]; }
    for (int off = 32; off; off >>= 1) s += __shfl_xor(s, off, 64);
    __syncthreads();
    if (lane == 0) sm[wave] = s;
    __syncthreads();
    if (tid < 16) {
        float t2 = sm[tid];
        for (int off = 8; off; off >>= 1) t2 += __shfl_xor(t2, off, 64);
        sm[tid] = t2;
    }
    __syncthreads();
    float inv = 1.f / sm[0];
#pragma unroll
    for (int i = 0; i < 4; ++i) out[tid + i * 1024] = v[i] * inv;
}

__global__ __launch_bounds__(512) void pool_k(
    const float* __restrict__ aatt, const float* __restrict__ h,
    float* __restrict__ pooled)
{
    int m = threadIdx.x;
    int t0 = blockIdx.x * 128;
    float acc = 0.f;
    for (int r = 0; r < 128; ++r) {
        int t = t0 + r;
        acc = fmaf(aatt[t], h[(size_t)t * DM + m], acc);
    }
    atomicAdd(&pooled[m], acc);
}

__global__ __launch_bounds__(64) void out2048_k(
    const float* __restrict__ pooled, const float* __restrict__ w,
    const float* __restrict__ b, float* __restrict__ out)
{
    int n = blockIdx.x;
    int lane = threadIdx.x;
    const float* wr = w + (size_t)n * DM;
    float acc = 0.f;
#pragma unroll
    for (int k = 0; k < 8; ++k)
        acc = fmaf(wr[lane + k * 64], pooled[lane + k * 64], acc);
    for (int off = 32; off; off >>= 1) acc += __shfl_xor(acc, off, 64);
    if (lane == 0) out[n] = acc + b[n];
}

extern "C" void kernel_launch(void* const* d_in, const int* in_sizes, int n_in,
                              void* d_out, int out_size, void* d_ws, size_t ws_size,
                              hipStream_t stream) {
    const float* x     = (const float*)d_in[0];
    const int*   rate  = (const int*)d_in[1];
    const float* fc1_w = (const float*)d_in[2];
    const float* fc1_b = (const float*)d_in[3];
    const float* ln_w  = (const float*)d_in[4];
    const float* ln_b  = (const float*)d_in[5];
    const float* ipw   = (const float*)d_in[6];
    const float* cw    = (const float*)d_in[7];
    const float* cb    = (const float*)d_in[8];
    const float* xpw   = (const float*)d_in[9];
    const float* dtw   = (const float*)d_in[10];
    const float* dtpb  = (const float*)d_in[11];
    const float* A_log = (const float*)d_in[12];
    const float* Dsk   = (const float*)d_in[13];
    const float* opw   = (const float*)d_in[14];
    const float* nw    = (const float*)d_in[15];
    const float* nb    = (const float*)d_in[16];
    const float* aw1   = (const float*)d_in[17];
    const float* ab1   = (const float*)d_in[18];
    const float* aw2   = (const float*)d_in[19];
    const float* ab2   = (const float*)d_in[20];
    const float* ow    = (const float*)d_in[21];
    const float* ob    = (const float*)d_in[22];
    float* out = (float*)d_out;

    int* perm = (int*)d_ws;
    float* f = (float*)d_ws + 4096;
    float* h    = f; f += (size_t)L * DM;
    float* hln  = f; f += (size_t)L * DM;
    float* xc   = f; f += (size_t)L * DI;
    float* dbl  = f; f += (size_t)L * 64;
    float* dtv  = f; f += (size_t)L * DI;
    float* avec = f; f += L;
    float* pooled = f; f += DM;
    float* Aprod = f; f += (size_t)NCH * DI * DS;
    float* carry = f; f += (size_t)NCH * DI * DS;
    float* Hin   = f; f += (size_t)NCH * DI * DS;
    _Float16* fh = (_Float16*)f;
    _Float16* xh     = fh; fh += (size_t)L * DIN;
    _Float16* hln_h  = fh; fh += (size_t)L * DM;
    _Float16* yo_h   = fh; fh += (size_t)L * DI;
    _Float16* xz_h   = fh; fh += (size_t)L * 2 * DI;
    _Float16* fc1w_h = fh; fh += (size_t)DM * DIN;
    _Float16* ipw_h  = fh; fh += (size_t)2 * 2 * DI * DM;
    _Float16* opw_h  = fh; fh += (size_t)2 * DM * DI;

    perm_k<<<16, 256, 0, stream>>>(perm, rate);

    // all fp32->fp16 conversions in a single launch
    f2h_multi_k<<<(L * DIN + DM * DIN + 2 * 2 * DI * DM + 2 * DM * DI) / 1024,
                  256, 0, stream>>>(
        x, xh, L * DIN / 1024,
        fc1_w, fc1w_h, DM * DIN / 1024,
        ipw, ipw_h, 2 * 2 * DI * DM / 1024,
        opw, opw_h, 2 * DM * DI / 1024);

    // h = relu(x @ fc1_w^T + fc1_b)   [fp16 MFMA, N64 tile -> 256 blocks]
    hgemm_nt<1, 64, 0><<<dim3(DM / 64, L / 128), 256, 0, stream>>>(
        xh, DIN, fc1w_h, DIN, h, DM, fc1_b, DIN, 0);

    for (int l = 0; l < 2; ++l) {
        layernorm_k<<<L, 256, 0, stream>>>(h, ln_w + l * DM, ln_b + l * DM,
                                           hln, hln_h, nullptr, nullptr);
        // xz = hln @ in_proj^T   [fp16 MFMA -> fp16 out, 512 blocks]
        hgemm_nt<0, 128, 1><<<dim3(2 * DI / 128, L / 128), 256, 0, stream>>>(
            hln_h, DM, ipw_h + (size_t)l * 2 * DI * DM, DM, xz_h, 2 * DI,
            nullptr, DM, 0);
        // xc = silu(causal_conv(x_perm)); also zeroes dbl for split-K atomics
        conv_silu_k<<<L * DI / 256, 256, 0, stream>>>(
            xz_h, perm, cw + (size_t)l * DI * 4, cb + (size_t)l * DI, xc, dbl);
        // dbl = xc @ x_proj^T  (N=64; split-K x4 for occupancy, atomic partials)
        gemm_nt<0><<<dim3(1, L / 64, 4), 256, 0, stream>>>(
            xc, DI, xpw + (size_t)l * 64 * DI, DI, dbl, 64, nullptr,
            L, 64, DI, DI / 4, 2, nullptr, nullptr);
        // dt = softplus(dbl[:, :32] @ dt_proj^T + dtb)  (K=32, 1024 blocks)
        gemm_nt<2><<<dim3(DI / 64, L / 64), 256, 0, stream>>>(
            dbl, 64, dtw + (size_t)l * DI * DTR, DTR, dtv, DI,
            dtpb + (size_t)l * DI, L, DI, DTR, DTR, 0, nullptr, nullptr);
        // chunked parallel selective scan (256 chunks -> 1024 blocks)
        scan_pass1<<<dim3(DI / 256, NCH), 256, 0, stream>>>(
            dtv, xc, dbl, A_log + (size_t)l * DI * DS, Aprod, carry);
        scan_pass2<<<DI * DS / 256, 256, 0, stream>>>(Aprod, carry, Hin);
        scan_pass3<<<dim3(DI / 256, NCH), 256, 0, stream>>>(
            dtv, xc, dbl, xz_h, A_log + (size_t)l * DI * DS,
            Dsk + (size_t)l * DI, perm, Hin, yo_h);
        // h += yo @ out_proj^T   [fp16 MFMA, N64 tile -> 256 blocks, accumulate]
        hgemm_nt<0, 64, 0><<<dim3(DM / 64, L / 128), 256, 0, stream>>>(
            yo_h, DI, opw_h + (size_t)l * DM * DI, DI, h, DM, nullptr, DI, 1);
    }

    // final LN (also seeds avec with attn bias b2)
    layernorm_k<<<L, 256, 0, stream>>>(h, nw, nb, hln, nullptr, avec, ab2);
    // fused: avec += tanh(hln @ aw1^T + ab1) . w2   (t1 never materialized)
    gemm_nt<4><<<dim3(128 / 64, L / 64), 256, 0, stream>>>(
        hln, DM, aw1, DM, nullptr, 0, ab1, L, 128, DM, DM, 0, aw2, avec);
    softmax_k<<<1, 1024, 0, stream>>>(avec, out + 2048, pooled);
    pool_k<<<32, 512, 0, stream>>>(out + 2048, hln, pooled);
    out2048_k<<<2048, 64, 0, stream>>>(pooled, ow, ob, out);
}

// Round 10
// 567.381 us; speedup vs baseline: 1.0928x; 1.0376x over previous
//
#include <hip/hip_runtime.h>
#include <hip/hip_fp16.h>
#include <math.h>

#define L 4096
#define DIN 1024
#define DM 512
#define DI 1024
#define DS 16
#define DTR 32
#define NCH 256
#define CHK 16   // NCH*CHK == L

typedef _Float16 v8h __attribute__((ext_vector_type(8)));
typedef float v4f __attribute__((ext_vector_type(4)));

// ---------------- perm table ----------------
__global__ void perm_k(int* __restrict__ perm, const int* __restrict__ ratep) {
    int p = blockIdx.x * blockDim.x + threadIdx.x;
    if (p >= L) return;
    int rate = ratep[0];
    int cum = 0;
    for (int g = 0; g < rate; ++g) {
        int sz = (L - g + rate - 1) / rate;
        if (p < cum + sz) { perm[p] = g + rate * (p - cum); return; }
        cum += sz;
    }
}

// ---------------- fp32 -> fp16 convert, 5 segments in one launch --------------
__global__ __launch_bounds__(256) void f2h_multi_k(
    const float* __restrict__ s0, _Float16* __restrict__ d0, int b0,
    const float* __restrict__ s1, _Float16* __restrict__ d1, int b1,
    const float* __restrict__ s2, _Float16* __restrict__ d2, int b2,
    const float* __restrict__ s3, _Float16* __restrict__ d3, int b3,
    const float* __restrict__ s4, _Float16* __restrict__ d4, int b4)
{
    int b = blockIdx.x;
    const float* src; _Float16* dst; int lb;
    if (b < b0)                     { src = s0; dst = d0; lb = b; }
    else if (b < b0 + b1)           { src = s1; dst = d1; lb = b - b0; }
    else if (b < b0 + b1 + b2)      { src = s2; dst = d2; lb = b - b0 - b1; }
    else if (b < b0 + b1 + b2 + b3) { src = s3; dst = d3; lb = b - b0 - b1 - b2; }
    else                            { src = s4; dst = d4; lb = b - b0 - b1 - b2 - b3; }
    int i = (lb * 256 + threadIdx.x) * 4;
    float4 v = *(const float4*)(src + i);
    _Float16 h4[4] = {(_Float16)v.x, (_Float16)v.y, (_Float16)v.z, (_Float16)v.w};
    *(uint2*)(dst + i) = *(uint2*)h4;
}

// ---------------- fp16 MFMA GEMM (reg prefetch, padded LDS) -------------------
// C = act(A(MxK)*B(NxK)^T + bias) [+C]. BNT=128: 4 waves 64x64; BNT=64: 4 waves
// 32x64 (2x grid for N=512). HALF=1: store C as fp16 (no accum).
template<int ACT, int BNT, int HALF>   // ACT: 0 none, 1 relu
__global__ __launch_bounds__(256) void hgemm_nt(
    const _Float16* __restrict__ A, int lda,
    const _Float16* __restrict__ B, int ldb,
    void* __restrict__ Cv, int ldc,
    const float* __restrict__ bias, int K, int accum)
{
    constexpr int MI = (BNT == 128) ? 4 : 2;
    __shared__ _Float16 As[128][40];   // pad 32->40: 2-way bank alias only (free)
    __shared__ _Float16 Bs[BNT][40];
    int tid = threadIdx.x;
    int m0 = blockIdx.y * 128, n0 = blockIdx.x * BNT;
    int lane = tid & 63, wave = tid >> 6;
    int wm, wn;
    if constexpr (BNT == 128) { wm = (wave >> 1) * 64; wn = (wave & 1) * 64; }
    else                      { wm = wave * 32;        wn = 0; }
    int quad = lane >> 4, r16 = lane & 15;
    v4f acc[MI][4] = {};

    int srow = tid >> 1;            // 0..127
    int scol = (tid & 1) * 16;      // 0 or 16
    const _Float16* Ag = A + (size_t)(m0 + srow) * lda + scol;
    int srowB = (BNT == 128) ? srow : (tid >> 2);
    int scolB = (BNT == 128) ? scol : (tid & 3) * 8;
    const _Float16* Bg = B + (size_t)(n0 + srowB) * ldb + scolB;

    uint4 a0, a1, b0, b1;
    a0 = *(const uint4*)(Ag);
    a1 = *(const uint4*)(Ag + 8);
    b0 = *(const uint4*)(Bg);
    if constexpr (BNT == 128) b1 = *(const uint4*)(Bg + 8);

    int KS = K / 32;
    for (int ks = 0; ks < KS; ++ks) {
        __syncthreads();
        *(uint4*)&As[srow][scol] = a0;
        *(uint4*)&As[srow][scol + 8] = a1;
        *(uint4*)&Bs[srowB][scolB] = b0;
        if constexpr (BNT == 128) *(uint4*)&Bs[srowB][scolB + 8] = b1;
        __syncthreads();
        if (ks + 1 < KS) {
            int k0 = (ks + 1) * 32;
            a0 = *(const uint4*)(Ag + k0);
            a1 = *(const uint4*)(Ag + k0 + 8);
            b0 = *(const uint4*)(Bg + k0);
            if constexpr (BNT == 128) b1 = *(const uint4*)(Bg + k0 + 8);
        }
        v8h af[MI], bf[4];
#pragma unroll
        for (int i = 0; i < MI; ++i)
            af[i] = *(const v8h*)&As[wm + i * 16 + r16][quad * 8];
#pragma unroll
        for (int j = 0; j < 4; ++j)
            bf[j] = *(const v8h*)&Bs[wn + j * 16 + r16][quad * 8];
#pragma unroll
        for (int i = 0; i < MI; ++i)
#pragma unroll
            for (int j = 0; j < 4; ++j)
                acc[i][j] = __builtin_amdgcn_mfma_f32_16x16x32_f16(
                    af[i], bf[j], acc[i][j], 0, 0, 0);
    }

    // C/D layout: col = lane&15, row = (lane>>4)*4 + reg
#pragma unroll
    for (int i = 0; i < MI; ++i) {
#pragma unroll
        for (int j = 0; j < 4; ++j) {
            int col = n0 + wn + j * 16 + r16;
            int rbase = m0 + wm + i * 16 + quad * 4;
            float bv = bias ? bias[col] : 0.f;
#pragma unroll
            for (int r = 0; r < 4; ++r) {
                float v = acc[i][j][r] + bv;
                if (ACT == 1) v = fmaxf(v, 0.f);
                if constexpr (HALF) {
                    ((_Float16*)Cv)[(size_t)(rbase + r) * ldc + col] = (_Float16)v;
                } else {
                    float* p = (float*)Cv + (size_t)(rbase + r) * ldc + col;
                    if (accum) v += *p;
                    *p = v;
                }
            }
        }
    }
}

// ---------------- x_proj fp16 MFMA split-K: dbl += xc_h @ xpw_h^T -------------
// M=4096 (tile 128), N=64 (full), K=1024 split 8x128 -> 256 blocks.
// fp32 atomicAdd epilogue into pre-zeroed dbl.
__global__ __launch_bounds__(256) void hgemm_xproj(
    const _Float16* __restrict__ A,    // xc_h, lda=DI
    const _Float16* __restrict__ B,    // xpw_h (64 x DI)
    float* __restrict__ C)             // dbl, ldc=64
{
    __shared__ _Float16 As[128][40];
    __shared__ _Float16 Bs[64][40];
    int tid = threadIdx.x;
    int m0 = blockIdx.y * 128;
    int kb = blockIdx.z * 128;
    int lane = tid & 63, wave = tid >> 6;
    int wm = wave * 32;
    int quad = lane >> 4, r16 = lane & 15;
    v4f acc[2][4] = {};

    int srow = tid >> 1, scol = (tid & 1) * 16;
    const _Float16* Ag = A + (size_t)(m0 + srow) * DI + kb + scol;
    int srowB = tid >> 2, scolB = (tid & 3) * 8;
    const _Float16* Bg = B + (size_t)srowB * DI + kb + scolB;

    uint4 a0 = *(const uint4*)(Ag);
    uint4 a1 = *(const uint4*)(Ag + 8);
    uint4 b0 = *(const uint4*)(Bg);

    for (int ks = 0; ks < 4; ++ks) {
        __syncthreads();
        *(uint4*)&As[srow][scol] = a0;
        *(uint4*)&As[srow][scol + 8] = a1;
        *(uint4*)&Bs[srowB][scolB] = b0;
        __syncthreads();
        if (ks + 1 < 4) {
            int k0 = (ks + 1) * 32;
            a0 = *(const uint4*)(Ag + k0);
            a1 = *(const uint4*)(Ag + k0 + 8);
            b0 = *(const uint4*)(Bg + k0);
        }
        v8h af[2], bf[4];
#pragma unroll
        for (int i = 0; i < 2; ++i)
            af[i] = *(const v8h*)&As[wm + i * 16 + r16][quad * 8];
#pragma unroll
        for (int j = 0; j < 4; ++j)
            bf[j] = *(const v8h*)&Bs[j * 16 + r16][quad * 8];
#pragma unroll
        for (int i = 0; i < 2; ++i)
#pragma unroll
            for (int j = 0; j < 4; ++j)
                acc[i][j] = __builtin_amdgcn_mfma_f32_16x16x32_f16(
                    af[i], bf[j], acc[i][j], 0, 0, 0);
    }
#pragma unroll
    for (int i = 0; i < 2; ++i) {
#pragma unroll
        for (int j = 0; j < 4; ++j) {
            int col = j * 16 + r16;
            int rbase = m0 + wm + i * 16 + quad * 4;
#pragma unroll
            for (int r = 0; r < 4; ++r)
                atomicAdd(&C[(size_t)(rbase + r) * 64 + col], acc[i][j][r]);
        }
    }
}

// ---------------- generic fp32 GEMM: C = act(A*B^T + bias) --------------------
// ACT: 2 softplus, 4 tanh+fused-dot (atomicAdd partial dots to avec)
#define BM 64
#define BN 64
#define BKK 32
template<int ACT>
__global__ __launch_bounds__(256) void gemm_nt(
    const float* __restrict__ A, int lda,
    const float* __restrict__ B, int ldb,
    float* __restrict__ C, int ldc,
    const float* __restrict__ bias,
    int M, int N, int K,
    const float* __restrict__ w2, float* __restrict__ avec)
{
    __shared__ float As[BKK][BM + 4];
    __shared__ float Bs[BKK][BN + 4];
    int tid = threadIdx.x;
    int m0 = blockIdx.y * BM;
    int n0 = blockIdx.x * BN;
    int tx = tid & 15, ty = tid >> 4;
    float acc[4][4] = {};
    int arow = tid >> 3;       // 0..31
    int ak = (tid & 7) * 4;    // 0..28

    for (int k0 = 0; k0 < K; k0 += BKK) {
#pragma unroll
        for (int r = 0; r < 2; ++r) {
            int row = arow + r * 32;
            float4 va = *(const float4*)(A + (size_t)(m0 + row) * lda + k0 + ak);
            As[ak + 0][row] = va.x; As[ak + 1][row] = va.y;
            As[ak + 2][row] = va.z; As[ak + 3][row] = va.w;
            float4 vb = *(const float4*)(B + (size_t)(n0 + row) * ldb + k0 + ak);
            Bs[ak + 0][row] = vb.x; Bs[ak + 1][row] = vb.y;
            Bs[ak + 2][row] = vb.z; Bs[ak + 3][row] = vb.w;
        }
        __syncthreads();
#pragma unroll
        for (int kk = 0; kk < BKK; ++kk) {
            float4 a4 = *(const float4*)&As[kk][ty * 4];
            float4 b4 = *(const float4*)&Bs[kk][tx * 4];
            float a[4] = {a4.x, a4.y, a4.z, a4.w};
            float b[4] = {b4.x, b4.y, b4.z, b4.w};
#pragma unroll
            for (int i = 0; i < 4; ++i)
#pragma unroll
                for (int j = 0; j < 4; ++j)
                    acc[i][j] = fmaf(a[i], b[j], acc[i][j]);
        }
        __syncthreads();
    }

#pragma unroll
    for (int i = 0; i < 4; ++i) {
        int row = m0 + ty * 4 + i;
        int col = n0 + tx * 4;
        if (ACT == 4) {
            float part = 0.f;
#pragma unroll
            for (int j = 0; j < 4; ++j) {
                float xv = tanhf(acc[i][j] + bias[col + j]);
                part = fmaf(xv, w2[col + j], part);
            }
            atomicAdd(&avec[row], part);
            continue;
        }
        float* cp = C + (size_t)row * ldc + col;
#pragma unroll
        for (int j = 0; j < 4; ++j) {
            float xv = acc[i][j] + (bias ? bias[col + j] : 0.f);
            if (ACT == 2) xv = (xv > 20.f) ? xv : log1pf(__expf(xv));
            cp[j] = xv;
        }
    }
}

// ---------------- layernorm (D=512); optional fp16 side-out; optional avec init
__global__ __launch_bounds__(256) void layernorm_k(
    const float* __restrict__ x, const float* __restrict__ w,
    const float* __restrict__ b, float* __restrict__ o,
    _Float16* __restrict__ oh, float* __restrict__ avec,
    const float* __restrict__ b2)
{
    int row = blockIdx.x;
    int tid = threadIdx.x;
    const float* xr = x + (size_t)row * DM;
    float v0 = xr[tid], v1 = xr[tid + 256];
    float s = v0 + v1, ss = v0 * v0 + v1 * v1;
    for (int off = 32; off; off >>= 1) {
        s += __shfl_down(s, off, 64);
        ss += __shfl_down(ss, off, 64);
    }
    __shared__ float sm[4], sm2[4];
    int wave = tid >> 6, lane = tid & 63;
    if (lane == 0) { sm[wave] = s; sm2[wave] = ss; }
    __syncthreads();
    float tot = sm[0] + sm[1] + sm[2] + sm[3];
    float tot2 = sm2[0] + sm2[1] + sm2[2] + sm2[3];
    float mu = tot * (1.f / DM);
    float var = tot2 * (1.f / DM) - mu * mu;
    float rs = rsqrtf(var + 1e-5f);
    float y0 = (v0 - mu) * rs * w[tid] + b[tid];
    float y1 = (v1 - mu) * rs * w[tid + 256] + b[tid + 256];
    o[(size_t)row * DM + tid] = y0;
    o[(size_t)row * DM + tid + 256] = y1;
    if (oh) {
        oh[(size_t)row * DM + tid] = (_Float16)y0;
        oh[(size_t)row * DM + tid + 256] = (_Float16)y1;
    }
    if (avec && tid == 0) avec[row] = b2[0];
}

// ---------------- permuted causal conv (K=4) + SiLU; fp16 out; zeroes dbl -----
__global__ __launch_bounds__(256) void conv_silu_k(
    const _Float16* __restrict__ xz, const int* __restrict__ perm,
    const float* __restrict__ cw, const float* __restrict__ cb,
    _Float16* __restrict__ xc, float* __restrict__ dbl)
{
    if (blockIdx.x < 256) {   // zero dbl (L*64 floats) for the split-K atomics
        int zi = (blockIdx.x * 256 + threadIdx.x) * 4;
        *(float4*)(dbl + zi) = make_float4(0.f, 0.f, 0.f, 0.f);
    }
    int g = blockIdx.x * 256 + threadIdx.x;   // g < L*DI
    int c = g & (DI - 1), p = g >> 10;
    float acc = cb[c];
#pragma unroll
    for (int k = 0; k < 4; ++k) {
        int q = p + k - 3;
        if (q >= 0)
            acc = fmaf((float)xz[(size_t)perm[q] * (2 * DI) + c], cw[c * 4 + k], acc);
    }
    float sig = 1.f / (1.f + __expf(-acc));
    xc[g] = (_Float16)(acc * sig);
}

// ---------------- chunked parallel selective scan ----------------
// One thread per (channel, chunk); 16 states in registers. NCH=256 chunks ->
// 1024 blocks = 4 blocks/CU for latency hiding. u read as fp16.
__global__ __launch_bounds__(256) void scan_pass1(
    const float* __restrict__ dt, const _Float16* __restrict__ u,
    const float* __restrict__ dbl, const float* __restrict__ A_log,
    float* __restrict__ Aprod, float* __restrict__ carry)
{
    int c = blockIdx.x * 256 + threadIdx.x;
    int j = blockIdx.y;
    float Ac[16];
#pragma unroll
    for (int s = 0; s < 16; ++s) Ac[s] = -__expf(A_log[c * DS + s]);
    float ap[16], h[16];
#pragma unroll
    for (int s = 0; s < 16; ++s) { ap[s] = 1.f; h[s] = 0.f; }
    int t0 = j * CHK;
    for (int tt = 0; tt < CHK; ++tt) {
        int t = t0 + tt;
        float dtv = dt[(size_t)t * DI + c];
        float uv  = (float)u[(size_t)t * DI + c];
        v4f Bv[4];
#pragma unroll
        for (int q = 0; q < 4; ++q)
            Bv[q] = *(const v4f*)(dbl + (size_t)t * 64 + DTR + q * 4);
        float du = dtv * uv;
#pragma unroll
        for (int s = 0; s < 16; ++s) {
            float dA = __expf(dtv * Ac[s]);
            h[s] = fmaf(dA, h[s], du * Bv[s >> 2][s & 3]);
            ap[s] *= dA;
        }
    }
    size_t base = ((size_t)j * DI + c) * DS;
#pragma unroll
    for (int q = 0; q < 4; ++q) {
        *(v4f*)(Aprod + base + q * 4) = *(v4f*)&ap[q * 4];
        *(v4f*)(carry + base + q * 4) = *(v4f*)&h[q * 4];
    }
}

// Pass 2: exclusive prefix across chunks per (c,s).
__global__ __launch_bounds__(256) void scan_pass2(
    const float* __restrict__ Aprod, const float* __restrict__ carry,
    float* __restrict__ Hin)
{
    int idx = blockIdx.x * 256 + threadIdx.x;  // (c,s) flat, 16384 total
    float H = 0.f;
    Hin[idx] = 0.f;
    for (int j = 1; j < NCH; ++j) {
        H = fmaf(Aprod[(size_t)(j - 1) * (DI * DS) + idx], H,
                 carry[(size_t)(j - 1) * (DI * DS) + idx]);
        Hin[(size_t)j * (DI * DS) + idx] = H;
    }
}

// Pass 3: seeded local scan; gated output scattered, fp16 for out_proj.
__global__ __launch_bounds__(256) void scan_pass3(
    const float* __restrict__ dt, const _Float16* __restrict__ u,
    const float* __restrict__ dbl, const _Float16* __restrict__ xz,
    const float* __restrict__ A_log, const float* __restrict__ Dsk,
    const int* __restrict__ perm, const float* __restrict__ Hin,
    _Float16* __restrict__ yo)
{
    int c = blockIdx.x * 256 + threadIdx.x;
    int j = blockIdx.y;
    float Ac[16];
#pragma unroll
    for (int s = 0; s < 16; ++s) Ac[s] = -__expf(A_log[c * DS + s]);
    float Dp = Dsk[c];
    float h[16];
    size_t hbase = ((size_t)j * DI + c) * DS;
#pragma unroll
    for (int q = 0; q < 4; ++q)
        *(v4f*)&h[q * 4] = *(const v4f*)(Hin + hbase + q * 4);
    int t0 = j * CHK;
    for (int tt = 0; tt < CHK; ++tt) {
        int t = t0 + tt;
        float dtv = dt[(size_t)t * DI + c];
        float uv  = (float)u[(size_t)t * DI + c];
        v4f Bv[4], Cv[4];
#pragma unroll
        for (int q = 0; q < 4; ++q) {
            Bv[q] = *(const v4f*)(dbl + (size_t)t * 64 + DTR + q * 4);
            Cv[q] = *(const v4f*)(dbl + (size_t)t * 64 + DTR + DS + q * 4);
        }
        float du = dtv * uv;
        float y = 0.f;
#pragma unroll
        for (int s = 0; s < 16; ++s) {
            float dA = __expf(dtv * Ac[s]);
            h[s] = fmaf(dA, h[s], du * Bv[s >> 2][s & 3]);
            y = fmaf(h[s], Cv[s >> 2][s & 3], y);
        }
        int tp = perm[t];
        float z = (float)xz[(size_t)tp * (2 * DI) + DI + c];
        float sig = 1.f / (1.f + __expf(-z));
        yo[(size_t)tp * DI + c] = (_Float16)((y + uv * Dp) * (z * sig));
    }
}

// ---------------- softmax over 4096 (single block); zeroes pooled -------------
__global__ __launch_bounds__(1024) void softmax_k(
    const float* __restrict__ a, float* __restrict__ out,
    float* __restrict__ pooled)
{
    int tid = threadIdx.x;
    if (tid < DM) pooled[tid] = 0.f;
    float v[4];
    float mx = -1e30f;
#pragma unroll
    for (int i = 0; i < 4; ++i) { v[i] = a[tid + i * 1024]; mx = fmaxf(mx, v[i]); }
    __shared__ float sm[16];
    for (int off = 32; off; off >>= 1) mx = fmaxf(mx, __shfl_xor(mx, off, 64));
    int wave = tid >> 6, lane = tid & 63;
    if (lane == 0) sm[wave] = mx;
    __syncthreads();
    if (tid < 16) {
        float m = sm[tid];
        for (int off = 8; off; off >>= 1) m = fmaxf(m, __shfl_xor(m, off, 64));
        sm[tid] = m;
    }
    __syncthreads();
    mx = sm[0];
    float s = 0.f;
#pragma unroll
    for (int i = 0; i < 4; ++i) { v[i] = __expf(v[i] - mx); s += v[i]; }
    for (int off = 32; off; off >>= 1) s += __shfl_xor(s, off, 64);
    __syncthreads();
    if (lane == 0) sm[wave] = s;
    __syncthreads();
    if (tid < 16) {
        float t2 = sm[tid];
        for (int off = 8; off; off >>= 1) t2 += __shfl_xor(t2, off, 64);
        sm[tid] = t2;
    }
    __syncthreads();
    float inv = 1.f / sm[0];
#pragma unroll
    for (int i = 0; i < 4; ++i) out[tid + i * 1024] = v[i] * inv;
}

__global__ __launch_bounds__(512) void pool_k(
    const float* __restrict__ aatt, const float* __restrict__ h,
    float* __restrict__ pooled)
{
    int m = threadIdx.x;
    int t0 = blockIdx.x * 128;
    float acc = 0.f;
    for (int r = 0; r < 128; ++r) {
        int t = t0 + r;
        acc = fmaf(aatt[t], h[(size_t)t * DM + m], acc);
    }
    atomicAdd(&pooled[m], acc);
}

__global__ __launch_bounds__(64) void out2048_k(
    const float* __restrict__ pooled, const float* __restrict__ w,
    const float* __restrict__ b, float* __restrict__ out)
{
    int n = blockIdx.x;
    int lane = threadIdx.x;
    const float* wr = w + (size_t)n * DM;
    float acc = 0.f;
#pragma unroll
    for (int k = 0; k < 8; ++k)
        acc = fmaf(wr[lane + k * 64], pooled[lane + k * 64], acc);
    for (int off = 32; off; off >>= 1) acc += __shfl_xor(acc, off, 64);
    if (lane == 0) out[n] = acc + b[n];
}

extern "C" void kernel_launch(void* const* d_in, const int* in_sizes, int n_in,
                              void* d_out, int out_size, void* d_ws, size_t ws_size,
                              hipStream_t stream) {
    const float* x     = (const float*)d_in[0];
    const int*   rate  = (const int*)d_in[1];
    const float* fc1_w = (const float*)d_in[2];
    const float* fc1_b = (const float*)d_in[3];
    const float* ln_w  = (const float*)d_in[4];
    const float* ln_b  = (const float*)d_in[5];
    const float* ipw   = (const float*)d_in[6];
    const float* cw    = (const float*)d_in[7];
    const float* cb    = (const float*)d_in[8];
    const float* xpw   = (const float*)d_in[9];
    const float* dtw   = (const float*)d_in[10];
    const float* dtpb  = (const float*)d_in[11];
    const float* A_log = (const float*)d_in[12];
    const float* Dsk   = (const float*)d_in[13];
    const float* opw   = (const float*)d_in[14];
    const float* nw    = (const float*)d_in[15];
    const float* nb    = (const float*)d_in[16];
    const float* aw1   = (const float*)d_in[17];
    const float* ab1   = (const float*)d_in[18];
    const float* aw2   = (const float*)d_in[19];
    const float* ab2   = (const float*)d_in[20];
    const float* ow    = (const float*)d_in[21];
    const float* ob    = (const float*)d_in[22];
    float* out = (float*)d_out;

    int* perm = (int*)d_ws;
    float* f = (float*)d_ws + 4096;
    float* h    = f; f += (size_t)L * DM;
    float* hln  = f; f += (size_t)L * DM;
    float* dbl  = f; f += (size_t)L * 64;
    float* dtv  = f; f += (size_t)L * DI;
    float* avec = f; f += L;
    float* pooled = f; f += DM;
    float* Aprod = f; f += (size_t)NCH * DI * DS;
    float* carry = f; f += (size_t)NCH * DI * DS;
    float* Hin   = f; f += (size_t)NCH * DI * DS;
    _Float16* fh = (_Float16*)f;
    _Float16* xh     = fh; fh += (size_t)L * DIN;
    _Float16* hln_h  = fh; fh += (size_t)L * DM;
    _Float16* yo_h   = fh; fh += (size_t)L * DI;
    _Float16* xz_h   = fh; fh += (size_t)L * 2 * DI;
    _Float16* xc_h   = fh; fh += (size_t)L * DI;
    _Float16* fc1w_h = fh; fh += (size_t)DM * DIN;
    _Float16* ipw_h  = fh; fh += (size_t)2 * 2 * DI * DM;
    _Float16* opw_h  = fh; fh += (size_t)2 * DM * DI;
    _Float16* xpw_h  = fh; fh += (size_t)2 * 64 * DI;

    perm_k<<<16, 256, 0, stream>>>(perm, rate);

    // all fp32->fp16 conversions in a single launch
    f2h_multi_k<<<(L * DIN + DM * DIN + 2 * 2 * DI * DM + 2 * DM * DI
                   + 2 * 64 * DI) / 1024, 256, 0, stream>>>(
        x, xh, L * DIN / 1024,
        fc1_w, fc1w_h, DM * DIN / 1024,
        ipw, ipw_h, 2 * 2 * DI * DM / 1024,
        opw, opw_h, 2 * DM * DI / 1024,
        xpw, xpw_h, 2 * 64 * DI / 1024);

    // h = relu(x @ fc1_w^T + fc1_b)   [fp16 MFMA, N64 tile -> 256 blocks]
    hgemm_nt<1, 64, 0><<<dim3(DM / 64, L / 128), 256, 0, stream>>>(
        xh, DIN, fc1w_h, DIN, h, DM, fc1_b, DIN, 0);

    for (int l = 0; l < 2; ++l) {
        layernorm_k<<<L, 256, 0, stream>>>(h, ln_w + l * DM, ln_b + l * DM,
                                           hln, hln_h, nullptr, nullptr);
        // xz = hln @ in_proj^T   [fp16 MFMA -> fp16 out, 512 blocks]
        hgemm_nt<0, 128, 1><<<dim3(2 * DI / 128, L / 128), 256, 0, stream>>>(
            hln_h, DM, ipw_h + (size_t)l * 2 * DI * DM, DM, xz_h, 2 * DI,
            nullptr, DM, 0);
        // xc = silu(causal_conv(x_perm)) -> fp16; also zeroes dbl
        conv_silu_k<<<L * DI / 256, 256, 0, stream>>>(
            xz_h, perm, cw + (size_t)l * DI * 4, cb + (size_t)l * DI, xc_h, dbl);
        // dbl += xc_h @ xpw_h^T  [fp16 MFMA split-K 8 -> 256 blocks]
        hgemm_xproj<<<dim3(1, L / 128, 8), 256, 0, stream>>>(
            xc_h, xpw_h + (size_t)l * 64 * DI, dbl);
        // dt = softplus(dbl[:, :32] @ dt_proj^T + dtb)  (K=32, 1024 blocks)
        gemm_nt<2><<<dim3(DI / 64, L / 64), 256, 0, stream>>>(
            dbl, 64, dtw + (size_t)l * DI * DTR, DTR, dtv, DI,
            dtpb + (size_t)l * DI, L, DI, DTR, nullptr, nullptr);
        // chunked parallel selective scan (256 chunks -> 1024 blocks)
        scan_pass1<<<dim3(DI / 256, NCH), 256, 0, stream>>>(
            dtv, xc_h, dbl, A_log + (size_t)l * DI * DS, Aprod, carry);
        scan_pass2<<<DI * DS / 256, 256, 0, stream>>>(Aprod, carry, Hin);
        scan_pass3<<<dim3(DI / 256, NCH), 256, 0, stream>>>(
            dtv, xc_h, dbl, xz_h, A_log + (size_t)l * DI * DS,
            Dsk + (size_t)l * DI, perm, Hin, yo_h);
        // h += yo @ out_proj^T   [fp16 MFMA, N64 tile -> 256 blocks, accumulate]
        hgemm_nt<0, 64, 0><<<dim3(DM / 64, L / 128), 256, 0, stream>>>(
            yo_h, DI, opw_h + (size_t)l * DM * DI, DI, h, DM, nullptr, DI, 1);
    }

    // final LN (also seeds avec with attn bias b2)
    layernorm_k<<<L, 256, 0, stream>>>(h, nw, nb, hln, nullptr, avec, ab2);
    // fused: avec += tanh(hln @ aw1^T + ab1) . w2   (t1 never materialized)
    gemm_nt<4><<<dim3(128 / 64, L / 64), 256, 0, stream>>>(
        hln, DM, aw1, DM, nullptr, 0, ab1, L, 128, DM, aw2, avec);
    softmax_k<<<1, 1024, 0, stream>>>(avec, out + 2048, pooled);
    pool_k<<<32, 512, 0, stream>>>(out + 2048, hln, pooled);
    out2048_k<<<2048, 64, 0, stream>>>(pooled, ow, ob, out);
}

// Round 11
// 536.383 us; speedup vs baseline: 1.1559x; 1.0578x over previous
//
#include <hip/hip_runtime.h>
#include <hip/hip_fp16.h>
#include <math.h>

#define L 4096
#define DIN 1024
#define DM 512
#define DI 1024
#define DS 16
#define DTR 32
#define NCH 256
#define CHK 16   // NCH*CHK == L

typedef _Float16 v8h __attribute__((ext_vector_type(8)));
typedef float v4f __attribute__((ext_vector_type(4)));

// ---------------- perm table ----------------
__global__ void perm_k(int* __restrict__ perm, const int* __restrict__ ratep) {
    int p = blockIdx.x * blockDim.x + threadIdx.x;
    if (p >= L) return;
    int rate = ratep[0];
    int cum = 0;
    for (int g = 0; g < rate; ++g) {
        int sz = (L - g + rate - 1) / rate;
        if (p < cum + sz) { perm[p] = g + rate * (p - cum); return; }
        cum += sz;
    }
}

// ---------------- fp32 -> fp16 convert, 6 segments in one launch --------------
__global__ __launch_bounds__(256) void f2h_multi_k(
    const float* __restrict__ s0, _Float16* __restrict__ d0, int b0,
    const float* __restrict__ s1, _Float16* __restrict__ d1, int b1,
    const float* __restrict__ s2, _Float16* __restrict__ d2, int b2,
    const float* __restrict__ s3, _Float16* __restrict__ d3, int b3,
    const float* __restrict__ s4, _Float16* __restrict__ d4, int b4,
    const float* __restrict__ s5, _Float16* __restrict__ d5, int b5)
{
    int b = blockIdx.x;
    const float* src; _Float16* dst; int lb;
    if (b < b0)                          { src = s0; dst = d0; lb = b; }
    else if (b < b0 + b1)                { src = s1; dst = d1; lb = b - b0; }
    else if (b < b0 + b1 + b2)           { src = s2; dst = d2; lb = b - b0 - b1; }
    else if (b < b0 + b1 + b2 + b3)      { src = s3; dst = d3; lb = b - b0 - b1 - b2; }
    else if (b < b0 + b1 + b2 + b3 + b4) { src = s4; dst = d4; lb = b - b0 - b1 - b2 - b3; }
    else                                 { src = s5; dst = d5; lb = b - b0 - b1 - b2 - b3 - b4; }
    int i = (lb * 256 + threadIdx.x) * 4;
    float4 v = *(const float4*)(src + i);
    _Float16 h4[4] = {(_Float16)v.x, (_Float16)v.y, (_Float16)v.z, (_Float16)v.w};
    *(uint2*)(dst + i) = *(uint2*)h4;
}

// ---------------- fp16 MFMA GEMM (reg prefetch, padded LDS) -------------------
// C = act(A(MxK)*B(NxK)^T + bias) [+C]. BNT=128: 4 waves 64x64; BNT=64: 4 waves
// 32x64 (2x grid for N=512). HALF=1: store C as fp16 (no accum).
template<int ACT, int BNT, int HALF>   // ACT: 0 none, 1 relu
__global__ __launch_bounds__(256) void hgemm_nt(
    const _Float16* __restrict__ A, int lda,
    const _Float16* __restrict__ B, int ldb,
    void* __restrict__ Cv, int ldc,
    const float* __restrict__ bias, int K, int accum)
{
    constexpr int MI = (BNT == 128) ? 4 : 2;
    __shared__ _Float16 As[128][40];   // pad 32->40: 2-way bank alias only (free)
    __shared__ _Float16 Bs[BNT][40];
    int tid = threadIdx.x;
    int m0 = blockIdx.y * 128, n0 = blockIdx.x * BNT;
    int lane = tid & 63, wave = tid >> 6;
    int wm, wn;
    if constexpr (BNT == 128) { wm = (wave >> 1) * 64; wn = (wave & 1) * 64; }
    else                      { wm = wave * 32;        wn = 0; }
    int quad = lane >> 4, r16 = lane & 15;
    v4f acc[MI][4] = {};

    int srow = tid >> 1;            // 0..127
    int scol = (tid & 1) * 16;      // 0 or 16
    const _Float16* Ag = A + (size_t)(m0 + srow) * lda + scol;
    int srowB = (BNT == 128) ? srow : (tid >> 2);
    int scolB = (BNT == 128) ? scol : (tid & 3) * 8;
    const _Float16* Bg = B + (size_t)(n0 + srowB) * ldb + scolB;

    uint4 a0, a1, b0, b1;
    a0 = *(const uint4*)(Ag);
    a1 = *(const uint4*)(Ag + 8);
    b0 = *(const uint4*)(Bg);
    if constexpr (BNT == 128) b1 = *(const uint4*)(Bg + 8);

    int KS = K / 32;
    for (int ks = 0; ks < KS; ++ks) {
        __syncthreads();
        *(uint4*)&As[srow][scol] = a0;
        *(uint4*)&As[srow][scol + 8] = a1;
        *(uint4*)&Bs[srowB][scolB] = b0;
        if constexpr (BNT == 128) *(uint4*)&Bs[srowB][scolB + 8] = b1;
        __syncthreads();
        if (ks + 1 < KS) {
            int k0 = (ks + 1) * 32;
            a0 = *(const uint4*)(Ag + k0);
            a1 = *(const uint4*)(Ag + k0 + 8);
            b0 = *(const uint4*)(Bg + k0);
            if constexpr (BNT == 128) b1 = *(const uint4*)(Bg + k0 + 8);
        }
        v8h af[MI], bf[4];
#pragma unroll
        for (int i = 0; i < MI; ++i)
            af[i] = *(const v8h*)&As[wm + i * 16 + r16][quad * 8];
#pragma unroll
        for (int j = 0; j < 4; ++j)
            bf[j] = *(const v8h*)&Bs[wn + j * 16 + r16][quad * 8];
#pragma unroll
        for (int i = 0; i < MI; ++i)
#pragma unroll
            for (int j = 0; j < 4; ++j)
                acc[i][j] = __builtin_amdgcn_mfma_f32_16x16x32_f16(
                    af[i], bf[j], acc[i][j], 0, 0, 0);
    }

    // C/D layout: col = lane&15, row = (lane>>4)*4 + reg
#pragma unroll
    for (int i = 0; i < MI; ++i) {
#pragma unroll
        for (int j = 0; j < 4; ++j) {
            int col = n0 + wn + j * 16 + r16;
            int rbase = m0 + wm + i * 16 + quad * 4;
            float bv = bias ? bias[col] : 0.f;
#pragma unroll
            for (int r = 0; r < 4; ++r) {
                float v = acc[i][j][r] + bv;
                if (ACT == 1) v = fmaxf(v, 0.f);
                if constexpr (HALF) {
                    ((_Float16*)Cv)[(size_t)(rbase + r) * ldc + col] = (_Float16)v;
                } else {
                    float* p = (float*)Cv + (size_t)(rbase + r) * ldc + col;
                    if (accum) v += *p;
                    *p = v;
                }
            }
        }
    }
}

// ---------------- x_proj fp16 MFMA split-K: dbl += xc_h @ xpw_h^T -------------
__global__ __launch_bounds__(256) void hgemm_xproj(
    const _Float16* __restrict__ A,    // xc_h, lda=DI
    const _Float16* __restrict__ B,    // xpw_h (64 x DI)
    float* __restrict__ C)             // dbl, ldc=64
{
    __shared__ _Float16 As[128][40];
    __shared__ _Float16 Bs[64][40];
    int tid = threadIdx.x;
    int m0 = blockIdx.y * 128;
    int kb = blockIdx.z * 128;
    int lane = tid & 63, wave = tid >> 6;
    int wm = wave * 32;
    int quad = lane >> 4, r16 = lane & 15;
    v4f acc[2][4] = {};

    int srow = tid >> 1, scol = (tid & 1) * 16;
    const _Float16* Ag = A + (size_t)(m0 + srow) * DI + kb + scol;
    int srowB = tid >> 2, scolB = (tid & 3) * 8;
    const _Float16* Bg = B + (size_t)srowB * DI + kb + scolB;

    uint4 a0 = *(const uint4*)(Ag);
    uint4 a1 = *(const uint4*)(Ag + 8);
    uint4 b0 = *(const uint4*)(Bg);

    for (int ks = 0; ks < 4; ++ks) {
        __syncthreads();
        *(uint4*)&As[srow][scol] = a0;
        *(uint4*)&As[srow][scol + 8] = a1;
        *(uint4*)&Bs[srowB][scolB] = b0;
        __syncthreads();
        if (ks + 1 < 4) {
            int k0 = (ks + 1) * 32;
            a0 = *(const uint4*)(Ag + k0);
            a1 = *(const uint4*)(Ag + k0 + 8);
            b0 = *(const uint4*)(Bg + k0);
        }
        v8h af[2], bf[4];
#pragma unroll
        for (int i = 0; i < 2; ++i)
            af[i] = *(const v8h*)&As[wm + i * 16 + r16][quad * 8];
#pragma unroll
        for (int j = 0; j < 4; ++j)
            bf[j] = *(const v8h*)&Bs[j * 16 + r16][quad * 8];
#pragma unroll
        for (int i = 0; i < 2; ++i)
#pragma unroll
            for (int j = 0; j < 4; ++j)
                acc[i][j] = __builtin_amdgcn_mfma_f32_16x16x32_f16(
                    af[i], bf[j], acc[i][j], 0, 0, 0);
    }
#pragma unroll
    for (int i = 0; i < 2; ++i) {
#pragma unroll
        for (int j = 0; j < 4; ++j) {
            int col = j * 16 + r16;
            int rbase = m0 + wm + i * 16 + quad * 4;
#pragma unroll
            for (int r = 0; r < 4; ++r)
                atomicAdd(&C[(size_t)(rbase + r) * 64 + col], acc[i][j][r]);
        }
    }
}

// ---------------- attn fp16 MFMA: avec[row] += tanh(hln_h@aw1_h^T + b1).w2 ----
// M=4096 (tile 128), N=128 (two 64-col blocks), K=512. Fused tanh+dot epilogue
// with quad-local shfl reduction -> one atomicAdd per row per block.
__global__ __launch_bounds__(256) void hgemm_attn(
    const _Float16* __restrict__ A,    // hln_h, lda=DM
    const _Float16* __restrict__ B,    // aw1_h (128 x DM)
    const float* __restrict__ b1, const float* __restrict__ w2,
    float* __restrict__ avec)
{
    __shared__ _Float16 As[128][40];
    __shared__ _Float16 Bs[64][40];
    int tid = threadIdx.x;
    int m0 = blockIdx.y * 128, n0 = blockIdx.x * 64;
    int lane = tid & 63, wave = tid >> 6;
    int wm = wave * 32;
    int quad = lane >> 4, r16 = lane & 15;
    v4f acc[2][4] = {};

    int srow = tid >> 1, scol = (tid & 1) * 16;
    const _Float16* Ag = A + (size_t)(m0 + srow) * DM + scol;
    int srowB = tid >> 2, scolB = (tid & 3) * 8;
    const _Float16* Bg = B + (size_t)(n0 + srowB) * DM + scolB;

    uint4 a0 = *(const uint4*)(Ag);
    uint4 a1 = *(const uint4*)(Ag + 8);
    uint4 b0 = *(const uint4*)(Bg);

    for (int ks = 0; ks < DM / 32; ++ks) {
        __syncthreads();
        *(uint4*)&As[srow][scol] = a0;
        *(uint4*)&As[srow][scol + 8] = a1;
        *(uint4*)&Bs[srowB][scolB] = b0;
        __syncthreads();
        if (ks + 1 < DM / 32) {
            int k0 = (ks + 1) * 32;
            a0 = *(const uint4*)(Ag + k0);
            a1 = *(const uint4*)(Ag + k0 + 8);
            b0 = *(const uint4*)(Bg + k0);
        }
        v8h af[2], bf[4];
#pragma unroll
        for (int i = 0; i < 2; ++i)
            af[i] = *(const v8h*)&As[wm + i * 16 + r16][quad * 8];
#pragma unroll
        for (int j = 0; j < 4; ++j)
            bf[j] = *(const v8h*)&Bs[j * 16 + r16][quad * 8];
#pragma unroll
        for (int i = 0; i < 2; ++i)
#pragma unroll
            for (int j = 0; j < 4; ++j)
                acc[i][j] = __builtin_amdgcn_mfma_f32_16x16x32_f16(
                    af[i], bf[j], acc[i][j], 0, 0, 0);
    }

#pragma unroll
    for (int i = 0; i < 2; ++i) {
        float part[4] = {0.f, 0.f, 0.f, 0.f};
#pragma unroll
        for (int j = 0; j < 4; ++j) {
            int col = n0 + j * 16 + r16;
            float bv = b1[col], wv = w2[col];
#pragma unroll
            for (int r = 0; r < 4; ++r)
                part[r] = fmaf(tanhf(acc[i][j][r] + bv), wv, part[r]);
        }
#pragma unroll
        for (int r = 0; r < 4; ++r) {
            part[r] += __shfl_xor(part[r], 1, 64);
            part[r] += __shfl_xor(part[r], 2, 64);
            part[r] += __shfl_xor(part[r], 4, 64);
            part[r] += __shfl_xor(part[r], 8, 64);
        }
        if (r16 == 0) {
            int rbase = m0 + wm + i * 16 + quad * 4;
#pragma unroll
            for (int r = 0; r < 4; ++r)
                atomicAdd(&avec[rbase + r], part[r]);
        }
    }
}

// ---------------- generic fp32 GEMM: C = act(A*B^T + bias) --------------------
// ACT: 2 softplus (dt)
#define BM 64
#define BN 64
#define BKK 32
template<int ACT>
__global__ __launch_bounds__(256) void gemm_nt(
    const float* __restrict__ A, int lda,
    const float* __restrict__ B, int ldb,
    float* __restrict__ C, int ldc,
    const float* __restrict__ bias,
    int M, int N, int K)
{
    __shared__ float As[BKK][BM + 4];
    __shared__ float Bs[BKK][BN + 4];
    int tid = threadIdx.x;
    int m0 = blockIdx.y * BM;
    int n0 = blockIdx.x * BN;
    int tx = tid & 15, ty = tid >> 4;
    float acc[4][4] = {};
    int arow = tid >> 3;       // 0..31
    int ak = (tid & 7) * 4;    // 0..28

    for (int k0 = 0; k0 < K; k0 += BKK) {
#pragma unroll
        for (int r = 0; r < 2; ++r) {
            int row = arow + r * 32;
            float4 va = *(const float4*)(A + (size_t)(m0 + row) * lda + k0 + ak);
            As[ak + 0][row] = va.x; As[ak + 1][row] = va.y;
            As[ak + 2][row] = va.z; As[ak + 3][row] = va.w;
            float4 vb = *(const float4*)(B + (size_t)(n0 + row) * ldb + k0 + ak);
            Bs[ak + 0][row] = vb.x; Bs[ak + 1][row] = vb.y;
            Bs[ak + 2][row] = vb.z; Bs[ak + 3][row] = vb.w;
        }
        __syncthreads();
#pragma unroll
        for (int kk = 0; kk < BKK; ++kk) {
            float4 a4 = *(const float4*)&As[kk][ty * 4];
            float4 b4 = *(const float4*)&Bs[kk][tx * 4];
            float a[4] = {a4.x, a4.y, a4.z, a4.w};
            float b[4] = {b4.x, b4.y, b4.z, b4.w};
#pragma unroll
            for (int i = 0; i < 4; ++i)
#pragma unroll
                for (int j = 0; j < 4; ++j)
                    acc[i][j] = fmaf(a[i], b[j], acc[i][j]);
        }
        __syncthreads();
    }

#pragma unroll
    for (int i = 0; i < 4; ++i) {
        int row = m0 + ty * 4 + i;
        int col = n0 + tx * 4;
        float* cp = C + (size_t)row * ldc + col;
#pragma unroll
        for (int j = 0; j < 4; ++j) {
            float xv = acc[i][j] + (bias ? bias[col + j] : 0.f);
            if (ACT == 2) xv = (xv > 20.f) ? xv : log1pf(__expf(xv));
            cp[j] = xv;
        }
    }
}

// ---------------- layernorm (D=512); optional fp16 side-out; optional avec init
__global__ __launch_bounds__(256) void layernorm_k(
    const float* __restrict__ x, const float* __restrict__ w,
    const float* __restrict__ b, float* __restrict__ o,
    _Float16* __restrict__ oh, float* __restrict__ avec,
    const float* __restrict__ b2)
{
    int row = blockIdx.x;
    int tid = threadIdx.x;
    const float* xr = x + (size_t)row * DM;
    float v0 = xr[tid], v1 = xr[tid + 256];
    float s = v0 + v1, ss = v0 * v0 + v1 * v1;
    for (int off = 32; off; off >>= 1) {
        s += __shfl_down(s, off, 64);
        ss += __shfl_down(ss, off, 64);
    }
    __shared__ float sm[4], sm2[4];
    int wave = tid >> 6, lane = tid & 63;
    if (lane == 0) { sm[wave] = s; sm2[wave] = ss; }
    __syncthreads();
    float tot = sm[0] + sm[1] + sm[2] + sm[3];
    float tot2 = sm2[0] + sm2[1] + sm2[2] + sm2[3];
    float mu = tot * (1.f / DM);
    float var = tot2 * (1.f / DM) - mu * mu;
    float rs = rsqrtf(var + 1e-5f);
    float y0 = (v0 - mu) * rs * w[tid] + b[tid];
    float y1 = (v1 - mu) * rs * w[tid + 256] + b[tid + 256];
    o[(size_t)row * DM + tid] = y0;
    o[(size_t)row * DM + tid + 256] = y1;
    if (oh) {
        oh[(size_t)row * DM + tid] = (_Float16)y0;
        oh[(size_t)row * DM + tid + 256] = (_Float16)y1;
    }
    if (avec && tid == 0) avec[row] = b2[0];
}

// ---------------- permuted causal conv (K=4) + SiLU; fp16 out; zeroes dbl -----
__global__ __launch_bounds__(256) void conv_silu_k(
    const _Float16* __restrict__ xz, const int* __restrict__ perm,
    const float* __restrict__ cw, const float* __restrict__ cb,
    _Float16* __restrict__ xc, float* __restrict__ dbl)
{
    if (blockIdx.x < 256) {   // zero dbl (L*64 floats) for the split-K atomics
        int zi = (blockIdx.x * 256 + threadIdx.x) * 4;
        *(float4*)(dbl + zi) = make_float4(0.f, 0.f, 0.f, 0.f);
    }
    int g = blockIdx.x * 256 + threadIdx.x;   // g < L*DI
    int c = g & (DI - 1), p = g >> 10;
    float acc = cb[c];
#pragma unroll
    for (int k = 0; k < 4; ++k) {
        int q = p + k - 3;
        if (q >= 0)
            acc = fmaf((float)xz[(size_t)perm[q] * (2 * DI) + c], cw[c * 4 + k], acc);
    }
    float sig = 1.f / (1.f + __expf(-acc));
    xc[g] = (_Float16)(acc * sig);
}

// ---------------- chunked parallel selective scan ----------------
__global__ __launch_bounds__(256) void scan_pass1(
    const float* __restrict__ dt, const _Float16* __restrict__ u,
    const float* __restrict__ dbl, const float* __restrict__ A_log,
    float* __restrict__ Aprod, float* __restrict__ carry)
{
    int c = blockIdx.x * 256 + threadIdx.x;
    int j = blockIdx.y;
    float Ac[16];
#pragma unroll
    for (int s = 0; s < 16; ++s) Ac[s] = -__expf(A_log[c * DS + s]);
    float ap[16], h[16];
#pragma unroll
    for (int s = 0; s < 16; ++s) { ap[s] = 1.f; h[s] = 0.f; }
    int t0 = j * CHK;
    for (int tt = 0; tt < CHK; ++tt) {
        int t = t0 + tt;
        float dtv = dt[(size_t)t * DI + c];
        float uv  = (float)u[(size_t)t * DI + c];
        v4f Bv[4];
#pragma unroll
        for (int q = 0; q < 4; ++q)
            Bv[q] = *(const v4f*)(dbl + (size_t)t * 64 + DTR + q * 4);
        float du = dtv * uv;
#pragma unroll
        for (int s = 0; s < 16; ++s) {
            float dA = __expf(dtv * Ac[s]);
            h[s] = fmaf(dA, h[s], du * Bv[s >> 2][s & 3]);
            ap[s] *= dA;
        }
    }
    size_t base = ((size_t)j * DI + c) * DS;
#pragma unroll
    for (int q = 0; q < 4; ++q) {
        *(v4f*)(Aprod + base + q * 4) = *(v4f*)&ap[q * 4];
        *(v4f*)(carry + base + q * 4) = *(v4f*)&h[q * 4];
    }
}

__global__ __launch_bounds__(256) void scan_pass2(
    const float* __restrict__ Aprod, const float* __restrict__ carry,
    float* __restrict__ Hin)
{
    int idx = blockIdx.x * 256 + threadIdx.x;  // (c,s) flat, 16384 total
    float H = 0.f;
    Hin[idx] = 0.f;
    for (int j = 1; j < NCH; ++j) {
        H = fmaf(Aprod[(size_t)(j - 1) * (DI * DS) + idx], H,
                 carry[(size_t)(j - 1) * (DI * DS) + idx]);
        Hin[(size_t)j * (DI * DS) + idx] = H;
    }
}

__global__ __launch_bounds__(256) void scan_pass3(
    const float* __restrict__ dt, const _Float16* __restrict__ u,
    const float* __restrict__ dbl, const _Float16* __restrict__ xz,
    const float* __restrict__ A_log, const float* __restrict__ Dsk,
    const int* __restrict__ perm, const float* __restrict__ Hin,
    _Float16* __restrict__ yo)
{
    int c = blockIdx.x * 256 + threadIdx.x;
    int j = blockIdx.y;
    float Ac[16];
#pragma unroll
    for (int s = 0; s < 16; ++s) Ac[s] = -__expf(A_log[c * DS + s]);
    float Dp = Dsk[c];
    float h[16];
    size_t hbase = ((size_t)j * DI + c) * DS;
#pragma unroll
    for (int q = 0; q < 4; ++q)
        *(v4f*)&h[q * 4] = *(const v4f*)(Hin + hbase + q * 4);
    int t0 = j * CHK;
    for (int tt = 0; tt < CHK; ++tt) {
        int t = t0 + tt;
        float dtv = dt[(size_t)t * DI + c];
        float uv  = (float)u[(size_t)t * DI + c];
        v4f Bv[4], Cv[4];
#pragma unroll
        for (int q = 0; q < 4; ++q) {
            Bv[q] = *(const v4f*)(dbl + (size_t)t * 64 + DTR + q * 4);
            Cv[q] = *(const v4f*)(dbl + (size_t)t * 64 + DTR + DS + q * 4);
        }
        float du = dtv * uv;
        float y = 0.f;
#pragma unroll
        for (int s = 0; s < 16; ++s) {
            float dA = __expf(dtv * Ac[s]);
            h[s] = fmaf(dA, h[s], du * Bv[s >> 2][s & 3]);
            y = fmaf(h[s], Cv[s >> 2][s & 3], y);
        }
        int tp = perm[t];
        float z = (float)xz[(size_t)tp * (2 * DI) + DI + c];
        float sig = 1.f / (1.f + __expf(-z));
        yo[(size_t)tp * DI + c] = (_Float16)((y + uv * Dp) * (z * sig));
    }
}

// ---------------- softmax over 4096 (single block); zeroes pooled -------------
__global__ __launch_bounds__(1024) void softmax_k(
    const float* __restrict__ a, float* __restrict__ out,
    float* __restrict__ pooled)
{
    int tid = threadIdx.x;
    if (tid < DM) pooled[tid] = 0.f;
    float v[4];
    float mx = -1e30f;
#pragma unroll
    for (int i = 0; i < 4; ++i) { v[i] = a[tid + i * 1024]; mx = fmaxf(mx, v[i]); }
    __shared__ float sm[16];
    for (int off = 32; off; off >>= 1) mx = fmaxf(mx, __shfl_xor(mx, off, 64));
    int wave = tid >> 6, lane = tid & 63;
    if (lane == 0) sm[wave] = mx;
    __syncthreads();
    if (tid < 16) {
        float m = sm[tid];
        for (int off = 8; off; off >>= 1) m = fmaxf(m, __shfl_xor(m, off, 64));
        sm[tid] = m;
    }
    __syncthreads();
    mx = sm[0];
    float s = 0.f;
#pragma unroll
    for (int i = 0; i < 4; ++i) { v[i] = __expf(v[i] - mx); s += v[i]; }
    for (int off = 32; off; off >>= 1) s += __shfl_xor(s, off, 64);
    __syncthreads();
    if (lane == 0) sm[wave] = s;
    __syncthreads();
    if (tid < 16) {
        float t2 = sm[tid];
        for (int off = 8; off; off >>= 1) t2 += __shfl_xor(t2, off, 64);
        sm[tid] = t2;
    }
    __syncthreads();
    float inv = 1.f / sm[0];
#pragma unroll
    for (int i = 0; i < 4; ++i) out[tid + i * 1024] = v[i] * inv;
}

__global__ __launch_bounds__(512) void pool_k(
    const float* __restrict__ aatt, const float* __restrict__ h,
    float* __restrict__ pooled)
{
    int m = threadIdx.x;
    int t0 = blockIdx.x * 128;
    float acc = 0.f;
    for (int r = 0; r < 128; ++r) {
        int t = t0 + r;
        acc = fmaf(aatt[t], h[(size_t)t * DM + m], acc);
    }
    atomicAdd(&pooled[m], acc);
}

__global__ __launch_bounds__(64) void out2048_k(
    const float* __restrict__ pooled, const float* __restrict__ w,
    const float* __restrict__ b, float* __restrict__ out)
{
    int n = blockIdx.x;
    int lane = threadIdx.x;
    const float* wr = w + (size_t)n * DM;
    float acc = 0.f;
#pragma unroll
    for (int k = 0; k < 8; ++k)
        acc = fmaf(wr[lane + k * 64], pooled[lane + k * 64], acc);
    for (int off = 32; off; off >>= 1) acc += __shfl_xor(acc, off, 64);
    if (lane == 0) out[n] = acc + b[n];
}

extern "C" void kernel_launch(void* const* d_in, const int* in_sizes, int n_in,
                              void* d_out, int out_size, void* d_ws, size_t ws_size,
                              hipStream_t stream) {
    const float* x     = (const float*)d_in[0];
    const int*   rate  = (const int*)d_in[1];
    const float* fc1_w = (const float*)d_in[2];
    const float* fc1_b = (const float*)d_in[3];
    const float* ln_w  = (const float*)d_in[4];
    const float* ln_b  = (const float*)d_in[5];
    const float* ipw   = (const float*)d_in[6];
    const float* cw    = (const float*)d_in[7];
    const float* cb    = (const float*)d_in[8];
    const float* xpw   = (const float*)d_in[9];
    const float* dtw   = (const float*)d_in[10];
    const float* dtpb  = (const float*)d_in[11];
    const float* A_log = (const float*)d_in[12];
    const float* Dsk   = (const float*)d_in[13];
    const float* opw   = (const float*)d_in[14];
    const float* nw    = (const float*)d_in[15];
    const float* nb    = (const float*)d_in[16];
    const float* aw1   = (const float*)d_in[17];
    const float* ab1   = (const float*)d_in[18];
    const float* aw2   = (const float*)d_in[19];
    const float* ab2   = (const float*)d_in[20];
    const float* ow    = (const float*)d_in[21];
    const float* ob    = (const float*)d_in[22];
    float* out = (float*)d_out;

    int* perm = (int*)d_ws;
    float* f = (float*)d_ws + 4096;
    float* h    = f; f += (size_t)L * DM;
    float* hln  = f; f += (size_t)L * DM;
    float* dbl  = f; f += (size_t)L * 64;
    float* dtv  = f; f += (size_t)L * DI;
    float* avec = f; f += L;
    float* pooled = f; f += DM;
    float* Aprod = f; f += (size_t)NCH * DI * DS;
    float* carry = f; f += (size_t)NCH * DI * DS;
    float* Hin   = f; f += (size_t)NCH * DI * DS;
    _Float16* fh = (_Float16*)f;
    _Float16* xh     = fh; fh += (size_t)L * DIN;
    _Float16* hln_h  = fh; fh += (size_t)L * DM;
    _Float16* yo_h   = fh; fh += (size_t)L * DI;
    _Float16* xz_h   = fh; fh += (size_t)L * 2 * DI;
    _Float16* xc_h   = fh; fh += (size_t)L * DI;
    _Float16* fc1w_h = fh; fh += (size_t)DM * DIN;
    _Float16* ipw_h  = fh; fh += (size_t)2 * 2 * DI * DM;
    _Float16* opw_h  = fh; fh += (size_t)2 * DM * DI;
    _Float16* xpw_h  = fh; fh += (size_t)2 * 64 * DI;
    _Float16* aw1_h  = fh; fh += (size_t)128 * DM;

    perm_k<<<16, 256, 0, stream>>>(perm, rate);

    // all fp32->fp16 conversions in a single launch
    f2h_multi_k<<<(L * DIN + DM * DIN + 2 * 2 * DI * DM + 2 * DM * DI
                   + 2 * 64 * DI + 128 * DM) / 1024, 256, 0, stream>>>(
        x, xh, L * DIN / 1024,
        fc1_w, fc1w_h, DM * DIN / 1024,
        ipw, ipw_h, 2 * 2 * DI * DM / 1024,
        opw, opw_h, 2 * DM * DI / 1024,
        xpw, xpw_h, 2 * 64 * DI / 1024,
        aw1, aw1_h, 128 * DM / 1024);

    // h = relu(x @ fc1_w^T + fc1_b)   [fp16 MFMA, N64 tile -> 256 blocks]
    hgemm_nt<1, 64, 0><<<dim3(DM / 64, L / 128), 256, 0, stream>>>(
        xh, DIN, fc1w_h, DIN, h, DM, fc1_b, DIN, 0);

    for (int l = 0; l < 2; ++l) {
        layernorm_k<<<L, 256, 0, stream>>>(h, ln_w + l * DM, ln_b + l * DM,
                                           hln, hln_h, nullptr, nullptr);
        // xz = hln @ in_proj^T   [fp16 MFMA -> fp16 out, 512 blocks]
        hgemm_nt<0, 128, 1><<<dim3(2 * DI / 128, L / 128), 256, 0, stream>>>(
            hln_h, DM, ipw_h + (size_t)l * 2 * DI * DM, DM, xz_h, 2 * DI,
            nullptr, DM, 0);
        // xc = silu(causal_conv(x_perm)) -> fp16; also zeroes dbl
        conv_silu_k<<<L * DI / 256, 256, 0, stream>>>(
            xz_h, perm, cw + (size_t)l * DI * 4, cb + (size_t)l * DI, xc_h, dbl);
        // dbl += xc_h @ xpw_h^T  [fp16 MFMA split-K 8 -> 256 blocks]
        hgemm_xproj<<<dim3(1, L / 128, 8), 256, 0, stream>>>(
            xc_h, xpw_h + (size_t)l * 64 * DI, dbl);
        // dt = softplus(dbl[:, :32] @ dt_proj^T + dtb)  (K=32, 1024 blocks)
        gemm_nt<2><<<dim3(DI / 64, L / 64), 256, 0, stream>>>(
            dbl, 64, dtw + (size_t)l * DI * DTR, DTR, dtv, DI,
            dtpb + (size_t)l * DI, L, DI, DTR);
        // chunked parallel selective scan (256 chunks -> 1024 blocks)
        scan_pass1<<<dim3(DI / 256, NCH), 256, 0, stream>>>(
            dtv, xc_h, dbl, A_log + (size_t)l * DI * DS, Aprod, carry);
        scan_pass2<<<DI * DS / 256, 256, 0, stream>>>(Aprod, carry, Hin);
        scan_pass3<<<dim3(DI / 256, NCH), 256, 0, stream>>>(
            dtv, xc_h, dbl, xz_h, A_log + (size_t)l * DI * DS,
            Dsk + (size_t)l * DI, perm, Hin, yo_h);
        // h += yo @ out_proj^T   [fp16 MFMA, N64 tile -> 256 blocks, accumulate]
        hgemm_nt<0, 64, 0><<<dim3(DM / 64, L / 128), 256, 0, stream>>>(
            yo_h, DI, opw_h + (size_t)l * DM * DI, DI, h, DM, nullptr, DI, 1);
    }

    // final LN: fp32 + fp16 out, seeds avec with attn bias b2
    layernorm_k<<<L, 256, 0, stream>>>(h, nw, nb, hln, hln_h, avec, ab2);
    // fused attn: avec += tanh(hln_h @ aw1_h^T + ab1) . w2   [fp16 MFMA]
    hgemm_attn<<<dim3(2, L / 128), 256, 0, stream>>>(
        hln_h, aw1_h, ab1, aw2, avec);
    softmax_k<<<1, 1024, 0, stream>>>(avec, out + 2048, pooled);
    pool_k<<<32, 512, 0, stream>>>(out + 2048, hln, pooled);
    out2048_k<<<2048, 64, 0, stream>>>(pooled, ow, ob, out);
}

// Round 12
// 508.186 us; speedup vs baseline: 1.2201x; 1.0555x over previous
//
#include <hip/hip_runtime.h>
#include <hip/hip_fp16.h>
#include <math.h>

#define L 4096
#define DIN 1024
#define DM 512
#define DI 1024
#define DS 16
#define DTR 32
#define NCH 256
#define CHK 16   // NCH*CHK == L

typedef _Float16 v8h __attribute__((ext_vector_type(8)));
typedef _Float16 v4h __attribute__((ext_vector_type(4)));
typedef float v4f __attribute__((ext_vector_type(4)));

// ------- perm + fp32->fp16 convert (6 segments), single launch ---------------
// blocks [0,16): perm table; then conversion segments.
__global__ __launch_bounds__(256) void f2h_multi_k(
    const int* __restrict__ ratep, int* __restrict__ perm,
    const float* __restrict__ s0, _Float16* __restrict__ d0, int b0,
    const float* __restrict__ s1, _Float16* __restrict__ d1, int b1,
    const float* __restrict__ s2, _Float16* __restrict__ d2, int b2,
    const float* __restrict__ s3, _Float16* __restrict__ d3, int b3,
    const float* __restrict__ s4, _Float16* __restrict__ d4, int b4,
    const float* __restrict__ s5, _Float16* __restrict__ d5, int b5)
{
    int b = blockIdx.x;
    if (b < 16) {
        int p = b * 256 + threadIdx.x;
        int rate = ratep[0];
        int cum = 0;
        for (int g = 0; g < rate; ++g) {
            int sz = (L - g + rate - 1) / rate;
            if (p < cum + sz) { perm[p] = g + rate * (p - cum); return; }
            cum += sz;
        }
        return;
    }
    b -= 16;
    const float* src; _Float16* dst; int lb;
    if (b < b0)                          { src = s0; dst = d0; lb = b; }
    else if (b < b0 + b1)                { src = s1; dst = d1; lb = b - b0; }
    else if (b < b0 + b1 + b2)           { src = s2; dst = d2; lb = b - b0 - b1; }
    else if (b < b0 + b1 + b2 + b3)      { src = s3; dst = d3; lb = b - b0 - b1 - b2; }
    else if (b < b0 + b1 + b2 + b3 + b4) { src = s4; dst = d4; lb = b - b0 - b1 - b2 - b3; }
    else                                 { src = s5; dst = d5; lb = b - b0 - b1 - b2 - b3 - b4; }
    int i = (lb * 256 + threadIdx.x) * 4;
    float4 v = *(const float4*)(src + i);
    _Float16 h4[4] = {(_Float16)v.x, (_Float16)v.y, (_Float16)v.z, (_Float16)v.w};
    *(uint2*)(dst + i) = *(uint2*)h4;
}

// ---------------- fp16 MFMA GEMM (reg prefetch, padded LDS) -------------------
// C = act(A(MxK)*B(NxK)^T + bias) [+C]. BNT=128: 4 waves 64x64; BNT=64: 4 waves
// 32x64 (2x grid for N=512). HALF=1: store C as fp16 (no accum).
template<int ACT, int BNT, int HALF>   // ACT: 0 none, 1 relu
__global__ __launch_bounds__(256) void hgemm_nt(
    const _Float16* __restrict__ A, int lda,
    const _Float16* __restrict__ B, int ldb,
    void* __restrict__ Cv, int ldc,
    const float* __restrict__ bias, int K, int accum)
{
    constexpr int MI = (BNT == 128) ? 4 : 2;
    __shared__ _Float16 As[128][40];   // pad 32->40: 2-way bank alias only (free)
    __shared__ _Float16 Bs[BNT][40];
    int tid = threadIdx.x;
    int m0 = blockIdx.y * 128, n0 = blockIdx.x * BNT;
    int lane = tid & 63, wave = tid >> 6;
    int wm, wn;
    if constexpr (BNT == 128) { wm = (wave >> 1) * 64; wn = (wave & 1) * 64; }
    else                      { wm = wave * 32;        wn = 0; }
    int quad = lane >> 4, r16 = lane & 15;
    v4f acc[MI][4] = {};

    int srow = tid >> 1;            // 0..127
    int scol = (tid & 1) * 16;      // 0 or 16
    const _Float16* Ag = A + (size_t)(m0 + srow) * lda + scol;
    int srowB = (BNT == 128) ? srow : (tid >> 2);
    int scolB = (BNT == 128) ? scol : (tid & 3) * 8;
    const _Float16* Bg = B + (size_t)(n0 + srowB) * ldb + scolB;

    uint4 a0, a1, b0, b1;
    a0 = *(const uint4*)(Ag);
    a1 = *(const uint4*)(Ag + 8);
    b0 = *(const uint4*)(Bg);
    if constexpr (BNT == 128) b1 = *(const uint4*)(Bg + 8);

    int KS = K / 32;
    for (int ks = 0; ks < KS; ++ks) {
        __syncthreads();
        *(uint4*)&As[srow][scol] = a0;
        *(uint4*)&As[srow][scol + 8] = a1;
        *(uint4*)&Bs[srowB][scolB] = b0;
        if constexpr (BNT == 128) *(uint4*)&Bs[srowB][scolB + 8] = b1;
        __syncthreads();
        if (ks + 1 < KS) {
            int k0 = (ks + 1) * 32;
            a0 = *(const uint4*)(Ag + k0);
            a1 = *(const uint4*)(Ag + k0 + 8);
            b0 = *(const uint4*)(Bg + k0);
            if constexpr (BNT == 128) b1 = *(const uint4*)(Bg + k0 + 8);
        }
        v8h af[MI], bf[4];
#pragma unroll
        for (int i = 0; i < MI; ++i)
            af[i] = *(const v8h*)&As[wm + i * 16 + r16][quad * 8];
#pragma unroll
        for (int j = 0; j < 4; ++j)
            bf[j] = *(const v8h*)&Bs[wn + j * 16 + r16][quad * 8];
#pragma unroll
        for (int i = 0; i < MI; ++i)
#pragma unroll
            for (int j = 0; j < 4; ++j)
                acc[i][j] = __builtin_amdgcn_mfma_f32_16x16x32_f16(
                    af[i], bf[j], acc[i][j], 0, 0, 0);
    }

    // C/D layout: col = lane&15, row = (lane>>4)*4 + reg
#pragma unroll
    for (int i = 0; i < MI; ++i) {
#pragma unroll
        for (int j = 0; j < 4; ++j) {
            int col = n0 + wn + j * 16 + r16;
            int rbase = m0 + wm + i * 16 + quad * 4;
            float bv = bias ? bias[col] : 0.f;
#pragma unroll
            for (int r = 0; r < 4; ++r) {
                float v = acc[i][j][r] + bv;
                if (ACT == 1) v = fmaxf(v, 0.f);
                if constexpr (HALF) {
                    ((_Float16*)Cv)[(size_t)(rbase + r) * ldc + col] = (_Float16)v;
                } else {
                    float* p = (float*)Cv + (size_t)(rbase + r) * ldc + col;
                    if (accum) v += *p;
                    *p = v;
                }
            }
        }
    }
}

// ---------------- x_proj fp16 MFMA split-K: dbl += xc_h @ xpw_h^T -------------
__global__ __launch_bounds__(256) void hgemm_xproj(
    const _Float16* __restrict__ A,    // xc_h, lda=DI
    const _Float16* __restrict__ B,    // xpw_h (64 x DI)
    float* __restrict__ C)             // dbl, ldc=64
{
    __shared__ _Float16 As[128][40];
    __shared__ _Float16 Bs[64][40];
    int tid = threadIdx.x;
    int m0 = blockIdx.y * 128;
    int kb = blockIdx.z * 128;
    int lane = tid & 63, wave = tid >> 6;
    int wm = wave * 32;
    int quad = lane >> 4, r16 = lane & 15;
    v4f acc[2][4] = {};

    int srow = tid >> 1, scol = (tid & 1) * 16;
    const _Float16* Ag = A + (size_t)(m0 + srow) * DI + kb + scol;
    int srowB = tid >> 2, scolB = (tid & 3) * 8;
    const _Float16* Bg = B + (size_t)srowB * DI + kb + scolB;

    uint4 a0 = *(const uint4*)(Ag);
    uint4 a1 = *(const uint4*)(Ag + 8);
    uint4 b0 = *(const uint4*)(Bg);

    for (int ks = 0; ks < 4; ++ks) {
        __syncthreads();
        *(uint4*)&As[srow][scol] = a0;
        *(uint4*)&As[srow][scol + 8] = a1;
        *(uint4*)&Bs[srowB][scolB] = b0;
        __syncthreads();
        if (ks + 1 < 4) {
            int k0 = (ks + 1) * 32;
            a0 = *(const uint4*)(Ag + k0);
            a1 = *(const uint4*)(Ag + k0 + 8);
            b0 = *(const uint4*)(Bg + k0);
        }
        v8h af[2], bf[4];
#pragma unroll
        for (int i = 0; i < 2; ++i)
            af[i] = *(const v8h*)&As[wm + i * 16 + r16][quad * 8];
#pragma unroll
        for (int j = 0; j < 4; ++j)
            bf[j] = *(const v8h*)&Bs[j * 16 + r16][quad * 8];
#pragma unroll
        for (int i = 0; i < 2; ++i)
#pragma unroll
            for (int j = 0; j < 4; ++j)
                acc[i][j] = __builtin_amdgcn_mfma_f32_16x16x32_f16(
                    af[i], bf[j], acc[i][j], 0, 0, 0);
    }
#pragma unroll
    for (int i = 0; i < 2; ++i) {
#pragma unroll
        for (int j = 0; j < 4; ++j) {
            int col = j * 16 + r16;
            int rbase = m0 + wm + i * 16 + quad * 4;
#pragma unroll
            for (int r = 0; r < 4; ++r)
                atomicAdd(&C[(size_t)(rbase + r) * 64 + col], acc[i][j][r]);
        }
    }
}

// ---------------- attn fp16 MFMA: avec[row] += tanh(hln_h@aw1_h^T + b1).w2 ----
__global__ __launch_bounds__(256) void hgemm_attn(
    const _Float16* __restrict__ A,    // hln_h, lda=DM
    const _Float16* __restrict__ B,    // aw1_h (128 x DM)
    const float* __restrict__ b1, const float* __restrict__ w2,
    float* __restrict__ avec)
{
    __shared__ _Float16 As[128][40];
    __shared__ _Float16 Bs[64][40];
    int tid = threadIdx.x;
    int m0 = blockIdx.y * 128, n0 = blockIdx.x * 64;
    int lane = tid & 63, wave = tid >> 6;
    int wm = wave * 32;
    int quad = lane >> 4, r16 = lane & 15;
    v4f acc[2][4] = {};

    int srow = tid >> 1, scol = (tid & 1) * 16;
    const _Float16* Ag = A + (size_t)(m0 + srow) * DM + scol;
    int srowB = tid >> 2, scolB = (tid & 3) * 8;
    const _Float16* Bg = B + (size_t)(n0 + srowB) * DM + scolB;

    uint4 a0 = *(const uint4*)(Ag);
    uint4 a1 = *(const uint4*)(Ag + 8);
    uint4 b0 = *(const uint4*)(Bg);

    for (int ks = 0; ks < DM / 32; ++ks) {
        __syncthreads();
        *(uint4*)&As[srow][scol] = a0;
        *(uint4*)&As[srow][scol + 8] = a1;
        *(uint4*)&Bs[srowB][scolB] = b0;
        __syncthreads();
        if (ks + 1 < DM / 32) {
            int k0 = (ks + 1) * 32;
            a0 = *(const uint4*)(Ag + k0);
            a1 = *(const uint4*)(Ag + k0 + 8);
            b0 = *(const uint4*)(Bg + k0);
        }
        v8h af[2], bf[4];
#pragma unroll
        for (int i = 0; i < 2; ++i)
            af[i] = *(const v8h*)&As[wm + i * 16 + r16][quad * 8];
#pragma unroll
        for (int j = 0; j < 4; ++j)
            bf[j] = *(const v8h*)&Bs[j * 16 + r16][quad * 8];
#pragma unroll
        for (int i = 0; i < 2; ++i)
#pragma unroll
            for (int j = 0; j < 4; ++j)
                acc[i][j] = __builtin_amdgcn_mfma_f32_16x16x32_f16(
                    af[i], bf[j], acc[i][j], 0, 0, 0);
    }

#pragma unroll
    for (int i = 0; i < 2; ++i) {
        float part[4] = {0.f, 0.f, 0.f, 0.f};
#pragma unroll
        for (int j = 0; j < 4; ++j) {
            int col = n0 + j * 16 + r16;
            float bv = b1[col], wv = w2[col];
#pragma unroll
            for (int r = 0; r < 4; ++r)
                part[r] = fmaf(tanhf(acc[i][j][r] + bv), wv, part[r]);
        }
#pragma unroll
        for (int r = 0; r < 4; ++r) {
            part[r] += __shfl_xor(part[r], 1, 64);
            part[r] += __shfl_xor(part[r], 2, 64);
            part[r] += __shfl_xor(part[r], 4, 64);
            part[r] += __shfl_xor(part[r], 8, 64);
        }
        if (r16 == 0) {
            int rbase = m0 + wm + i * 16 + quad * 4;
#pragma unroll
            for (int r = 0; r < 4; ++r)
                atomicAdd(&avec[rbase + r], part[r]);
        }
    }
}

// ------- dt GEMM (fp32 SIMT, K=32): dtv_h = softplus(dbl[:,:32]@dtw^T + b) ----
#define BM 64
#define BN 64
#define BKK 32
__global__ __launch_bounds__(256) void gemm_dt(
    const float* __restrict__ A, int lda,
    const float* __restrict__ B, int ldb,
    _Float16* __restrict__ C, int ldc,
    const float* __restrict__ bias, int K)
{
    __shared__ float As[BKK][BM + 4];
    __shared__ float Bs[BKK][BN + 4];
    int tid = threadIdx.x;
    int m0 = blockIdx.y * BM;
    int n0 = blockIdx.x * BN;
    int tx = tid & 15, ty = tid >> 4;
    float acc[4][4] = {};
    int arow = tid >> 3;       // 0..31
    int ak = (tid & 7) * 4;    // 0..28

    for (int k0 = 0; k0 < K; k0 += BKK) {
#pragma unroll
        for (int r = 0; r < 2; ++r) {
            int row = arow + r * 32;
            float4 va = *(const float4*)(A + (size_t)(m0 + row) * lda + k0 + ak);
            As[ak + 0][row] = va.x; As[ak + 1][row] = va.y;
            As[ak + 2][row] = va.z; As[ak + 3][row] = va.w;
            float4 vb = *(const float4*)(B + (size_t)(n0 + row) * ldb + k0 + ak);
            Bs[ak + 0][row] = vb.x; Bs[ak + 1][row] = vb.y;
            Bs[ak + 2][row] = vb.z; Bs[ak + 3][row] = vb.w;
        }
        __syncthreads();
#pragma unroll
        for (int kk = 0; kk < BKK; ++kk) {
            float4 a4 = *(const float4*)&As[kk][ty * 4];
            float4 b4 = *(const float4*)&Bs[kk][tx * 4];
            float a[4] = {a4.x, a4.y, a4.z, a4.w};
            float b[4] = {b4.x, b4.y, b4.z, b4.w};
#pragma unroll
            for (int i = 0; i < 4; ++i)
#pragma unroll
                for (int j = 0; j < 4; ++j)
                    acc[i][j] = fmaf(a[i], b[j], acc[i][j]);
        }
        __syncthreads();
    }

#pragma unroll
    for (int i = 0; i < 4; ++i) {
        int row = m0 + ty * 4 + i;
        int col = n0 + tx * 4;
        _Float16 v4[4];
#pragma unroll
        for (int j = 0; j < 4; ++j) {
            float xv = acc[i][j] + bias[col + j];
            xv = (xv > 20.f) ? xv : log1pf(__expf(xv));
            v4[j] = (_Float16)xv;
        }
        *(uint2*)(C + (size_t)row * ldc + col) = *(uint2*)v4;
    }
}

// ---------------- layernorm (D=512); optional fp16 side-out; optional avec init
__global__ __launch_bounds__(256) void layernorm_k(
    const float* __restrict__ x, const float* __restrict__ w,
    const float* __restrict__ b, float* __restrict__ o,
    _Float16* __restrict__ oh, float* __restrict__ avec,
    const float* __restrict__ b2)
{
    int row = blockIdx.x;
    int tid = threadIdx.x;
    const float* xr = x + (size_t)row * DM;
    float v0 = xr[tid], v1 = xr[tid + 256];
    float s = v0 + v1, ss = v0 * v0 + v1 * v1;
    for (int off = 32; off; off >>= 1) {
        s += __shfl_down(s, off, 64);
        ss += __shfl_down(ss, off, 64);
    }
    __shared__ float sm[4], sm2[4];
    int wave = tid >> 6, lane = tid & 63;
    if (lane == 0) { sm[wave] = s; sm2[wave] = ss; }
    __syncthreads();
    float tot = sm[0] + sm[1] + sm[2] + sm[3];
    float tot2 = sm2[0] + sm2[1] + sm2[2] + sm2[3];
    float mu = tot * (1.f / DM);
    float var = tot2 * (1.f / DM) - mu * mu;
    float rs = rsqrtf(var + 1e-5f);
    float y0 = (v0 - mu) * rs * w[tid] + b[tid];
    float y1 = (v1 - mu) * rs * w[tid + 256] + b[tid + 256];
    o[(size_t)row * DM + tid] = y0;
    o[(size_t)row * DM + tid + 256] = y1;
    if (oh) {
        oh[(size_t)row * DM + tid] = (_Float16)y0;
        oh[(size_t)row * DM + tid + 256] = (_Float16)y1;
    }
    if (avec && tid == 0) avec[row] = b2[0];
}

// ---------------- permuted causal conv (K=4) + SiLU; fp16 out; zeroes dbl -----
__global__ __launch_bounds__(256) void conv_silu_k(
    const _Float16* __restrict__ xz, const int* __restrict__ perm,
    const float* __restrict__ cw, const float* __restrict__ cb,
    _Float16* __restrict__ xc, float* __restrict__ dbl)
{
    if (blockIdx.x < 256) {   // zero dbl (L*64 floats) for the split-K atomics
        int zi = (blockIdx.x * 256 + threadIdx.x) * 4;
        *(float4*)(dbl + zi) = make_float4(0.f, 0.f, 0.f, 0.f);
    }
    int g = blockIdx.x * 256 + threadIdx.x;   // g < L*DI
    int c = g & (DI - 1), p = g >> 10;
    float acc = cb[c];
#pragma unroll
    for (int k = 0; k < 4; ++k) {
        int q = p + k - 3;
        if (q >= 0)
            acc = fmaf((float)xz[(size_t)perm[q] * (2 * DI) + c], cw[c * 4 + k], acc);
    }
    float sig = 1.f / (1.f + __expf(-acc));
    xc[g] = (_Float16)(acc * sig);
}

// ---------------- chunked parallel selective scan (fp16 summaries) ------------
__global__ __launch_bounds__(256) void scan_pass1(
    const _Float16* __restrict__ dt, const _Float16* __restrict__ u,
    const float* __restrict__ dbl, const float* __restrict__ A_log,
    _Float16* __restrict__ Aprod, _Float16* __restrict__ carry)
{
    int c = blockIdx.x * 256 + threadIdx.x;
    int j = blockIdx.y;
    float Ac[16];
#pragma unroll
    for (int s = 0; s < 16; ++s) Ac[s] = -__expf(A_log[c * DS + s]);
    float ap[16], h[16];
#pragma unroll
    for (int s = 0; s < 16; ++s) { ap[s] = 1.f; h[s] = 0.f; }
    int t0 = j * CHK;
    for (int tt = 0; tt < CHK; ++tt) {
        int t = t0 + tt;
        float dtv = (float)dt[(size_t)t * DI + c];
        float uv  = (float)u[(size_t)t * DI + c];
        v4f Bv[4];
#pragma unroll
        for (int q = 0; q < 4; ++q)
            Bv[q] = *(const v4f*)(dbl + (size_t)t * 64 + DTR + q * 4);
        float du = dtv * uv;
#pragma unroll
        for (int s = 0; s < 16; ++s) {
            float dA = __expf(dtv * Ac[s]);
            h[s] = fmaf(dA, h[s], du * Bv[s >> 2][s & 3]);
            ap[s] *= dA;
        }
    }
    size_t base = ((size_t)j * DI + c) * DS;
#pragma unroll
    for (int q = 0; q < 4; ++q) {
        v4h av = {(_Float16)ap[q*4], (_Float16)ap[q*4+1], (_Float16)ap[q*4+2], (_Float16)ap[q*4+3]};
        v4h hv = {(_Float16)h[q*4], (_Float16)h[q*4+1], (_Float16)h[q*4+2], (_Float16)h[q*4+3]};
        *(v4h*)(Aprod + base + q * 4) = av;
        *(v4h*)(carry + base + q * 4) = hv;
    }
}

// Pass 2: exclusive prefix across chunks per (c,s); fp32 accumulate, fp16 out.
__global__ __launch_bounds__(256) void scan_pass2(
    const _Float16* __restrict__ Aprod, const _Float16* __restrict__ carry,
    _Float16* __restrict__ Hin)
{
    int idx = blockIdx.x * 256 + threadIdx.x;  // (c,s) flat, 16384 total
    float H = 0.f;
    Hin[idx] = (_Float16)0.f;
    for (int j = 1; j < NCH; ++j) {
        H = fmaf((float)Aprod[(size_t)(j - 1) * (DI * DS) + idx], H,
                 (float)carry[(size_t)(j - 1) * (DI * DS) + idx]);
        Hin[(size_t)j * (DI * DS) + idx] = (_Float16)H;
    }
}

// Pass 3: seeded local scan; gated output scattered, fp16 for out_proj.
__global__ __launch_bounds__(256) void scan_pass3(
    const _Float16* __restrict__ dt, const _Float16* __restrict__ u,
    const float* __restrict__ dbl, const _Float16* __restrict__ xz,
    const float* __restrict__ A_log, const float* __restrict__ Dsk,
    const int* __restrict__ perm, const _Float16* __restrict__ Hin,
    _Float16* __restrict__ yo)
{
    int c = blockIdx.x * 256 + threadIdx.x;
    int j = blockIdx.y;
    float Ac[16];
#pragma unroll
    for (int s = 0; s < 16; ++s) Ac[s] = -__expf(A_log[c * DS + s]);
    float Dp = Dsk[c];
    float h[16];
    size_t hbase = ((size_t)j * DI + c) * DS;
#pragma unroll
    for (int q = 0; q < 4; ++q) {
        v4h hv = *(const v4h*)(Hin + hbase + q * 4);
#pragma unroll
        for (int r = 0; r < 4; ++r) h[q * 4 + r] = (float)hv[r];
    }
    int t0 = j * CHK;
    for (int tt = 0; tt < CHK; ++tt) {
        int t = t0 + tt;
        float dtv = (float)dt[(size_t)t * DI + c];
        float uv  = (float)u[(size_t)t * DI + c];
        v4f Bv[4], Cv[4];
#pragma unroll
        for (int q = 0; q < 4; ++q) {
            Bv[q] = *(const v4f*)(dbl + (size_t)t * 64 + DTR + q * 4);
            Cv[q] = *(const v4f*)(dbl + (size_t)t * 64 + DTR + DS + q * 4);
        }
        float du = dtv * uv;
        float y = 0.f;
#pragma unroll
        for (int s = 0; s < 16; ++s) {
            float dA = __expf(dtv * Ac[s]);
            h[s] = fmaf(dA, h[s], du * Bv[s >> 2][s & 3]);
            y = fmaf(h[s], Cv[s >> 2][s & 3], y);
        }
        int tp = perm[t];
        float z = (float)xz[(size_t)tp * (2 * DI) + DI + c];
        float sig = 1.f / (1.f + __expf(-z));
        yo[(size_t)tp * DI + c] = (_Float16)((y + uv * Dp) * (z * sig));
    }
}

// ---------------- softmax over 4096 (single block); zeroes pooled -------------
__global__ __launch_bounds__(1024) void softmax_k(
    const float* __restrict__ a, float* __restrict__ out,
    float* __restrict__ pooled)
{
    int tid = threadIdx.x;
    if (tid < DM) pooled[tid] = 0.f;
    float v[4];
    float mx = -1e30f;
#pragma unroll
    for (int i = 0; i < 4; ++i) { v[i] = a[tid + i * 1024]; mx = fmaxf(mx, v[i]); }
    __shared__ float sm[16];
    for (int off = 32; off; off >>= 1) mx = fmaxf(mx, __shfl_xor(mx, off, 64));
    int wave = tid >> 6, lane = tid & 63;
    if (lane == 0) sm[wave] = mx;
    __syncthreads();
    if (tid < 16) {
        float m = sm[tid];
        for (int off = 8; off; off >>= 1) m = fmaxf(m, __shfl_xor(m, off, 64));
        sm[tid] = m;
    }
    __syncthreads();
    mx = sm[0];
    float s = 0.f;
#pragma unroll
    for (int i = 0; i < 4; ++i) { v[i] = __expf(v[i] - mx); s += v[i]; }
    for (int off = 32; off; off >>= 1) s += __shfl_xor(s, off, 64);
    __syncthreads();
    if (lane == 0) sm[wave] = s;
    __syncthreads();
    if (tid < 16) {
        float t2 = sm[tid];
        for (int off = 8; off; off >>= 1) t2 += __shfl_xor(t2, off, 64);
        sm[tid] = t2;
    }
    __syncthreads();
    float inv = 1.f / sm[0];
#pragma unroll
    for (int i = 0; i < 4; ++i) out[tid + i * 1024] = v[i] * inv;
}

__global__ __launch_bounds__(512) void pool_k(
    const float* __restrict__ aatt, const float* __restrict__ h,
    float* __restrict__ pooled)
{
    int m = threadIdx.x;
    int t0 = blockIdx.x * 128;
    float acc = 0.f;
    for (int r = 0; r < 128; ++r) {
        int t = t0 + r;
        acc = fmaf(aatt[t], h[(size_t)t * DM + m], acc);
    }
    atomicAdd(&pooled[m], acc);
}

__global__ __launch_bounds__(64) void out2048_k(
    const float* __restrict__ pooled, const float* __restrict__ w,
    const float* __restrict__ b, float* __restrict__ out)
{
    int n = blockIdx.x;
    int lane = threadIdx.x;
    const float* wr = w + (size_t)n * DM;
    float acc = 0.f;
#pragma unroll
    for (int k = 0; k < 8; ++k)
        acc = fmaf(wr[lane + k * 64], pooled[lane + k * 64], acc);
    for (int off = 32; off; off >>= 1) acc += __shfl_xor(acc, off, 64);
    if (lane == 0) out[n] = acc + b[n];
}

extern "C" void kernel_launch(void* const* d_in, const int* in_sizes, int n_in,
                              void* d_out, int out_size, void* d_ws, size_t ws_size,
                              hipStream_t stream) {
    const float* x     = (const float*)d_in[0];
    const int*   rate  = (const int*)d_in[1];
    const float* fc1_w = (const float*)d_in[2];
    const float* fc1_b = (const float*)d_in[3];
    const float* ln_w  = (const float*)d_in[4];
    const float* ln_b  = (const float*)d_in[5];
    const float* ipw   = (const float*)d_in[6];
    const float* cw    = (const float*)d_in[7];
    const float* cb    = (const float*)d_in[8];
    const float* xpw   = (const float*)d_in[9];
    const float* dtw   = (const float*)d_in[10];
    const float* dtpb  = (const float*)d_in[11];
    const float* A_log = (const float*)d_in[12];
    const float* Dsk   = (const float*)d_in[13];
    const float* opw   = (const float*)d_in[14];
    const float* nw    = (const float*)d_in[15];
    const float* nb    = (const float*)d_in[16];
    const float* aw1   = (const float*)d_in[17];
    const float* ab1   = (const float*)d_in[18];
    const float* aw2   = (const float*)d_in[19];
    const float* ab2   = (const float*)d_in[20];
    const float* ow    = (const float*)d_in[21];
    const float* ob    = (const float*)d_in[22];
    float* out = (float*)d_out;

    int* perm = (int*)d_ws;
    float* f = (float*)d_ws + 4096;
    float* h    = f; f += (size_t)L * DM;
    float* hln  = f; f += (size_t)L * DM;
    float* dbl  = f; f += (size_t)L * 64;
    float* avec = f; f += L;
    float* pooled = f; f += DM;
    _Float16* fh = (_Float16*)f;
    _Float16* xh     = fh; fh += (size_t)L * DIN;
    _Float16* hln_h  = fh; fh += (size_t)L * DM;
    _Float16* yo_h   = fh; fh += (size_t)L * DI;
    _Float16* xz_h   = fh; fh += (size_t)L * 2 * DI;
    _Float16* xc_h   = fh; fh += (size_t)L * DI;
    _Float16* dtv_h  = fh; fh += (size_t)L * DI;
    _Float16* Aprod  = fh; fh += (size_t)NCH * DI * DS;
    _Float16* carry  = fh; fh += (size_t)NCH * DI * DS;
    _Float16* Hin    = fh; fh += (size_t)NCH * DI * DS;
    _Float16* fc1w_h = fh; fh += (size_t)DM * DIN;
    _Float16* ipw_h  = fh; fh += (size_t)2 * 2 * DI * DM;
    _Float16* opw_h  = fh; fh += (size_t)2 * DM * DI;
    _Float16* xpw_h  = fh; fh += (size_t)2 * 64 * DI;
    _Float16* aw1_h  = fh; fh += (size_t)128 * DM;

    // perm + all fp32->fp16 conversions in one launch
    f2h_multi_k<<<16 + (L * DIN + DM * DIN + 2 * 2 * DI * DM + 2 * DM * DI
                   + 2 * 64 * DI + 128 * DM) / 1024, 256, 0, stream>>>(
        rate, perm,
        x, xh, L * DIN / 1024,
        fc1_w, fc1w_h, DM * DIN / 1024,
        ipw, ipw_h, 2 * 2 * DI * DM / 1024,
        opw, opw_h, 2 * DM * DI / 1024,
        xpw, xpw_h, 2 * 64 * DI / 1024,
        aw1, aw1_h, 128 * DM / 1024);

    // h = relu(x @ fc1_w^T + fc1_b)   [fp16 MFMA, N64 tile -> 256 blocks]
    hgemm_nt<1, 64, 0><<<dim3(DM / 64, L / 128), 256, 0, stream>>>(
        xh, DIN, fc1w_h, DIN, h, DM, fc1_b, DIN, 0);

    for (int l = 0; l < 2; ++l) {
        layernorm_k<<<L, 256, 0, stream>>>(h, ln_w + l * DM, ln_b + l * DM,
                                           hln, hln_h, nullptr, nullptr);
        // xz = hln @ in_proj^T   [fp16 MFMA -> fp16 out, 512 blocks]
        hgemm_nt<0, 128, 1><<<dim3(2 * DI / 128, L / 128), 256, 0, stream>>>(
            hln_h, DM, ipw_h + (size_t)l * 2 * DI * DM, DM, xz_h, 2 * DI,
            nullptr, DM, 0);
        // xc = silu(causal_conv(x_perm)) -> fp16; also zeroes dbl
        conv_silu_k<<<L * DI / 256, 256, 0, stream>>>(
            xz_h, perm, cw + (size_t)l * DI * 4, cb + (size_t)l * DI, xc_h, dbl);
        // dbl += xc_h @ xpw_h^T  [fp16 MFMA split-K 8 -> 256 blocks]
        hgemm_xproj<<<dim3(1, L / 128, 8), 256, 0, stream>>>(
            xc_h, xpw_h + (size_t)l * 64 * DI, dbl);
        // dtv_h = softplus(dbl[:, :32] @ dt_proj^T + dtb)  (fp16 out)
        gemm_dt<<<dim3(DI / 64, L / 64), 256, 0, stream>>>(
            dbl, 64, dtw + (size_t)l * DI * DTR, DTR, dtv_h, DI,
            dtpb + (size_t)l * DI, DTR);
        // chunked parallel selective scan (256 chunks -> 1024 blocks)
        scan_pass1<<<dim3(DI / 256, NCH), 256, 0, stream>>>(
            dtv_h, xc_h, dbl, A_log + (size_t)l * DI * DS, Aprod, carry);
        scan_pass2<<<DI * DS / 256, 256, 0, stream>>>(Aprod, carry, Hin);
        scan_pass3<<<dim3(DI / 256, NCH), 256, 0, stream>>>(
            dtv_h, xc_h, dbl, xz_h, A_log + (size_t)l * DI * DS,
            Dsk + (size_t)l * DI, perm, Hin, yo_h);
        // h += yo @ out_proj^T   [fp16 MFMA, N64 tile -> 256 blocks, accumulate]
        hgemm_nt<0, 64, 0><<<dim3(DM / 64, L / 128), 256, 0, stream>>>(
            yo_h, DI, opw_h + (size_t)l * DM * DI, DI, h, DM, nullptr, DI, 1);
    }

    // final LN: fp32 + fp16 out, seeds avec with attn bias b2
    layernorm_k<<<L, 256, 0, stream>>>(h, nw, nb, hln, hln_h, avec, ab2);
    // fused attn: avec += tanh(hln_h @ aw1_h^T + ab1) . w2   [fp16 MFMA]
    hgemm_attn<<<dim3(2, L / 128), 256, 0, stream>>>(
        hln_h, aw1_h, ab1, aw2, avec);
    softmax_k<<<1, 1024, 0, stream>>>(avec, out + 2048, pooled);
    pool_k<<<32, 512, 0, stream>>>(out + 2048, hln, pooled);
    out2048_k<<<2048, 64, 0, stream>>>(pooled, ow, ob, out);
}

// Round 13
// 504.314 us; speedup vs baseline: 1.2295x; 1.0077x over previous
//
#include <hip/hip_runtime.h>
#include <hip/hip_fp16.h>
#include <math.h>

#define L 4096
#define DIN 1024
#define DM 512
#define DI 1024
#define DS 16
#define DTR 32
#define NCH 256
#define CHK 16   // NCH*CHK == L

typedef _Float16 v8h __attribute__((ext_vector_type(8)));
typedef _Float16 v4h __attribute__((ext_vector_type(4)));
typedef float v4f __attribute__((ext_vector_type(4)));

// ------- perm + fp32->fp16 convert (6 segments), single launch ---------------
__global__ __launch_bounds__(256) void f2h_multi_k(
    const int* __restrict__ ratep, int* __restrict__ perm,
    const float* __restrict__ s0, _Float16* __restrict__ d0, int b0,
    const float* __restrict__ s1, _Float16* __restrict__ d1, int b1,
    const float* __restrict__ s2, _Float16* __restrict__ d2, int b2,
    const float* __restrict__ s3, _Float16* __restrict__ d3, int b3,
    const float* __restrict__ s4, _Float16* __restrict__ d4, int b4,
    const float* __restrict__ s5, _Float16* __restrict__ d5, int b5)
{
    int b = blockIdx.x;
    if (b < 16) {
        int p = b * 256 + threadIdx.x;
        int rate = ratep[0];
        int cum = 0;
        for (int g = 0; g < rate; ++g) {
            int sz = (L - g + rate - 1) / rate;
            if (p < cum + sz) { perm[p] = g + rate * (p - cum); return; }
            cum += sz;
        }
        return;
    }
    b -= 16;
    const float* src; _Float16* dst; int lb;
    if (b < b0)                          { src = s0; dst = d0; lb = b; }
    else if (b < b0 + b1)                { src = s1; dst = d1; lb = b - b0; }
    else if (b < b0 + b1 + b2)           { src = s2; dst = d2; lb = b - b0 - b1; }
    else if (b < b0 + b1 + b2 + b3)      { src = s3; dst = d3; lb = b - b0 - b1 - b2; }
    else if (b < b0 + b1 + b2 + b3 + b4) { src = s4; dst = d4; lb = b - b0 - b1 - b2 - b3; }
    else                                 { src = s5; dst = d5; lb = b - b0 - b1 - b2 - b3 - b4; }
    int i = (lb * 256 + threadIdx.x) * 4;
    float4 v = *(const float4*)(src + i);
    _Float16 h4[4] = {(_Float16)v.x, (_Float16)v.y, (_Float16)v.z, (_Float16)v.w};
    *(uint2*)(dst + i) = *(uint2*)h4;
}

// ---------------- fp16 MFMA GEMM, BK=64 (reg prefetch, padded LDS) ------------
// C = act(A(MxK)*B(NxK)^T + bias) [+C]. BNT=128: 4 waves 64x64; BNT=64: 4 waves
// 32x64. Two 32-deep MFMA sub-steps per barrier pair (halves barrier count).
// Requires K % 64 == 0 (all call sites: 512 or 1024).
template<int ACT, int BNT, int HALF>   // ACT: 0 none, 1 relu
__global__ __launch_bounds__(256) void hgemm_nt(
    const _Float16* __restrict__ A, int lda,
    const _Float16* __restrict__ B, int ldb,
    void* __restrict__ Cv, int ldc,
    const float* __restrict__ bias, int K, int accum)
{
    constexpr int MI = (BNT == 128) ? 4 : 2;
    __shared__ _Float16 As[128][72];   // 64+8 pad; row stride 144 B (16B-aligned)
    __shared__ _Float16 Bs[BNT][72];
    int tid = threadIdx.x;
    int m0 = blockIdx.y * 128, n0 = blockIdx.x * BNT;
    int lane = tid & 63, wave = tid >> 6;
    int wm, wn;
    if constexpr (BNT == 128) { wm = (wave >> 1) * 64; wn = (wave & 1) * 64; }
    else                      { wm = wave * 32;        wn = 0; }
    int quad = lane >> 4, r16 = lane & 15;
    v4f acc[MI][4] = {};

    // A staging: thread -> row = tid>>1 (0..127), col half = (tid&1)*32; 4 uint4
    int srow = tid >> 1;
    int scol = (tid & 1) * 32;
    const _Float16* Ag = A + (size_t)(m0 + srow) * lda + scol;
    // B staging: BNT=128 mirrors A; BNT=64: row = tid>>2, colq = (tid&3)*16; 2 uint4
    int srowB = (BNT == 128) ? srow : (tid >> 2);
    int scolB = (BNT == 128) ? scol : (tid & 3) * 16;
    const _Float16* Bg = B + (size_t)(n0 + srowB) * ldb + scolB;

    uint4 a0, a1, a2, a3, b0, b1, b2, b3;
    a0 = *(const uint4*)(Ag);      a1 = *(const uint4*)(Ag + 8);
    a2 = *(const uint4*)(Ag + 16); a3 = *(const uint4*)(Ag + 24);
    b0 = *(const uint4*)(Bg);      b1 = *(const uint4*)(Bg + 8);
    if constexpr (BNT == 128) {
        b2 = *(const uint4*)(Bg + 16); b3 = *(const uint4*)(Bg + 24);
    }

    int KS = K / 64;
    for (int ks = 0; ks < KS; ++ks) {
        __syncthreads();
        *(uint4*)&As[srow][scol]      = a0;
        *(uint4*)&As[srow][scol + 8]  = a1;
        *(uint4*)&As[srow][scol + 16] = a2;
        *(uint4*)&As[srow][scol + 24] = a3;
        *(uint4*)&Bs[srowB][scolB]     = b0;
        *(uint4*)&Bs[srowB][scolB + 8] = b1;
        if constexpr (BNT == 128) {
            *(uint4*)&Bs[srowB][scolB + 16] = b2;
            *(uint4*)&Bs[srowB][scolB + 24] = b3;
        }
        __syncthreads();
        if (ks + 1 < KS) {
            int k0 = (ks + 1) * 64;
            a0 = *(const uint4*)(Ag + k0);      a1 = *(const uint4*)(Ag + k0 + 8);
            a2 = *(const uint4*)(Ag + k0 + 16); a3 = *(const uint4*)(Ag + k0 + 24);
            b0 = *(const uint4*)(Bg + k0);      b1 = *(const uint4*)(Bg + k0 + 8);
            if constexpr (BNT == 128) {
                b2 = *(const uint4*)(Bg + k0 + 16); b3 = *(const uint4*)(Bg + k0 + 24);
            }
        }
#pragma unroll
        for (int kk = 0; kk < 2; ++kk) {
            v8h af[MI], bf[4];
#pragma unroll
            for (int i = 0; i < MI; ++i)
                af[i] = *(const v8h*)&As[wm + i * 16 + r16][kk * 32 + quad * 8];
#pragma unroll
            for (int j = 0; j < 4; ++j)
                bf[j] = *(const v8h*)&Bs[wn + j * 16 + r16][kk * 32 + quad * 8];
#pragma unroll
            for (int i = 0; i < MI; ++i)
#pragma unroll
                for (int j = 0; j < 4; ++j)
                    acc[i][j] = __builtin_amdgcn_mfma_f32_16x16x32_f16(
                        af[i], bf[j], acc[i][j], 0, 0, 0);
        }
    }

    // C/D layout: col = lane&15, row = (lane>>4)*4 + reg
#pragma unroll
    for (int i = 0; i < MI; ++i) {
#pragma unroll
        for (int j = 0; j < 4; ++j) {
            int col = n0 + wn + j * 16 + r16;
            int rbase = m0 + wm + i * 16 + quad * 4;
            float bv = bias ? bias[col] : 0.f;
#pragma unroll
            for (int r = 0; r < 4; ++r) {
                float v = acc[i][j][r] + bv;
                if (ACT == 1) v = fmaxf(v, 0.f);
                if constexpr (HALF) {
                    ((_Float16*)Cv)[(size_t)(rbase + r) * ldc + col] = (_Float16)v;
                } else {
                    float* p = (float*)Cv + (size_t)(rbase + r) * ldc + col;
                    if (accum) v += *p;
                    *p = v;
                }
            }
        }
    }
}

// ---------------- x_proj fp16 MFMA split-K: dbl += xc_h @ xpw_h^T -------------
__global__ __launch_bounds__(256) void hgemm_xproj(
    const _Float16* __restrict__ A,    // xc_h, lda=DI
    const _Float16* __restrict__ B,    // xpw_h (64 x DI)
    float* __restrict__ C)             // dbl, ldc=64
{
    __shared__ _Float16 As[128][40];
    __shared__ _Float16 Bs[64][40];
    int tid = threadIdx.x;
    int m0 = blockIdx.y * 128;
    int kb = blockIdx.z * 128;
    int lane = tid & 63, wave = tid >> 6;
    int wm = wave * 32;
    int quad = lane >> 4, r16 = lane & 15;
    v4f acc[2][4] = {};

    int srow = tid >> 1, scol = (tid & 1) * 16;
    const _Float16* Ag = A + (size_t)(m0 + srow) * DI + kb + scol;
    int srowB = tid >> 2, scolB = (tid & 3) * 8;
    const _Float16* Bg = B + (size_t)srowB * DI + kb + scolB;

    uint4 a0 = *(const uint4*)(Ag);
    uint4 a1 = *(const uint4*)(Ag + 8);
    uint4 b0 = *(const uint4*)(Bg);

    for (int ks = 0; ks < 4; ++ks) {
        __syncthreads();
        *(uint4*)&As[srow][scol] = a0;
        *(uint4*)&As[srow][scol + 8] = a1;
        *(uint4*)&Bs[srowB][scolB] = b0;
        __syncthreads();
        if (ks + 1 < 4) {
            int k0 = (ks + 1) * 32;
            a0 = *(const uint4*)(Ag + k0);
            a1 = *(const uint4*)(Ag + k0 + 8);
            b0 = *(const uint4*)(Bg + k0);
        }
        v8h af[2], bf[4];
#pragma unroll
        for (int i = 0; i < 2; ++i)
            af[i] = *(const v8h*)&As[wm + i * 16 + r16][quad * 8];
#pragma unroll
        for (int j = 0; j < 4; ++j)
            bf[j] = *(const v8h*)&Bs[j * 16 + r16][quad * 8];
#pragma unroll
        for (int i = 0; i < 2; ++i)
#pragma unroll
            for (int j = 0; j < 4; ++j)
                acc[i][j] = __builtin_amdgcn_mfma_f32_16x16x32_f16(
                    af[i], bf[j], acc[i][j], 0, 0, 0);
    }
#pragma unroll
    for (int i = 0; i < 2; ++i) {
#pragma unroll
        for (int j = 0; j < 4; ++j) {
            int col = j * 16 + r16;
            int rbase = m0 + wm + i * 16 + quad * 4;
#pragma unroll
            for (int r = 0; r < 4; ++r)
                atomicAdd(&C[(size_t)(rbase + r) * 64 + col], acc[i][j][r]);
        }
    }
}

// ---------------- attn fp16 MFMA: avec[row] += tanh(hln_h@aw1_h^T + b1).w2 ----
__global__ __launch_bounds__(256) void hgemm_attn(
    const _Float16* __restrict__ A,    // hln_h, lda=DM
    const _Float16* __restrict__ B,    // aw1_h (128 x DM)
    const float* __restrict__ b1, const float* __restrict__ w2,
    float* __restrict__ avec)
{
    __shared__ _Float16 As[128][40];
    __shared__ _Float16 Bs[64][40];
    int tid = threadIdx.x;
    int m0 = blockIdx.y * 128, n0 = blockIdx.x * 64;
    int lane = tid & 63, wave = tid >> 6;
    int wm = wave * 32;
    int quad = lane >> 4, r16 = lane & 15;
    v4f acc[2][4] = {};

    int srow = tid >> 1, scol = (tid & 1) * 16;
    const _Float16* Ag = A + (size_t)(m0 + srow) * DM + scol;
    int srowB = tid >> 2, scolB = (tid & 3) * 8;
    const _Float16* Bg = B + (size_t)(n0 + srowB) * DM + scolB;

    uint4 a0 = *(const uint4*)(Ag);
    uint4 a1 = *(const uint4*)(Ag + 8);
    uint4 b0 = *(const uint4*)(Bg);

    for (int ks = 0; ks < DM / 32; ++ks) {
        __syncthreads();
        *(uint4*)&As[srow][scol] = a0;
        *(uint4*)&As[srow][scol + 8] = a1;
        *(uint4*)&Bs[srowB][scolB] = b0;
        __syncthreads();
        if (ks + 1 < DM / 32) {
            int k0 = (ks + 1) * 32;
            a0 = *(const uint4*)(Ag + k0);
            a1 = *(const uint4*)(Ag + k0 + 8);
            b0 = *(const uint4*)(Bg + k0);
        }
        v8h af[2], bf[4];
#pragma unroll
        for (int i = 0; i < 2; ++i)
            af[i] = *(const v8h*)&As[wm + i * 16 + r16][quad * 8];
#pragma unroll
        for (int j = 0; j < 4; ++j)
            bf[j] = *(const v8h*)&Bs[j * 16 + r16][quad * 8];
#pragma unroll
        for (int i = 0; i < 2; ++i)
#pragma unroll
            for (int j = 0; j < 4; ++j)
                acc[i][j] = __builtin_amdgcn_mfma_f32_16x16x32_f16(
                    af[i], bf[j], acc[i][j], 0, 0, 0);
    }

#pragma unroll
    for (int i = 0; i < 2; ++i) {
        float part[4] = {0.f, 0.f, 0.f, 0.f};
#pragma unroll
        for (int j = 0; j < 4; ++j) {
            int col = n0 + j * 16 + r16;
            float bv = b1[col], wv = w2[col];
#pragma unroll
            for (int r = 0; r < 4; ++r)
                part[r] = fmaf(tanhf(acc[i][j][r] + bv), wv, part[r]);
        }
#pragma unroll
        for (int r = 0; r < 4; ++r) {
            part[r] += __shfl_xor(part[r], 1, 64);
            part[r] += __shfl_xor(part[r], 2, 64);
            part[r] += __shfl_xor(part[r], 4, 64);
            part[r] += __shfl_xor(part[r], 8, 64);
        }
        if (r16 == 0) {
            int rbase = m0 + wm + i * 16 + quad * 4;
#pragma unroll
            for (int r = 0; r < 4; ++r)
                atomicAdd(&avec[rbase + r], part[r]);
        }
    }
}

// ------- dt GEMM (fp32 SIMT, K=32): dtv_h = softplus(dbl[:,:32]@dtw^T + b) ----
#define BM 64
#define BN 64
#define BKK 32
__global__ __launch_bounds__(256) void gemm_dt(
    const float* __restrict__ A, int lda,
    const float* __restrict__ B, int ldb,
    _Float16* __restrict__ C, int ldc,
    const float* __restrict__ bias, int K)
{
    __shared__ float As[BKK][BM + 4];
    __shared__ float Bs[BKK][BN + 4];
    int tid = threadIdx.x;
    int m0 = blockIdx.y * BM;
    int n0 = blockIdx.x * BN;
    int tx = tid & 15, ty = tid >> 4;
    float acc[4][4] = {};
    int arow = tid >> 3;       // 0..31
    int ak = (tid & 7) * 4;    // 0..28

    for (int k0 = 0; k0 < K; k0 += BKK) {
#pragma unroll
        for (int r = 0; r < 2; ++r) {
            int row = arow + r * 32;
            float4 va = *(const float4*)(A + (size_t)(m0 + row) * lda + k0 + ak);
            As[ak + 0][row] = va.x; As[ak + 1][row] = va.y;
            As[ak + 2][row] = va.z; As[ak + 3][row] = va.w;
            float4 vb = *(const float4*)(B + (size_t)(n0 + row) * ldb + k0 + ak);
            Bs[ak + 0][row] = vb.x; Bs[ak + 1][row] = vb.y;
            Bs[ak + 2][row] = vb.z; Bs[ak + 3][row] = vb.w;
        }
        __syncthreads();
#pragma unroll
        for (int kk = 0; kk < BKK; ++kk) {
            float4 a4 = *(const float4*)&As[kk][ty * 4];
            float4 b4 = *(const float4*)&Bs[kk][tx * 4];
            float a[4] = {a4.x, a4.y, a4.z, a4.w};
            float b[4] = {b4.x, b4.y, b4.z, b4.w};
#pragma unroll
            for (int i = 0; i < 4; ++i)
#pragma unroll
                for (int j = 0; j < 4; ++j)
                    acc[i][j] = fmaf(a[i], b[j], acc[i][j]);
        }
        __syncthreads();
    }

#pragma unroll
    for (int i = 0; i < 4; ++i) {
        int row = m0 + ty * 4 + i;
        int col = n0 + tx * 4;
        _Float16 v4[4];
#pragma unroll
        for (int j = 0; j < 4; ++j) {
            float xv = acc[i][j] + bias[col + j];
            xv = (xv > 20.f) ? xv : log1pf(__expf(xv));
            v4[j] = (_Float16)xv;
        }
        *(uint2*)(C + (size_t)row * ldc + col) = *(uint2*)v4;
    }
}

// ---------------- layernorm (D=512); optional fp16 side-out; optional avec init
__global__ __launch_bounds__(256) void layernorm_k(
    const float* __restrict__ x, const float* __restrict__ w,
    const float* __restrict__ b, float* __restrict__ o,
    _Float16* __restrict__ oh, float* __restrict__ avec,
    const float* __restrict__ b2)
{
    int row = blockIdx.x;
    int tid = threadIdx.x;
    const float* xr = x + (size_t)row * DM;
    float v0 = xr[tid], v1 = xr[tid + 256];
    float s = v0 + v1, ss = v0 * v0 + v1 * v1;
    for (int off = 32; off; off >>= 1) {
        s += __shfl_down(s, off, 64);
        ss += __shfl_down(ss, off, 64);
    }
    __shared__ float sm[4], sm2[4];
    int wave = tid >> 6, lane = tid & 63;
    if (lane == 0) { sm[wave] = s; sm2[wave] = ss; }
    __syncthreads();
    float tot = sm[0] + sm[1] + sm[2] + sm[3];
    float tot2 = sm2[0] + sm2[1] + sm2[2] + sm2[3];
    float mu = tot * (1.f / DM);
    float var = tot2 * (1.f / DM) - mu * mu;
    float rs = rsqrtf(var + 1e-5f);
    float y0 = (v0 - mu) * rs * w[tid] + b[tid];
    float y1 = (v1 - mu) * rs * w[tid + 256] + b[tid + 256];
    o[(size_t)row * DM + tid] = y0;
    o[(size_t)row * DM + tid + 256] = y1;
    if (oh) {
        oh[(size_t)row * DM + tid] = (_Float16)y0;
        oh[(size_t)row * DM + tid + 256] = (_Float16)y1;
    }
    if (avec && tid == 0) avec[row] = b2[0];
}

// ---------------- permuted causal conv (K=4) + SiLU; fp16 out; zeroes dbl -----
__global__ __launch_bounds__(256) void conv_silu_k(
    const _Float16* __restrict__ xz, const int* __restrict__ perm,
    const float* __restrict__ cw, const float* __restrict__ cb,
    _Float16* __restrict__ xc, float* __restrict__ dbl)
{
    if (blockIdx.x < 256) {   // zero dbl (L*64 floats) for the split-K atomics
        int zi = (blockIdx.x * 256 + threadIdx.x) * 4;
        *(float4*)(dbl + zi) = make_float4(0.f, 0.f, 0.f, 0.f);
    }
    int g = blockIdx.x * 256 + threadIdx.x;   // g < L*DI
    int c = g & (DI - 1), p = g >> 10;
    float acc = cb[c];
#pragma unroll
    for (int k = 0; k < 4; ++k) {
        int q = p + k - 3;
        if (q >= 0)
            acc = fmaf((float)xz[(size_t)perm[q] * (2 * DI) + c], cw[c * 4 + k], acc);
    }
    float sig = 1.f / (1.f + __expf(-acc));
    xc[g] = (_Float16)(acc * sig);
}

// ---------------- chunked parallel selective scan (fp16 summaries) ------------
__global__ __launch_bounds__(256) void scan_pass1(
    const _Float16* __restrict__ dt, const _Float16* __restrict__ u,
    const float* __restrict__ dbl, const float* __restrict__ A_log,
    _Float16* __restrict__ Aprod, _Float16* __restrict__ carry)
{
    int c = blockIdx.x * 256 + threadIdx.x;
    int j = blockIdx.y;
    float Ac[16];
#pragma unroll
    for (int s = 0; s < 16; ++s) Ac[s] = -__expf(A_log[c * DS + s]);
    float ap[16], h[16];
#pragma unroll
    for (int s = 0; s < 16; ++s) { ap[s] = 1.f; h[s] = 0.f; }
    int t0 = j * CHK;
    for (int tt = 0; tt < CHK; ++tt) {
        int t = t0 + tt;
        float dtv = (float)dt[(size_t)t * DI + c];
        float uv  = (float)u[(size_t)t * DI + c];
        v4f Bv[4];
#pragma unroll
        for (int q = 0; q < 4; ++q)
            Bv[q] = *(const v4f*)(dbl + (size_t)t * 64 + DTR + q * 4);
        float du = dtv * uv;
#pragma unroll
        for (int s = 0; s < 16; ++s) {
            float dA = __expf(dtv * Ac[s]);
            h[s] = fmaf(dA, h[s], du * Bv[s >> 2][s & 3]);
            ap[s] *= dA;
        }
    }
    size_t base = ((size_t)j * DI + c) * DS;
#pragma unroll
    for (int q = 0; q < 4; ++q) {
        v4h av = {(_Float16)ap[q*4], (_Float16)ap[q*4+1], (_Float16)ap[q*4+2], (_Float16)ap[q*4+3]};
        v4h hv = {(_Float16)h[q*4], (_Float16)h[q*4+1], (_Float16)h[q*4+2], (_Float16)h[q*4+3]};
        *(v4h*)(Aprod + base + q * 4) = av;
        *(v4h*)(carry + base + q * 4) = hv;
    }
}

__global__ __launch_bounds__(256) void scan_pass2(
    const _Float16* __restrict__ Aprod, const _Float16* __restrict__ carry,
    _Float16* __restrict__ Hin)
{
    int idx = blockIdx.x * 256 + threadIdx.x;  // (c,s) flat, 16384 total
    float H = 0.f;
    Hin[idx] = (_Float16)0.f;
    for (int j = 1; j < NCH; ++j) {
        H = fmaf((float)Aprod[(size_t)(j - 1) * (DI * DS) + idx], H,
                 (float)carry[(size_t)(j - 1) * (DI * DS) + idx]);
        Hin[(size_t)j * (DI * DS) + idx] = (_Float16)H;
    }
}

__global__ __launch_bounds__(256) void scan_pass3(
    const _Float16* __restrict__ dt, const _Float16* __restrict__ u,
    const float* __restrict__ dbl, const _Float16* __restrict__ xz,
    const float* __restrict__ A_log, const float* __restrict__ Dsk,
    const int* __restrict__ perm, const _Float16* __restrict__ Hin,
    _Float16* __restrict__ yo)
{
    int c = blockIdx.x * 256 + threadIdx.x;
    int j = blockIdx.y;
    float Ac[16];
#pragma unroll
    for (int s = 0; s < 16; ++s) Ac[s] = -__expf(A_log[c * DS + s]);
    float Dp = Dsk[c];
    float h[16];
    size_t hbase = ((size_t)j * DI + c) * DS;
#pragma unroll
    for (int q = 0; q < 4; ++q) {
        v4h hv = *(const v4h*)(Hin + hbase + q * 4);
#pragma unroll
        for (int r = 0; r < 4; ++r) h[q * 4 + r] = (float)hv[r];
    }
    int t0 = j * CHK;
    for (int tt = 0; tt < CHK; ++tt) {
        int t = t0 + tt;
        float dtv = (float)dt[(size_t)t * DI + c];
        float uv  = (float)u[(size_t)t * DI + c];
        v4f Bv[4], Cv[4];
#pragma unroll
        for (int q = 0; q < 4; ++q) {
            Bv[q] = *(const v4f*)(dbl + (size_t)t * 64 + DTR + q * 4);
            Cv[q] = *(const v4f*)(dbl + (size_t)t * 64 + DTR + DS + q * 4);
        }
        float du = dtv * uv;
        float y = 0.f;
#pragma unroll
        for (int s = 0; s < 16; ++s) {
            float dA = __expf(dtv * Ac[s]);
            h[s] = fmaf(dA, h[s], du * Bv[s >> 2][s & 3]);
            y = fmaf(h[s], Cv[s >> 2][s & 3], y);
        }
        int tp = perm[t];
        float z = (float)xz[(size_t)tp * (2 * DI) + DI + c];
        float sig = 1.f / (1.f + __expf(-z));
        yo[(size_t)tp * DI + c] = (_Float16)((y + uv * Dp) * (z * sig));
    }
}

// ---------------- softmax over 4096 (single block); zeroes pooled -------------
__global__ __launch_bounds__(1024) void softmax_k(
    const float* __restrict__ a, float* __restrict__ out,
    float* __restrict__ pooled)
{
    int tid = threadIdx.x;
    if (tid < DM) pooled[tid] = 0.f;
    float v[4];
    float mx = -1e30f;
#pragma unroll
    for (int i = 0; i < 4; ++i) { v[i] = a[tid + i * 1024]; mx = fmaxf(mx, v[i]); }
    __shared__ float sm[16];
    for (int off = 32; off; off >>= 1) mx = fmaxf(mx, __shfl_xor(mx, off, 64));
    int wave = tid >> 6, lane = tid & 63;
    if (lane == 0) sm[wave] = mx;
    __syncthreads();
    if (tid < 16) {
        float m = sm[tid];
        for (int off = 8; off; off >>= 1) m = fmaxf(m, __shfl_xor(m, off, 64));
        sm[tid] = m;
    }
    __syncthreads();
    mx = sm[0];
    float s = 0.f;
#pragma unroll
    for (int i = 0; i < 4; ++i) { v[i] = __expf(v[i] - mx); s += v[i]; }
    for (int off = 32; off; off >>= 1) s += __shfl_xor(s, off, 64);
    __syncthreads();
    if (lane == 0) sm[wave] = s;
    __syncthreads();
    if (tid < 16) {
        float t2 = sm[tid];
        for (int off = 8; off; off >>= 1) t2 += __shfl_xor(t2, off, 64);
        sm[tid] = t2;
    }
    __syncthreads();
    float inv = 1.f / sm[0];
#pragma unroll
    for (int i = 0; i < 4; ++i) out[tid + i * 1024] = v[i] * inv;
}

__global__ __launch_bounds__(512) void pool_k(
    const float* __restrict__ aatt, const float* __restrict__ h,
    float* __restrict__ pooled)
{
    int m = threadIdx.x;
    int t0 = blockIdx.x * 128;
    float acc = 0.f;
    for (int r = 0; r < 128; ++r) {
        int t = t0 + r;
        acc = fmaf(aatt[t], h[(size_t)t * DM + m], acc);
    }
    atomicAdd(&pooled[m], acc);
}

__global__ __launch_bounds__(64) void out2048_k(
    const float* __restrict__ pooled, const float* __restrict__ w,
    const float* __restrict__ b, float* __restrict__ out)
{
    int n = blockIdx.x;
    int lane = threadIdx.x;
    const float* wr = w + (size_t)n * DM;
    float acc = 0.f;
#pragma unroll
    for (int k = 0; k < 8; ++k)
        acc = fmaf(wr[lane + k * 64], pooled[lane + k * 64], acc);
    for (int off = 32; off; off >>= 1) acc += __shfl_xor(acc, off, 64);
    if (lane == 0) out[n] = acc + b[n];
}

extern "C" void kernel_launch(void* const* d_in, const int* in_sizes, int n_in,
                              void* d_out, int out_size, void* d_ws, size_t ws_size,
                              hipStream_t stream) {
    const float* x     = (const float*)d_in[0];
    const int*   rate  = (const int*)d_in[1];
    const float* fc1_w = (const float*)d_in[2];
    const float* fc1_b = (const float*)d_in[3];
    const float* ln_w  = (const float*)d_in[4];
    const float* ln_b  = (const float*)d_in[5];
    const float* ipw   = (const float*)d_in[6];
    const float* cw    = (const float*)d_in[7];
    const float* cb    = (const float*)d_in[8];
    const float* xpw   = (const float*)d_in[9];
    const float* dtw   = (const float*)d_in[10];
    const float* dtpb  = (const float*)d_in[11];
    const float* A_log = (const float*)d_in[12];
    const float* Dsk   = (const float*)d_in[13];
    const float* opw   = (const float*)d_in[14];
    const float* nw    = (const float*)d_in[15];
    const float* nb    = (const float*)d_in[16];
    const float* aw1   = (const float*)d_in[17];
    const float* ab1   = (const float*)d_in[18];
    const float* aw2   = (const float*)d_in[19];
    const float* ab2   = (const float*)d_in[20];
    const float* ow    = (const float*)d_in[21];
    const float* ob    = (const float*)d_in[22];
    float* out = (float*)d_out;

    int* perm = (int*)d_ws;
    float* f = (float*)d_ws + 4096;
    float* h    = f; f += (size_t)L * DM;
    float* hln  = f; f += (size_t)L * DM;
    float* dbl  = f; f += (size_t)L * 64;
    float* avec = f; f += L;
    float* pooled = f; f += DM;
    _Float16* fh = (_Float16*)f;
    _Float16* xh     = fh; fh += (size_t)L * DIN;
    _Float16* hln_h  = fh; fh += (size_t)L * DM;
    _Float16* yo_h   = fh; fh += (size_t)L * DI;
    _Float16* xz_h   = fh; fh += (size_t)L * 2 * DI;
    _Float16* xc_h   = fh; fh += (size_t)L * DI;
    _Float16* dtv_h  = fh; fh += (size_t)L * DI;
    _Float16* Aprod  = fh; fh += (size_t)NCH * DI * DS;
    _Float16* carry  = fh; fh += (size_t)NCH * DI * DS;
    _Float16* Hin    = fh; fh += (size_t)NCH * DI * DS;
    _Float16* fc1w_h = fh; fh += (size_t)DM * DIN;
    _Float16* ipw_h  = fh; fh += (size_t)2 * 2 * DI * DM;
    _Float16* opw_h  = fh; fh += (size_t)2 * DM * DI;
    _Float16* xpw_h  = fh; fh += (size_t)2 * 64 * DI;
    _Float16* aw1_h  = fh; fh += (size_t)128 * DM;

    // perm + all fp32->fp16 conversions in one launch
    f2h_multi_k<<<16 + (L * DIN + DM * DIN + 2 * 2 * DI * DM + 2 * DM * DI
                   + 2 * 64 * DI + 128 * DM) / 1024, 256, 0, stream>>>(
        rate, perm,
        x, xh, L * DIN / 1024,
        fc1_w, fc1w_h, DM * DIN / 1024,
        ipw, ipw_h, 2 * 2 * DI * DM / 1024,
        opw, opw_h, 2 * DM * DI / 1024,
        xpw, xpw_h, 2 * 64 * DI / 1024,
        aw1, aw1_h, 128 * DM / 1024);

    // h = relu(x @ fc1_w^T + fc1_b)   [fp16 MFMA, BK=64, N64 tile]
    hgemm_nt<1, 64, 0><<<dim3(DM / 64, L / 128), 256, 0, stream>>>(
        xh, DIN, fc1w_h, DIN, h, DM, fc1_b, DIN, 0);

    for (int l = 0; l < 2; ++l) {
        layernorm_k<<<L, 256, 0, stream>>>(h, ln_w + l * DM, ln_b + l * DM,
                                           hln, hln_h, nullptr, nullptr);
        // xz = hln @ in_proj^T   [fp16 MFMA, BK=64 -> fp16 out, 512 blocks]
        hgemm_nt<0, 128, 1><<<dim3(2 * DI / 128, L / 128), 256, 0, stream>>>(
            hln_h, DM, ipw_h + (size_t)l * 2 * DI * DM, DM, xz_h, 2 * DI,
            nullptr, DM, 0);
        // xc = silu(causal_conv(x_perm)) -> fp16; also zeroes dbl
        conv_silu_k<<<L * DI / 256, 256, 0, stream>>>(
            xz_h, perm, cw + (size_t)l * DI * 4, cb + (size_t)l * DI, xc_h, dbl);
        // dbl += xc_h @ xpw_h^T  [fp16 MFMA split-K 8 -> 256 blocks]
        hgemm_xproj<<<dim3(1, L / 128, 8), 256, 0, stream>>>(
            xc_h, xpw_h + (size_t)l * 64 * DI, dbl);
        // dtv_h = softplus(dbl[:, :32] @ dt_proj^T + dtb)  (fp16 out)
        gemm_dt<<<dim3(DI / 64, L / 64), 256, 0, stream>>>(
            dbl, 64, dtw + (size_t)l * DI * DTR, DTR, dtv_h, DI,
            dtpb + (size_t)l * DI, DTR);
        // chunked parallel selective scan (256 chunks -> 1024 blocks)
        scan_pass1<<<dim3(DI / 256, NCH), 256, 0, stream>>>(
            dtv_h, xc_h, dbl, A_log + (size_t)l * DI * DS, Aprod, carry);
        scan_pass2<<<DI * DS / 256, 256, 0, stream>>>(Aprod, carry, Hin);
        scan_pass3<<<dim3(DI / 256, NCH), 256, 0, stream>>>(
            dtv_h, xc_h, dbl, xz_h, A_log + (size_t)l * DI * DS,
            Dsk + (size_t)l * DI, perm, Hin, yo_h);
        // h += yo @ out_proj^T   [fp16 MFMA, BK=64, N64 tile, accumulate]
        hgemm_nt<0, 64, 0><<<dim3(DM / 64, L / 128), 256, 0, stream>>>(
            yo_h, DI, opw_h + (size_t)l * DM * DI, DI, h, DM, nullptr, DI, 1);
    }

    // final LN: fp32 + fp16 out, seeds avec with attn bias b2
    layernorm_k<<<L, 256, 0, stream>>>(h, nw, nb, hln, hln_h, avec, ab2);
    // fused attn: avec += tanh(hln_h @ aw1_h^T + ab1) . w2   [fp16 MFMA]
    hgemm_attn<<<dim3(2, L / 128), 256, 0, stream>>>(
        hln_h, aw1_h, ab1, aw2, avec);
    softmax_k<<<1, 1024, 0, stream>>>(avec, out + 2048, pooled);
    pool_k<<<32, 512, 0, stream>>>(out + 2048, hln, pooled);
    out2048_k<<<2048, 64, 0, stream>>>(pooled, ow, ob, out);
}

// Round 14
// 499.400 us; speedup vs baseline: 1.2416x; 1.0098x over previous
//
#include <hip/hip_runtime.h>
#include <hip/hip_fp16.h>
#include <math.h>

#define L 4096
#define DIN 1024
#define DM 512
#define DI 1024
#define DS 16
#define DTR 32
#define NCH 256
#define CHK 16   // NCH*CHK == L

typedef _Float16 v8h __attribute__((ext_vector_type(8)));
typedef _Float16 v4h __attribute__((ext_vector_type(4)));
typedef float v4f __attribute__((ext_vector_type(4)));

// ------- perm + ticket-zero + fp32->fp16 convert (6 segments), one launch ----
__global__ __launch_bounds__(256) void f2h_multi_k(
    const int* __restrict__ ratep, int* __restrict__ perm, int* __restrict__ ticket,
    const float* __restrict__ s0, _Float16* __restrict__ d0, int b0,
    const float* __restrict__ s1, _Float16* __restrict__ d1, int b1,
    const float* __restrict__ s2, _Float16* __restrict__ d2, int b2,
    const float* __restrict__ s3, _Float16* __restrict__ d3, int b3,
    const float* __restrict__ s4, _Float16* __restrict__ d4, int b4,
    const float* __restrict__ s5, _Float16* __restrict__ d5, int b5)
{
    int b = blockIdx.x;
    if (b < 16) {
        if (b == 0 && threadIdx.x == 0) *ticket = 0;
        int p = b * 256 + threadIdx.x;
        int rate = ratep[0];
        int cum = 0;
        for (int g = 0; g < rate; ++g) {
            int sz = (L - g + rate - 1) / rate;
            if (p < cum + sz) { perm[p] = g + rate * (p - cum); return; }
            cum += sz;
        }
        return;
    }
    b -= 16;
    const float* src; _Float16* dst; int lb;
    if (b < b0)                          { src = s0; dst = d0; lb = b; }
    else if (b < b0 + b1)                { src = s1; dst = d1; lb = b - b0; }
    else if (b < b0 + b1 + b2)           { src = s2; dst = d2; lb = b - b0 - b1; }
    else if (b < b0 + b1 + b2 + b3)      { src = s3; dst = d3; lb = b - b0 - b1 - b2; }
    else if (b < b0 + b1 + b2 + b3 + b4) { src = s4; dst = d4; lb = b - b0 - b1 - b2 - b3; }
    else                                 { src = s5; dst = d5; lb = b - b0 - b1 - b2 - b3 - b4; }
    int i = (lb * 256 + threadIdx.x) * 4;
    float4 v = *(const float4*)(src + i);
    _Float16 h4[4] = {(_Float16)v.x, (_Float16)v.y, (_Float16)v.z, (_Float16)v.w};
    *(uint2*)(dst + i) = *(uint2*)h4;
}

// ---------------- fp16 MFMA GEMM, BK=64 (reg prefetch, padded LDS) ------------
template<int ACT, int BNT, int HALF>   // ACT: 0 none, 1 relu
__global__ __launch_bounds__(256) void hgemm_nt(
    const _Float16* __restrict__ A, int lda,
    const _Float16* __restrict__ B, int ldb,
    void* __restrict__ Cv, int ldc,
    const float* __restrict__ bias, int K, int accum)
{
    constexpr int MI = (BNT == 128) ? 4 : 2;
    __shared__ _Float16 As[128][72];
    __shared__ _Float16 Bs[BNT][72];
    int tid = threadIdx.x;
    int m0 = blockIdx.y * 128, n0 = blockIdx.x * BNT;
    int lane = tid & 63, wave = tid >> 6;
    int wm, wn;
    if constexpr (BNT == 128) { wm = (wave >> 1) * 64; wn = (wave & 1) * 64; }
    else                      { wm = wave * 32;        wn = 0; }
    int quad = lane >> 4, r16 = lane & 15;
    v4f acc[MI][4] = {};

    int srow = tid >> 1;
    int scol = (tid & 1) * 32;
    const _Float16* Ag = A + (size_t)(m0 + srow) * lda + scol;
    int srowB = (BNT == 128) ? srow : (tid >> 2);
    int scolB = (BNT == 128) ? scol : (tid & 3) * 16;
    const _Float16* Bg = B + (size_t)(n0 + srowB) * ldb + scolB;

    uint4 a0, a1, a2, a3, b0, b1, b2, b3;
    a0 = *(const uint4*)(Ag);      a1 = *(const uint4*)(Ag + 8);
    a2 = *(const uint4*)(Ag + 16); a3 = *(const uint4*)(Ag + 24);
    b0 = *(const uint4*)(Bg);      b1 = *(const uint4*)(Bg + 8);
    if constexpr (BNT == 128) {
        b2 = *(const uint4*)(Bg + 16); b3 = *(const uint4*)(Bg + 24);
    }

    int KS = K / 64;
    for (int ks = 0; ks < KS; ++ks) {
        __syncthreads();
        *(uint4*)&As[srow][scol]      = a0;
        *(uint4*)&As[srow][scol + 8]  = a1;
        *(uint4*)&As[srow][scol + 16] = a2;
        *(uint4*)&As[srow][scol + 24] = a3;
        *(uint4*)&Bs[srowB][scolB]     = b0;
        *(uint4*)&Bs[srowB][scolB + 8] = b1;
        if constexpr (BNT == 128) {
            *(uint4*)&Bs[srowB][scolB + 16] = b2;
            *(uint4*)&Bs[srowB][scolB + 24] = b3;
        }
        __syncthreads();
        if (ks + 1 < KS) {
            int k0 = (ks + 1) * 64;
            a0 = *(const uint4*)(Ag + k0);      a1 = *(const uint4*)(Ag + k0 + 8);
            a2 = *(const uint4*)(Ag + k0 + 16); a3 = *(const uint4*)(Ag + k0 + 24);
            b0 = *(const uint4*)(Bg + k0);      b1 = *(const uint4*)(Bg + k0 + 8);
            if constexpr (BNT == 128) {
                b2 = *(const uint4*)(Bg + k0 + 16); b3 = *(const uint4*)(Bg + k0 + 24);
            }
        }
#pragma unroll
        for (int kk = 0; kk < 2; ++kk) {
            v8h af[MI], bf[4];
#pragma unroll
            for (int i = 0; i < MI; ++i)
                af[i] = *(const v8h*)&As[wm + i * 16 + r16][kk * 32 + quad * 8];
#pragma unroll
            for (int j = 0; j < 4; ++j)
                bf[j] = *(const v8h*)&Bs[wn + j * 16 + r16][kk * 32 + quad * 8];
#pragma unroll
            for (int i = 0; i < MI; ++i)
#pragma unroll
                for (int j = 0; j < 4; ++j)
                    acc[i][j] = __builtin_amdgcn_mfma_f32_16x16x32_f16(
                        af[i], bf[j], acc[i][j], 0, 0, 0);
        }
    }

#pragma unroll
    for (int i = 0; i < MI; ++i) {
#pragma unroll
        for (int j = 0; j < 4; ++j) {
            int col = n0 + wn + j * 16 + r16;
            int rbase = m0 + wm + i * 16 + quad * 4;
            float bv = bias ? bias[col] : 0.f;
#pragma unroll
            for (int r = 0; r < 4; ++r) {
                float v = acc[i][j][r] + bv;
                if (ACT == 1) v = fmaxf(v, 0.f);
                if constexpr (HALF) {
                    ((_Float16*)Cv)[(size_t)(rbase + r) * ldc + col] = (_Float16)v;
                } else {
                    float* p = (float*)Cv + (size_t)(rbase + r) * ldc + col;
                    if (accum) v += *p;
                    *p = v;
                }
            }
        }
    }
}

// ---------------- x_proj fp16 MFMA split-K: dbl += xc_h @ xpw_h^T -------------
__global__ __launch_bounds__(256) void hgemm_xproj(
    const _Float16* __restrict__ A,    // xc_h, lda=DI
    const _Float16* __restrict__ B,    // xpw_h (64 x DI)
    float* __restrict__ C)             // dbl, ldc=64
{
    __shared__ _Float16 As[128][40];
    __shared__ _Float16 Bs[64][40];
    int tid = threadIdx.x;
    int m0 = blockIdx.y * 128;
    int kb = blockIdx.z * 128;
    int lane = tid & 63, wave = tid >> 6;
    int wm = wave * 32;
    int quad = lane >> 4, r16 = lane & 15;
    v4f acc[2][4] = {};

    int srow = tid >> 1, scol = (tid & 1) * 16;
    const _Float16* Ag = A + (size_t)(m0 + srow) * DI + kb + scol;
    int srowB = tid >> 2, scolB = (tid & 3) * 8;
    const _Float16* Bg = B + (size_t)srowB * DI + kb + scolB;

    uint4 a0 = *(const uint4*)(Ag);
    uint4 a1 = *(const uint4*)(Ag + 8);
    uint4 b0 = *(const uint4*)(Bg);

    for (int ks = 0; ks < 4; ++ks) {
        __syncthreads();
        *(uint4*)&As[srow][scol] = a0;
        *(uint4*)&As[srow][scol + 8] = a1;
        *(uint4*)&Bs[srowB][scolB] = b0;
        __syncthreads();
        if (ks + 1 < 4) {
            int k0 = (ks + 1) * 32;
            a0 = *(const uint4*)(Ag + k0);
            a1 = *(const uint4*)(Ag + k0 + 8);
            b0 = *(const uint4*)(Bg + k0);
        }
        v8h af[2], bf[4];
#pragma unroll
        for (int i = 0; i < 2; ++i)
            af[i] = *(const v8h*)&As[wm + i * 16 + r16][quad * 8];
#pragma unroll
        for (int j = 0; j < 4; ++j)
            bf[j] = *(const v8h*)&Bs[j * 16 + r16][quad * 8];
#pragma unroll
        for (int i = 0; i < 2; ++i)
#pragma unroll
            for (int j = 0; j < 4; ++j)
                acc[i][j] = __builtin_amdgcn_mfma_f32_16x16x32_f16(
                    af[i], bf[j], acc[i][j], 0, 0, 0);
    }
#pragma unroll
    for (int i = 0; i < 2; ++i) {
#pragma unroll
        for (int j = 0; j < 4; ++j) {
            int col = j * 16 + r16;
            int rbase = m0 + wm + i * 16 + quad * 4;
#pragma unroll
            for (int r = 0; r < 4; ++r)
                atomicAdd(&C[(size_t)(rbase + r) * 64 + col], acc[i][j][r]);
        }
    }
}

// --- attn fp16 MFMA + fused softmax tail (last-block ticket) ------------------
// avec[row] += tanh(hln_h@aw1_h^T + b1).w2 ; 64th block: softmax(avec)->aatt,
// zero pooled.
__global__ __launch_bounds__(256) void hgemm_attn(
    const _Float16* __restrict__ A,    // hln_h, lda=DM
    const _Float16* __restrict__ B,    // aw1_h (128 x DM)
    const float* __restrict__ b1, const float* __restrict__ w2,
    float* __restrict__ avec, int* __restrict__ ticket,
    float* __restrict__ aatt, float* __restrict__ pooled)
{
    __shared__ _Float16 As[128][40];
    __shared__ _Float16 Bs[64][40];
    int tid = threadIdx.x;
    int m0 = blockIdx.y * 128, n0 = blockIdx.x * 64;
    int lane = tid & 63, wave = tid >> 6;
    int wm = wave * 32;
    int quad = lane >> 4, r16 = lane & 15;
    v4f acc[2][4] = {};

    int srow = tid >> 1, scol = (tid & 1) * 16;
    const _Float16* Ag = A + (size_t)(m0 + srow) * DM + scol;
    int srowB = tid >> 2, scolB = (tid & 3) * 8;
    const _Float16* Bg = B + (size_t)(n0 + srowB) * DM + scolB;

    uint4 a0 = *(const uint4*)(Ag);
    uint4 a1 = *(const uint4*)(Ag + 8);
    uint4 b0 = *(const uint4*)(Bg);

    for (int ks = 0; ks < DM / 32; ++ks) {
        __syncthreads();
        *(uint4*)&As[srow][scol] = a0;
        *(uint4*)&As[srow][scol + 8] = a1;
        *(uint4*)&Bs[srowB][scolB] = b0;
        __syncthreads();
        if (ks + 1 < DM / 32) {
            int k0 = (ks + 1) * 32;
            a0 = *(const uint4*)(Ag + k0);
            a1 = *(const uint4*)(Ag + k0 + 8);
            b0 = *(const uint4*)(Bg + k0);
        }
        v8h af[2], bf[4];
#pragma unroll
        for (int i = 0; i < 2; ++i)
            af[i] = *(const v8h*)&As[wm + i * 16 + r16][quad * 8];
#pragma unroll
        for (int j = 0; j < 4; ++j)
            bf[j] = *(const v8h*)&Bs[j * 16 + r16][quad * 8];
#pragma unroll
        for (int i = 0; i < 2; ++i)
#pragma unroll
            for (int j = 0; j < 4; ++j)
                acc[i][j] = __builtin_amdgcn_mfma_f32_16x16x32_f16(
                    af[i], bf[j], acc[i][j], 0, 0, 0);
    }

#pragma unroll
    for (int i = 0; i < 2; ++i) {
        float part[4] = {0.f, 0.f, 0.f, 0.f};
#pragma unroll
        for (int j = 0; j < 4; ++j) {
            int col = n0 + j * 16 + r16;
            float bv = b1[col], wv = w2[col];
#pragma unroll
            for (int r = 0; r < 4; ++r)
                part[r] = fmaf(tanhf(acc[i][j][r] + bv), wv, part[r]);
        }
#pragma unroll
        for (int r = 0; r < 4; ++r) {
            part[r] += __shfl_xor(part[r], 1, 64);
            part[r] += __shfl_xor(part[r], 2, 64);
            part[r] += __shfl_xor(part[r], 4, 64);
            part[r] += __shfl_xor(part[r], 8, 64);
        }
        if (r16 == 0) {
            int rbase = m0 + wm + i * 16 + quad * 4;
#pragma unroll
            for (int r = 0; r < 4; ++r)
                atomicAdd(&avec[rbase + r], part[r]);
        }
    }

    // ---- last-block softmax tail ----
    __threadfence();
    __shared__ int st;
    if (tid == 0) st = atomicAdd(ticket, 1);
    __syncthreads();
    if (st != 63) return;
    __threadfence();
    float v[16];
    float mx = -1e30f;
#pragma unroll
    for (int i = 0; i < 16; ++i) { v[i] = avec[tid + i * 256]; mx = fmaxf(mx, v[i]); }
    for (int off = 32; off; off >>= 1) mx = fmaxf(mx, __shfl_xor(mx, off, 64));
    __shared__ float sred[4];
    int wv = tid >> 6, ln2 = tid & 63;
    if (ln2 == 0) sred[wv] = mx;
    __syncthreads();
    mx = fmaxf(fmaxf(sred[0], sred[1]), fmaxf(sred[2], sred[3]));
    float ssum = 0.f;
#pragma unroll
    for (int i = 0; i < 16; ++i) { v[i] = __expf(v[i] - mx); ssum += v[i]; }
    for (int off = 32; off; off >>= 1) ssum += __shfl_xor(ssum, off, 64);
    __syncthreads();
    if (ln2 == 0) sred[wv] = ssum;
    __syncthreads();
    ssum = sred[0] + sred[1] + sred[2] + sred[3];
    float inv = 1.f / ssum;
#pragma unroll
    for (int i = 0; i < 16; ++i) aatt[tid + i * 256] = v[i] * inv;
    pooled[tid] = 0.f;
    pooled[tid + 256] = 0.f;
}

// ------- dt GEMM (fp32 SIMT, K=32): dtv_h = softplus(dbl[:,:32]@dtw^T + b) ----
#define BM 64
#define BN 64
#define BKK 32
__global__ __launch_bounds__(256) void gemm_dt(
    const float* __restrict__ A, int lda,
    const float* __restrict__ B, int ldb,
    _Float16* __restrict__ C, int ldc,
    const float* __restrict__ bias, int K)
{
    __shared__ float As[BKK][BM + 4];
    __shared__ float Bs[BKK][BN + 4];
    int tid = threadIdx.x;
    int m0 = blockIdx.y * BM;
    int n0 = blockIdx.x * BN;
    int tx = tid & 15, ty = tid >> 4;
    float acc[4][4] = {};
    int arow = tid >> 3;
    int ak = (tid & 7) * 4;

    for (int k0 = 0; k0 < K; k0 += BKK) {
#pragma unroll
        for (int r = 0; r < 2; ++r) {
            int row = arow + r * 32;
            float4 va = *(const float4*)(A + (size_t)(m0 + row) * lda + k0 + ak);
            As[ak + 0][row] = va.x; As[ak + 1][row] = va.y;
            As[ak + 2][row] = va.z; As[ak + 3][row] = va.w;
            float4 vb = *(const float4*)(B + (size_t)(n0 + row) * ldb + k0 + ak);
            Bs[ak + 0][row] = vb.x; Bs[ak + 1][row] = vb.y;
            Bs[ak + 2][row] = vb.z; Bs[ak + 3][row] = vb.w;
        }
        __syncthreads();
#pragma unroll
        for (int kk = 0; kk < BKK; ++kk) {
            float4 a4 = *(const float4*)&As[kk][ty * 4];
            float4 b4 = *(const float4*)&Bs[kk][tx * 4];
            float a[4] = {a4.x, a4.y, a4.z, a4.w};
            float b[4] = {b4.x, b4.y, b4.z, b4.w};
#pragma unroll
            for (int i = 0; i < 4; ++i)
#pragma unroll
                for (int j = 0; j < 4; ++j)
                    acc[i][j] = fmaf(a[i], b[j], acc[i][j]);
        }
        __syncthreads();
    }

#pragma unroll
    for (int i = 0; i < 4; ++i) {
        int row = m0 + ty * 4 + i;
        int col = n0 + tx * 4;
        _Float16 v4[4];
#pragma unroll
        for (int j = 0; j < 4; ++j) {
            float xv = acc[i][j] + bias[col + j];
            xv = (xv > 20.f) ? xv : log1pf(__expf(xv));
            v4[j] = (_Float16)xv;
        }
        *(uint2*)(C + (size_t)row * ldc + col) = *(uint2*)v4;
    }
}

// ---------------- layernorm (D=512); fp32 out optional; fp16 out; avec init ---
__global__ __launch_bounds__(256) void layernorm_k(
    const float* __restrict__ x, const float* __restrict__ w,
    const float* __restrict__ b, float* __restrict__ o,
    _Float16* __restrict__ oh, float* __restrict__ avec,
    const float* __restrict__ b2)
{
    int row = blockIdx.x;
    int tid = threadIdx.x;
    const float* xr = x + (size_t)row * DM;
    float v0 = xr[tid], v1 = xr[tid + 256];
    float s = v0 + v1, ss = v0 * v0 + v1 * v1;
    for (int off = 32; off; off >>= 1) {
        s += __shfl_down(s, off, 64);
        ss += __shfl_down(ss, off, 64);
    }
    __shared__ float sm[4], sm2[4];
    int wave = tid >> 6, lane = tid & 63;
    if (lane == 0) { sm[wave] = s; sm2[wave] = ss; }
    __syncthreads();
    float tot = sm[0] + sm[1] + sm[2] + sm[3];
    float tot2 = sm2[0] + sm2[1] + sm2[2] + sm2[3];
    float mu = tot * (1.f / DM);
    float var = tot2 * (1.f / DM) - mu * mu;
    float rs = rsqrtf(var + 1e-5f);
    float y0 = (v0 - mu) * rs * w[tid] + b[tid];
    float y1 = (v1 - mu) * rs * w[tid + 256] + b[tid + 256];
    if (o) {
        o[(size_t)row * DM + tid] = y0;
        o[(size_t)row * DM + tid + 256] = y1;
    }
    oh[(size_t)row * DM + tid] = (_Float16)y0;
    oh[(size_t)row * DM + tid + 256] = (_Float16)y1;
    if (avec && tid == 0) avec[row] = b2[0];
}

// ---------------- permuted causal conv (K=4) + SiLU; fp16 out; zeroes dbl -----
__global__ __launch_bounds__(256) void conv_silu_k(
    const _Float16* __restrict__ xz, const int* __restrict__ perm,
    const float* __restrict__ cw, const float* __restrict__ cb,
    _Float16* __restrict__ xc, float* __restrict__ dbl)
{
    if (blockIdx.x < 256) {
        int zi = (blockIdx.x * 256 + threadIdx.x) * 4;
        *(float4*)(dbl + zi) = make_float4(0.f, 0.f, 0.f, 0.f);
    }
    int g = blockIdx.x * 256 + threadIdx.x;   // g < L*DI
    int c = g & (DI - 1), p = g >> 10;
    float acc = cb[c];
#pragma unroll
    for (int k = 0; k < 4; ++k) {
        int q = p + k - 3;
        if (q >= 0)
            acc = fmaf((float)xz[(size_t)perm[q] * (2 * DI) + c], cw[c * 4 + k], acc);
    }
    float sig = 1.f / (1.f + __expf(-acc));
    xc[g] = (_Float16)(acc * sig);
}

// ---------------- chunked parallel selective scan (fp16 summaries) ------------
__global__ __launch_bounds__(256) void scan_pass1(
    const _Float16* __restrict__ dt, const _Float16* __restrict__ u,
    const float* __restrict__ dbl, const float* __restrict__ A_log,
    _Float16* __restrict__ Aprod, _Float16* __restrict__ carry)
{
    int c = blockIdx.x * 256 + threadIdx.x;
    int j = blockIdx.y;
    float Ac[16];
#pragma unroll
    for (int s = 0; s < 16; ++s) Ac[s] = -__expf(A_log[c * DS + s]);
    float ap[16], h[16];
#pragma unroll
    for (int s = 0; s < 16; ++s) { ap[s] = 1.f; h[s] = 0.f; }
    int t0 = j * CHK;
    for (int tt = 0; tt < CHK; ++tt) {
        int t = t0 + tt;
        float dtv = (float)dt[(size_t)t * DI + c];
        float uv  = (float)u[(size_t)t * DI + c];
        v4f Bv[4];
#pragma unroll
        for (int q = 0; q < 4; ++q)
            Bv[q] = *(const v4f*)(dbl + (size_t)t * 64 + DTR + q * 4);
        float du = dtv * uv;
#pragma unroll
        for (int s = 0; s < 16; ++s) {
            float dA = __expf(dtv * Ac[s]);
            h[s] = fmaf(dA, h[s], du * Bv[s >> 2][s & 3]);
            ap[s] *= dA;
        }
    }
    size_t base = ((size_t)j * DI + c) * DS;
#pragma unroll
    for (int q = 0; q < 4; ++q) {
        v4h av = {(_Float16)ap[q*4], (_Float16)ap[q*4+1], (_Float16)ap[q*4+2], (_Float16)ap[q*4+3]};
        v4h hv = {(_Float16)h[q*4], (_Float16)h[q*4+1], (_Float16)h[q*4+2], (_Float16)h[q*4+3]};
        *(v4h*)(Aprod + base + q * 4) = av;
        *(v4h*)(carry + base + q * 4) = hv;
    }
}

__global__ __launch_bounds__(256) void scan_pass2(
    const _Float16* __restrict__ Aprod, const _Float16* __restrict__ carry,
    _Float16* __restrict__ Hin)
{
    int idx = blockIdx.x * 256 + threadIdx.x;
    float H = 0.f;
    Hin[idx] = (_Float16)0.f;
    for (int j = 1; j < NCH; ++j) {
        H = fmaf((float)Aprod[(size_t)(j - 1) * (DI * DS) + idx], H,
                 (float)carry[(size_t)(j - 1) * (DI * DS) + idx]);
        Hin[(size_t)j * (DI * DS) + idx] = (_Float16)H;
    }
}

__global__ __launch_bounds__(256) void scan_pass3(
    const _Float16* __restrict__ dt, const _Float16* __restrict__ u,
    const float* __restrict__ dbl, const _Float16* __restrict__ xz,
    const float* __restrict__ A_log, const float* __restrict__ Dsk,
    const int* __restrict__ perm, const _Float16* __restrict__ Hin,
    _Float16* __restrict__ yo)
{
    int c = blockIdx.x * 256 + threadIdx.x;
    int j = blockIdx.y;
    float Ac[16];
#pragma unroll
    for (int s = 0; s < 16; ++s) Ac[s] = -__expf(A_log[c * DS + s]);
    float Dp = Dsk[c];
    float h[16];
    size_t hbase = ((size_t)j * DI + c) * DS;
#pragma unroll
    for (int q = 0; q < 4; ++q) {
        v4h hv = *(const v4h*)(Hin + hbase + q * 4);
#pragma unroll
        for (int r = 0; r < 4; ++r) h[q * 4 + r] = (float)hv[r];
    }
    int t0 = j * CHK;
    for (int tt = 0; tt < CHK; ++tt) {
        int t = t0 + tt;
        float dtv = (float)dt[(size_t)t * DI + c];
        float uv  = (float)u[(size_t)t * DI + c];
        v4f Bv[4], Cv[4];
#pragma unroll
        for (int q = 0; q < 4; ++q) {
            Bv[q] = *(const v4f*)(dbl + (size_t)t * 64 + DTR + q * 4);
            Cv[q] = *(const v4f*)(dbl + (size_t)t * 64 + DTR + DS + q * 4);
        }
        float du = dtv * uv;
        float y = 0.f;
#pragma unroll
        for (int s = 0; s < 16; ++s) {
            float dA = __expf(dtv * Ac[s]);
            h[s] = fmaf(dA, h[s], du * Bv[s >> 2][s & 3]);
            y = fmaf(h[s], Cv[s >> 2][s & 3], y);
        }
        int tp = perm[t];
        float z = (float)xz[(size_t)tp * (2 * DI) + DI + c];
        float sig = 1.f / (1.f + __expf(-z));
        yo[(size_t)tp * DI + c] = (_Float16)((y + uv * Dp) * (z * sig));
    }
}

// ---------------- pooled[m] += sum_t aatt[t]*hln_h[t,m]; 128 blocks -----------
__global__ __launch_bounds__(512) void pool_k(
    const float* __restrict__ aatt, const _Float16* __restrict__ hh,
    float* __restrict__ pooled)
{
    int m = threadIdx.x;
    int t0 = blockIdx.x * 32;
    float acc = 0.f;
    for (int r = 0; r < 32; ++r) {
        int t = t0 + r;
        acc = fmaf(aatt[t], (float)hh[(size_t)t * DM + m], acc);
    }
    atomicAdd(&pooled[m], acc);
}

__global__ __launch_bounds__(64) void out2048_k(
    const float* __restrict__ pooled, const float* __restrict__ w,
    const float* __restrict__ b, float* __restrict__ out)
{
    int n = blockIdx.x;
    int lane = threadIdx.x;
    const float* wr = w + (size_t)n * DM;
    float acc = 0.f;
#pragma unroll
    for (int k = 0; k < 8; ++k)
        acc = fmaf(wr[lane + k * 64], pooled[lane + k * 64], acc);
    for (int off = 32; off; off >>= 1) acc += __shfl_xor(acc, off, 64);
    if (lane == 0) out[n] = acc + b[n];
}

extern "C" void kernel_launch(void* const* d_in, const int* in_sizes, int n_in,
                              void* d_out, int out_size, void* d_ws, size_t ws_size,
                              hipStream_t stream) {
    const float* x     = (const float*)d_in[0];
    const int*   rate  = (const int*)d_in[1];
    const float* fc1_w = (const float*)d_in[2];
    const float* fc1_b = (const float*)d_in[3];
    const float* ln_w  = (const float*)d_in[4];
    const float* ln_b  = (const float*)d_in[5];
    const float* ipw   = (const float*)d_in[6];
    const float* cw    = (const float*)d_in[7];
    const float* cb    = (const float*)d_in[8];
    const float* xpw   = (const float*)d_in[9];
    const float* dtw   = (const float*)d_in[10];
    const float* dtpb  = (const float*)d_in[11];
    const float* A_log = (const float*)d_in[12];
    const float* Dsk   = (const float*)d_in[13];
    const float* opw   = (const float*)d_in[14];
    const float* nw    = (const float*)d_in[15];
    const float* nb    = (const float*)d_in[16];
    const float* aw1   = (const float*)d_in[17];
    const float* ab1   = (const float*)d_in[18];
    const float* aw2   = (const float*)d_in[19];
    const float* ab2   = (const float*)d_in[20];
    const float* ow    = (const float*)d_in[21];
    const float* ob    = (const float*)d_in[22];
    float* out = (float*)d_out;

    int* perm = (int*)d_ws;
    int* ticket = (int*)d_ws + 4096;
    float* f = (float*)d_ws + 4096 + 256;   // 256-int pad keeps 1KB alignment
    float* h    = f; f += (size_t)L * DM;
    float* dbl  = f; f += (size_t)L * 64;
    float* avec = f; f += L;
    float* pooled = f; f += DM;
    _Float16* fh = (_Float16*)f;
    _Float16* xh     = fh; fh += (size_t)L * DIN;
    _Float16* hln_h  = fh; fh += (size_t)L * DM;
    _Float16* yo_h   = fh; fh += (size_t)L * DI;
    _Float16* xz_h   = fh; fh += (size_t)L * 2 * DI;
    _Float16* xc_h   = fh; fh += (size_t)L * DI;
    _Float16* dtv_h  = fh; fh += (size_t)L * DI;
    _Float16* Aprod  = fh; fh += (size_t)NCH * DI * DS;
    _Float16* carry  = fh; fh += (size_t)NCH * DI * DS;
    _Float16* Hin    = fh; fh += (size_t)NCH * DI * DS;
    _Float16* fc1w_h = fh; fh += (size_t)DM * DIN;
    _Float16* ipw_h  = fh; fh += (size_t)2 * 2 * DI * DM;
    _Float16* opw_h  = fh; fh += (size_t)2 * DM * DI;
    _Float16* xpw_h  = fh; fh += (size_t)2 * 64 * DI;
    _Float16* aw1_h  = fh; fh += (size_t)128 * DM;

    // perm + ticket-zero + all fp32->fp16 conversions in one launch
    f2h_multi_k<<<16 + (L * DIN + DM * DIN + 2 * 2 * DI * DM + 2 * DM * DI
                   + 2 * 64 * DI + 128 * DM) / 1024, 256, 0, stream>>>(
        rate, perm, ticket,
        x, xh, L * DIN / 1024,
        fc1_w, fc1w_h, DM * DIN / 1024,
        ipw, ipw_h, 2 * 2 * DI * DM / 1024,
        opw, opw_h, 2 * DM * DI / 1024,
        xpw, xpw_h, 2 * 64 * DI / 1024,
        aw1, aw1_h, 128 * DM / 1024);

    // h = relu(x @ fc1_w^T + fc1_b)   [fp16 MFMA, BK=64, N64 tile]
    hgemm_nt<1, 64, 0><<<dim3(DM / 64, L / 128), 256, 0, stream>>>(
        xh, DIN, fc1w_h, DIN, h, DM, fc1_b, DIN, 0);

    for (int l = 0; l < 2; ++l) {
        // LN -> fp16 only (fp32 LN output is dead in the loop)
        layernorm_k<<<L, 256, 0, stream>>>(h, ln_w + l * DM, ln_b + l * DM,
                                           nullptr, hln_h, nullptr, nullptr);
        // xz = hln @ in_proj^T   [fp16 MFMA, BK=64 -> fp16 out, 512 blocks]
        hgemm_nt<0, 128, 1><<<dim3(2 * DI / 128, L / 128), 256, 0, stream>>>(
            hln_h, DM, ipw_h + (size_t)l * 2 * DI * DM, DM, xz_h, 2 * DI,
            nullptr, DM, 0);
        // xc = silu(causal_conv(x_perm)) -> fp16; also zeroes dbl
        conv_silu_k<<<L * DI / 256, 256, 0, stream>>>(
            xz_h, perm, cw + (size_t)l * DI * 4, cb + (size_t)l * DI, xc_h, dbl);
        // dbl += xc_h @ xpw_h^T  [fp16 MFMA split-K 8 -> 256 blocks]
        hgemm_xproj<<<dim3(1, L / 128, 8), 256, 0, stream>>>(
            xc_h, xpw_h + (size_t)l * 64 * DI, dbl);
        // dtv_h = softplus(dbl[:, :32] @ dt_proj^T + dtb)  (fp16 out)
        gemm_dt<<<dim3(DI / 64, L / 64), 256, 0, stream>>>(
            dbl, 64, dtw + (size_t)l * DI * DTR, DTR, dtv_h, DI,
            dtpb + (size_t)l * DI, DTR);
        // chunked parallel selective scan (256 chunks -> 1024 blocks)
        scan_pass1<<<dim3(DI / 256, NCH), 256, 0, stream>>>(
            dtv_h, xc_h, dbl, A_log + (size_t)l * DI * DS, Aprod, carry);
        scan_pass2<<<DI * DS / 256, 256, 0, stream>>>(Aprod, carry, Hin);
        scan_pass3<<<dim3(DI / 256, NCH), 256, 0, stream>>>(
            dtv_h, xc_h, dbl, xz_h, A_log + (size_t)l * DI * DS,
            Dsk + (size_t)l * DI, perm, Hin, yo_h);
        // h += yo @ out_proj^T   [fp16 MFMA, BK=64, N64 tile, accumulate]
        hgemm_nt<0, 64, 0><<<dim3(DM / 64, L / 128), 256, 0, stream>>>(
            yo_h, DI, opw_h + (size_t)l * DM * DI, DI, h, DM, nullptr, DI, 1);
    }

    // final LN: fp16 out only, seeds avec with attn bias b2
    layernorm_k<<<L, 256, 0, stream>>>(h, nw, nb, nullptr, hln_h, avec, ab2);
    // fused attn + last-block softmax (writes aatt=out+2048, zeroes pooled)
    hgemm_attn<<<dim3(2, L / 128), 256, 0, stream>>>(
        hln_h, aw1_h, ab1, aw2, avec, ticket, out + 2048, pooled);
    pool_k<<<128, 512, 0, stream>>>(out + 2048, hln_h, pooled);
    out2048_k<<<2048, 64, 0, stream>>>(pooled, ow, ob, out);
}